// Round 12
// baseline (1155.502 us; speedup 1.0000x reference)
//
#include <hip/hip_runtime.h>
#include <math.h>

// Problem constants
#define BB 8
#define MM 2048
#define KM 1024
#define DD 256
#define HH 4
#define HD 64
#define NLAYER 2
#define BN (BB*KM)        // 8192 rows per "decoder half"
#define N2 (2*BN)         // 16384 rows d0||d1
#define CG_ITERS 5

// XOR-swizzled LDS addressing for the attention tiles: stride 64 (no pad),
// 16-byte blocks permuted by row. Conflict-free for uint4 stores, bf16x8
// reads, and short4v reads — and keeps every access 16B/8B aligned.
#define SWZ(r,c) (((r)<<6) + ((((c)>>3) ^ ((r)&7))<<3) + ((c)&7))

typedef __bf16 bf16;
typedef __bf16 bf16x8 __attribute__((ext_vector_type(8)));
typedef __bf16 bf16x4 __attribute__((ext_vector_type(4)));
typedef __bf16 bf16x2 __attribute__((ext_vector_type(2)));
typedef _Float16 fp16;
typedef _Float16 fp16x8 __attribute__((ext_vector_type(8)));
typedef short  short4v __attribute__((ext_vector_type(4)));
typedef float  floatx4 __attribute__((ext_vector_type(4)));
#define MFMA16(a,b,c)  __builtin_amdgcn_mfma_f32_16x16x32_bf16(a,b,c,0,0,0)
#define MFMA16H(a,b,c) __builtin_amdgcn_mfma_f32_16x16x32_f16(a,b,c,0,0,0)

// K=16 bf16 MFMA (PV stage: S^T C-frag == its B-operand layout).
#if defined(__HIP_DEVICE_COMPILE__)
  #if __has_builtin(__builtin_amdgcn_mfma_f32_16x16x16bf16_1k)
    #define MFMA1K(a,b,c) __builtin_amdgcn_mfma_f32_16x16x16bf16_1k(a,b,c,0,0,0)
  #else
    #error "device pass lacks mfma_f32_16x16x16bf16_1k"
  #endif
#else
  #define MFMA1K(a,b,c) (c)   /* host stub, never executed */
#endif

__device__ __forceinline__ float softplusf(float x) {
  return fmaxf(x, 0.f) + log1pf(expf(-fabsf(x)));
}

__device__ __forceinline__ float wred(float x) {
  x += __shfl_xor(x, 1);  x += __shfl_xor(x, 2);  x += __shfl_xor(x, 4);
  x += __shfl_xor(x, 8);  x += __shfl_xor(x, 16); x += __shfl_xor(x, 32);
  return x;
}

__device__ __forceinline__ short4v pack4(float a, float b, float c, float d) {
  bf16x4 v = {(bf16)a,(bf16)b,(bf16)c,(bf16)d};
  short4v s;
  __builtin_memcpy(&s, &v, 8);
  return s;
}

// stage 8 elements (convert to bf16 if needed), 16B LDS store
__device__ __forceinline__ void stage8(bf16* dst, const float* src) {
  float4 a = *(const float4*)src;
  float4 b = *(const float4*)(src + 4);
  bf16x8 v = { (bf16)a.x,(bf16)a.y,(bf16)a.z,(bf16)a.w,
               (bf16)b.x,(bf16)b.y,(bf16)b.z,(bf16)b.w };
  *(bf16x8*)dst = v;
}
__device__ __forceinline__ void stage8(bf16* dst, const bf16* src) {
  *(uint4*)dst = *(const uint4*)src;
}

// raw staging to fp16 LDS (CG phase)
template<typename T> struct Raw8;
template<> struct Raw8<float> {
  float4 a, b;
  __device__ __forceinline__ void load(const float* s) {
    a = *(const float4*)s; b = *(const float4*)(s + 4);
  }
  __device__ __forceinline__ void store(fp16* d) const {
    fp16x8 v = { (fp16)a.x,(fp16)a.y,(fp16)a.z,(fp16)a.w,
                 (fp16)b.x,(fp16)b.y,(fp16)b.z,(fp16)b.w };
    *(fp16x8*)d = v;
  }
  __device__ __forceinline__ void storeb(bf16* d) const {
    bf16x8 v = { (bf16)a.x,(bf16)a.y,(bf16)a.z,(bf16)a.w,
                 (bf16)b.x,(bf16)b.y,(bf16)b.z,(bf16)b.w };
    *(bf16x8*)d = v;
  }
};
template<> struct Raw8<fp16> {
  uint4 u;
  __device__ __forceinline__ void load(const fp16* s) { u = *(const uint4*)s; }
  __device__ __forceinline__ void store(fp16* d) const { *(uint4*)d = u; }
};

// ---------------- gather (writes F to both FBUF and DCAT; no copy pass) -----
__global__ __launch_bounds__(256) void gather_kernel(
    const float* __restrict__ fa, const float* __restrict__ fb,
    const int* __restrict__ matches, const float* __restrict__ ka,
    const float* __restrict__ kb, float* __restrict__ F,
    float* __restrict__ Fd,
    float* __restrict__ xy0, float* __restrict__ xy1)
{
  int si = blockIdx.x;
  int s  = si >> 10;
  int t  = threadIdx.x;
  int ia = matches[(size_t)si*2+0];
  int ib = matches[(size_t)si*2+1];
  float v = fb[((size_t)s*MM + ib)*DD + t] - fa[((size_t)s*MM + ia)*DD + t];
  F[(size_t)si*DD + t]  = v;
  Fd[(size_t)si*DD + t] = v;
  if (t == 0) {
    xy0[(size_t)si*2+0] = ka[((size_t)s*MM + ia)*2+0];
    xy0[(size_t)si*2+1] = ka[((size_t)s*MM + ia)*2+1];
    xy1[(size_t)si*2+0] = kb[((size_t)s*MM + ib)*2+0];
    xy1[(size_t)si*2+1] = kb[((size_t)s*MM + ib)*2+1];
  }
}

// ---------------- positional encoding (4 rows per 256-thread block) ---------
__global__ __launch_bounds__(256) void posenc_kernel(
    const float* __restrict__ xy, const float* __restrict__ Wr,
    float* __restrict__ enc)
{
  int t = threadIdx.x;
  int si = blockIdx.x*4 + (t >> 6);
  int s = si >> 10, i = si & 1023;
  int d = t & 63; int p = d >> 1;
  float x = xy[(size_t)si*2], y = xy[(size_t)si*2+1];
  float pr = Wr[p*2]*x + Wr[p*2+1]*y;
  enc[(((size_t)s*2+0)*KM + i)*HD + d] = cosf(pr);
  enc[(((size_t)s*2+1)*KM + i)*HD + d] = sinf(pr);
}

// ---------------- Kmat (fp16) + rowsum (wave butterflies) -------------------
// exp2f with beta*log2e folded: single v_exp_f32 instead of libm expf; the
// <=1ulp f32 delta is far below the fp16 quantization of Km.
__global__ __launch_bounds__(256) void kmat_kernel(
    const float* __restrict__ xy0, const float* __restrict__ beta_ptr,
    fp16* __restrict__ Km, float* __restrict__ rowsum)
{
  __shared__ float redw[4];
  int si = blockIdx.x; int s = si >> 10;
  int t = threadIdx.x;
  int lane = t & 63, w = t >> 6;
  float beta_l2 = softplusf(beta_ptr[0]) * 1.442695040888963f;
  float xi = xy0[(size_t)si*2], yi = xy0[(size_t)si*2+1];
  const float* xys = xy0 + (size_t)s*KM*2;
  float sum = 0.f;
  for (int jj = 0; jj < 4; ++jj) {
    int j = jj*256 + t;
    float dx = xi - xys[j*2], dy = yi - xys[j*2+1];
    float v = exp2f(-beta_l2*(dx*dx + dy*dy));
    Km[(size_t)si*KM + j] = (fp16)v;
    sum += v;
  }
  sum = wred(sum);
  if (lane == 0) redw[w] = sum;
  __syncthreads();
  if (t == 0)
    rowsum[si] = ((redw[0]+redw[1]) + (redw[2]+redw[3])) + 1e-6f;
}

// ---------------- MFMA GEMM, tile 128xNT (NT=128 or 64), BK=64 ----------------
// C = [A1|A2] @ Wsel.T, epilogue (v+bias)*scale (+resid).
// WPERM: W row index perm(j)=(j&255)*3+(j>>8)  (qkv channel de-interleave)
// DUALW: cols [0,256) from W/bias/scale, cols [256,512) from Wb/biasb/scaleb
// Round-8 staging structure (stage8 direct to LDS, 2 barriers/step) with
// k-independent A/W row pointers hoisted out of the K-loop.
template<int NT, int WPERM, int DUALW,
         typename TA1, typename TA2, typename TW, typename TO>
__global__ __launch_bounds__(256) void mm_kernel(
    const TA1* __restrict__ A1, const TA2* __restrict__ A2, int K1, int K,
    const TW* __restrict__ W, const float* __restrict__ bias,
    const TW* __restrict__ Wb, const float* __restrict__ biasb,
    TO* __restrict__ C, int O, float scale, float scaleb,
    const float* __restrict__ resid)
{
  __shared__ __align__(16) bf16 Al[128*72];
  __shared__ __align__(16) bf16 Wl[NT*72];
  constexpr int MB = (NT == 128) ? 4 : 2;
  constexpr int WP = NT/32;
  int tid = threadIdx.x;
  int row0 = blockIdx.x*128, col0 = blockIdx.y*NT;
  int lane = tid & 63, w = tid >> 6;
  int wr = (NT == 128) ? (w>>1)*64 : w*32;
  int wc = (NT == 128) ? (w&1)*64 : 0;
  int lm = lane & 15, lq = lane >> 4;
  int srow = tid >> 3, sc8 = (tid & 7)*8;

  // k-independent source row pointers
  const TA1* aptr1[4]; const TA2* aptr2[4];
#pragma unroll
  for (int p = 0; p < 4; ++p) {
    int row = p*32 + srow;
    aptr1[p] = A1 + (size_t)(row0+row)*K1 + sc8;
    aptr2[p] = A2 + (size_t)(row0+row)*(K-K1) + sc8;
  }
  const TW* wptr[WP];
#pragma unroll
  for (int p = 0; p < WP; ++p) {
    int wg = col0 + p*32 + srow;
    const TW* wsrc; int wrow;
    if (DUALW && wg >= 256) { wsrc = Wb; wrow = wg - 256; }
    else { wsrc = W; wrow = WPERM ? ((wg & 255)*3 + (wg >> 8)) : wg; }
    wptr[p] = wsrc + (size_t)wrow*K + sc8;
  }

  floatx4 acc[MB][4];
#pragma unroll
  for (int mb = 0; mb < MB; ++mb)
#pragma unroll
    for (int nb = 0; nb < 4; ++nb) acc[mb][nb] = (floatx4){0.f,0.f,0.f,0.f};
  for (int k0 = 0; k0 < K; k0 += 64) {
    bool use1 = (k0 < K1);
#pragma unroll
    for (int p = 0; p < 4; ++p) {
      bf16* d = &Al[(p*32+srow)*72 + sc8];
      if (use1) stage8(d, aptr1[p] + k0);
      else      stage8(d, aptr2[p] + (k0 - K1));
    }
#pragma unroll
    for (int p = 0; p < WP; ++p)
      stage8(&Wl[(p*32+srow)*72 + sc8], wptr[p] + k0);
    __syncthreads();
    bf16x8 af[MB][2], bfr[4][2];
#pragma unroll
    for (int mb = 0; mb < MB; ++mb) {
      af[mb][0] = *(bf16x8*)&Al[(wr + mb*16 + lm)*72 + lq*8];
      af[mb][1] = *(bf16x8*)&Al[(wr + mb*16 + lm)*72 + 32 + lq*8];
    }
#pragma unroll
    for (int nb = 0; nb < 4; ++nb) {
      bfr[nb][0] = *(bf16x8*)&Wl[(wc + nb*16 + lm)*72 + lq*8];
      bfr[nb][1] = *(bf16x8*)&Wl[(wc + nb*16 + lm)*72 + 32 + lq*8];
    }
#pragma unroll
    for (int mb = 0; mb < MB; ++mb)
#pragma unroll
      for (int nb = 0; nb < 4; ++nb) {
        acc[mb][nb] = MFMA16(af[mb][0], bfr[nb][0], acc[mb][nb]);
        acc[mb][nb] = MFMA16(af[mb][1], bfr[nb][1], acc[mb][nb]);
      }
    __syncthreads();
  }
#pragma unroll
  for (int mb = 0; mb < MB; ++mb) {
#pragma unroll
    for (int nb = 0; nb < 4; ++nb) {
#pragma unroll
      for (int r = 0; r < 4; ++r) {
        int grow = row0 + wr + mb*16 + lq*4 + r;
        int gcol = col0 + wc + nb*16 + lm;
        float v = acc[mb][nb][r];
        float bv = 0.f, scl = scale;
        if (DUALW && gcol >= 256) {
          if (biasb) bv = biasb[gcol - 256];
          scl = scaleb;
        } else if (bias) {
          bv = bias[WPERM ? ((gcol & 255)*3 + (gcol >> 8)) : gcol];
        }
        v = (v + bv) * scl;
        if (resid) v += resid[(size_t)grow*O + gcol];
        C[(size_t)grow*O + gcol] = (TO)v;
      }
    }
  }
}

// ---------------- mm64: 128x64 tile GEMM, mv64-pattern pipeline --------------
// C = A(bf16) @ W(float)^T + bias (+resid). Double-buffered LDS + register
// prefetch + ONE barrier per K-step (the schedule proven in mv64 on this
// problem; occupancy here is LDS/grid-capped at 2 blocks/CU either way, so
// the extra prefetch VGPRs cannot cost waves). Numerics identical to the
// mm_kernel<64,...> path it replaces.
template<typename TO>
__global__ __launch_bounds__(256) void mm64_kernel(
    const bf16* __restrict__ A, int K, const float* __restrict__ W,
    const float* __restrict__ bias, TO* __restrict__ C, int O,
    const float* __restrict__ resid)
{
  __shared__ __align__(16) bf16 Al[2][128*72];
  __shared__ __align__(16) bf16 Wl[2][64*72];
  int tid = threadIdx.x;
  int row0 = blockIdx.x*128, col0 = blockIdx.y*64;
  int lane = tid & 63, w = tid >> 6;
  int wr = w*32;
  int lm = lane & 15, lq = lane >> 4;
  int srow = tid >> 3, sc8 = (tid & 7)*8;

  const bf16* aptr[4];
#pragma unroll
  for (int p = 0; p < 4; ++p)
    aptr[p] = A + (size_t)(row0 + p*32 + srow)*K + sc8;
  const float* wptr[2];
#pragma unroll
  for (int p = 0; p < 2; ++p)
    wptr[p] = W + (size_t)(col0 + p*32 + srow)*K + sc8;

  floatx4 acc[2][4];
#pragma unroll
  for (int mb = 0; mb < 2; ++mb)
#pragma unroll
    for (int nb = 0; nb < 4; ++nb) acc[mb][nb] = (floatx4){0.f,0.f,0.f,0.f};

  uint4 ra[4]; Raw8<float> rw[2];
#pragma unroll
  for (int p = 0; p < 4; ++p) ra[p] = *(const uint4*)aptr[p];
#pragma unroll
  for (int p = 0; p < 2; ++p) rw[p].load(wptr[p]);
#pragma unroll
  for (int p = 0; p < 4; ++p) *(uint4*)&Al[0][(p*32+srow)*72 + sc8] = ra[p];
#pragma unroll
  for (int p = 0; p < 2; ++p) rw[p].storeb(&Wl[0][(p*32+srow)*72 + sc8]);
  __syncthreads();

  int nst = K >> 6;
  for (int j = 0; j < nst; ++j) {
    int cur = j & 1;
    bool pre = (j + 1 < nst);
    if (pre) {
      int k1 = (j+1) << 6;
#pragma unroll
      for (int p = 0; p < 4; ++p) ra[p] = *(const uint4*)(aptr[p] + k1);
#pragma unroll
      for (int p = 0; p < 2; ++p) rw[p].load(wptr[p] + k1);
    }
    bf16x8 af[2][2], bfr[4][2];
#pragma unroll
    for (int mb = 0; mb < 2; ++mb) {
      af[mb][0] = *(bf16x8*)&Al[cur][(wr + mb*16 + lm)*72 + lq*8];
      af[mb][1] = *(bf16x8*)&Al[cur][(wr + mb*16 + lm)*72 + 32 + lq*8];
    }
#pragma unroll
    for (int nb = 0; nb < 4; ++nb) {
      bfr[nb][0] = *(bf16x8*)&Wl[cur][(nb*16 + lm)*72 + lq*8];
      bfr[nb][1] = *(bf16x8*)&Wl[cur][(nb*16 + lm)*72 + 32 + lq*8];
    }
#pragma unroll
    for (int mb = 0; mb < 2; ++mb)
#pragma unroll
      for (int nb = 0; nb < 4; ++nb) {
        acc[mb][nb] = MFMA16(af[mb][0], bfr[nb][0], acc[mb][nb]);
        acc[mb][nb] = MFMA16(af[mb][1], bfr[nb][1], acc[mb][nb]);
      }
    if (pre) {
#pragma unroll
      for (int p = 0; p < 4; ++p)
        *(uint4*)&Al[cur^1][(p*32+srow)*72 + sc8] = ra[p];
#pragma unroll
      for (int p = 0; p < 2; ++p)
        rw[p].storeb(&Wl[cur^1][(p*32+srow)*72 + sc8]);
    }
    __syncthreads();
  }
#pragma unroll
  for (int mb = 0; mb < 2; ++mb) {
#pragma unroll
    for (int nb = 0; nb < 4; ++nb) {
#pragma unroll
      for (int r = 0; r < 4; ++r) {
        int grow = row0 + wr + mb*16 + lq*4 + r;
        int gcol = col0 + nb*16 + lm;
        float v = acc[mb][nb][r] + bias[gcol];
        if (resid) v += resid[(size_t)grow*O + gcol];
        C[(size_t)grow*O + gcol] = (TO)v;
      }
    }
  }
}

// ---------------- MFMA matvec-GEMM, 64x64 tile, BK=64, batched over z --------
// fp16 staging/MFMA (CG phase). Double-buffered LDS + register prefetch:
// one barrier per K-step, global latency hidden under MFMA. Deterministic.
template<typename TA, typename TW, typename TO>
__global__ __launch_bounds__(256) void mv64_kernel(
    const TA* __restrict__ A, int K, const TW* __restrict__ W,
    TO* __restrict__ C, int O,
    const float* __restrict__ resid, const float* __restrict__ lam_ptr,
    const float* __restrict__ rowdiv,
    long zsA, long zsW, long zsC, long zsR)
{
  __shared__ __align__(16) fp16 Al[2][64*72];
  __shared__ __align__(16) fp16 Wl[2][64*72];
  int tid = threadIdx.x;
  int z = blockIdx.z;
  const TA* Az = A + (size_t)z*zsA;
  const TW* Wz = W + (size_t)z*zsW;
  TO* Cz = C + (size_t)z*zsC;
  const float* Rz = resid ? (resid + (size_t)z*zsR) : (const float*)0;
  int row0 = blockIdx.x*64, col0 = blockIdx.y*64;
  int lane = tid & 63, w = tid >> 6;
  int wr = (w>>1)*32, wc = (w&1)*32;
  int lm = lane & 15, lq = lane >> 4;
  int sr0 = tid >> 3, c8 = (tid & 7)*8;
  int sr1 = sr0 + 32;
  floatx4 acc[2][2];
#pragma unroll
  for (int mb = 0; mb < 2; ++mb)
#pragma unroll
    for (int nb = 0; nb < 2; ++nb) acc[mb][nb] = (floatx4){0.f,0.f,0.f,0.f};

  Raw8<TA> a0p, a1p; Raw8<TW> w0p, w1p;
  a0p.load(&Az[(size_t)(row0+sr0)*K + c8]);
  a1p.load(&Az[(size_t)(row0+sr1)*K + c8]);
  w0p.load(&Wz[(size_t)(col0+sr0)*K + c8]);
  w1p.load(&Wz[(size_t)(col0+sr1)*K + c8]);
  a0p.store(&Al[0][sr0*72 + c8]); a1p.store(&Al[0][sr1*72 + c8]);
  w0p.store(&Wl[0][sr0*72 + c8]); w1p.store(&Wl[0][sr1*72 + c8]);
  __syncthreads();

  for (int k0 = 0; k0 < K; k0 += 64) {
    int cur = (k0 >> 6) & 1;
    bool pre = (k0 + 64 < K);
    if (pre) {
      a0p.load(&Az[(size_t)(row0+sr0)*K + k0+64 + c8]);
      a1p.load(&Az[(size_t)(row0+sr1)*K + k0+64 + c8]);
      w0p.load(&Wz[(size_t)(col0+sr0)*K + k0+64 + c8]);
      w1p.load(&Wz[(size_t)(col0+sr1)*K + k0+64 + c8]);
    }
    fp16x8 a0[2], a1[2], b0[2], b1[2];
#pragma unroll
    for (int mb = 0; mb < 2; ++mb) {
      a0[mb] = *(fp16x8*)&Al[cur][(wr + mb*16 + lm)*72 + lq*8];
      a1[mb] = *(fp16x8*)&Al[cur][(wr + mb*16 + lm)*72 + 32 + lq*8];
    }
#pragma unroll
    for (int nb = 0; nb < 2; ++nb) {
      b0[nb] = *(fp16x8*)&Wl[cur][(wc + nb*16 + lm)*72 + lq*8];
      b1[nb] = *(fp16x8*)&Wl[cur][(wc + nb*16 + lm)*72 + 32 + lq*8];
    }
#pragma unroll
    for (int mb = 0; mb < 2; ++mb)
#pragma unroll
      for (int nb = 0; nb < 2; ++nb) {
        acc[mb][nb] = MFMA16H(a0[mb], b0[nb], acc[mb][nb]);
        acc[mb][nb] = MFMA16H(a1[mb], b1[nb], acc[mb][nb]);
      }
    if (pre) {
      a0p.store(&Al[cur^1][sr0*72 + c8]); a1p.store(&Al[cur^1][sr1*72 + c8]);
      w0p.store(&Wl[cur^1][sr0*72 + c8]); w1p.store(&Wl[cur^1][sr1*72 + c8]);
    }
    __syncthreads();
  }
  float lamv = 1.f;
  if (lam_ptr) lamv = softplusf(lam_ptr[0]) + 1e-6f;
#pragma unroll
  for (int mb = 0; mb < 2; ++mb) {
#pragma unroll
    for (int nb = 0; nb < 2; ++nb) {
#pragma unroll
      for (int r = 0; r < 4; ++r) {
        int grow = row0 + wr + mb*16 + lq*4 + r;
        int gcol = col0 + wc + nb*16 + lm;
        float v = acc[mb][nb][r];
        if (rowdiv) v /= rowdiv[(size_t)z*KM + grow];
        if (Rz) v += lamv * Rz[(size_t)grow*O + gcol];
        Cz[(size_t)grow*O + gcol] = (TO)v;
      }
    }
  }
}

// ---------------- fp32 tile GEMM (head only, O=64) ----------------
__global__ __launch_bounds__(256) void gemm_f32_kernel(
    const float* __restrict__ A, int K,
    const float* __restrict__ W, const float* __restrict__ bias,
    float* __restrict__ C, int O)
{
  __shared__ float As[32][68];
  __shared__ float Ws[32][68];
  int t = threadIdx.x;
  int row0 = blockIdx.x * 64;
  int col0 = blockIdx.y * 64;
  int ti = t & 15, tj = t >> 4;
  float acc[4][4] = {};
  for (int k0 = 0; k0 < K; k0 += 32) {
#pragma unroll
    for (int p = 0; p < 2; ++p) {
      int idx = p*256 + t;
      int ar = idx >> 3, af = (idx & 7)*4;
      float4 av = *(const float4*)&A[(size_t)(row0+ar)*K + k0 + af];
      As[af+0][ar] = av.x; As[af+1][ar] = av.y;
      As[af+2][ar] = av.z; As[af+3][ar] = av.w;
      float4 wv = *(const float4*)&W[(size_t)(col0+ar)*K + k0 + af];
      Ws[af+0][ar] = wv.x; Ws[af+1][ar] = wv.y;
      Ws[af+2][ar] = wv.z; Ws[af+3][ar] = wv.w;
    }
    __syncthreads();
#pragma unroll
    for (int kk = 0; kk < 32; ++kk) {
      float4 a4 = *(float4*)&As[kk][ti*4];
      float4 b4 = *(float4*)&Ws[kk][tj*4];
      float a[4] = {a4.x, a4.y, a4.z, a4.w};
      float b[4] = {b4.x, b4.y, b4.z, b4.w};
#pragma unroll
      for (int x = 0; x < 4; ++x)
#pragma unroll
        for (int y = 0; y < 4; ++y) acc[x][y] += a[x]*b[y];
    }
    __syncthreads();
  }
#pragma unroll
  for (int x = 0; x < 4; ++x) {
    int r = row0 + ti*4 + x;
#pragma unroll
    for (int y = 0; y < 4; ++y) {
      int c = col0 + tj*4 + y;
      float v = fmaxf(acc[x][y] + bias[c], 0.f);
      C[(size_t)r*O + c] = v;
    }
  }
}

// ---------------- transpose-init: PT=RT=F^T, XT=0 (no atomics) --------------
__global__ __launch_bounds__(256) void tinit_kernel(
    const float* __restrict__ F, float* __restrict__ PT, float* __restrict__ RT,
    float* __restrict__ XT)
{
  __shared__ float Ls[64][68];
  int t = threadIdx.x;
  int k0 = blockIdx.x*64, n0 = blockIdx.y*64, z = blockIdx.z;
#pragma unroll
  for (int p = 0; p < 4; ++p) {
    int idx = p*256 + t;
    int kr = idx >> 4, c4 = (idx & 15)*4;
    *(float4*)&Ls[kr][c4] = *(const float4*)&F[((size_t)z*KM + k0+kr)*DD + n0 + c4];
  }
  __syncthreads();
#pragma unroll
  for (int p = 0; p < 4; ++p) {
    int idx = p*256 + t;
    int nl = idx >> 4, k4 = (idx & 15)*4;
    float4 v = { Ls[k4+0][nl], Ls[k4+1][nl], Ls[k4+2][nl], Ls[k4+3][nl] };
    size_t o = ((size_t)z*DD + n0+nl)*KM + k0 + k4;
    *(float4*)&PT[o] = v;
    *(float4*)&RT[o] = v;
    float4 zr = {0.f,0.f,0.f,0.f};
    *(float4*)&XT[o] = zr;
  }
}

// ---------------- merged CG update (self-contained, deterministic) ----------
// One block per state row (KM=1024, float4 per thread). rr and pAp via
// fixed-order wave butterflies + 4-slot LDS combine — no fp atomics.
__global__ __launch_bounds__(256) void cg_update_kernel(
    float* __restrict__ XT, float* __restrict__ RT,
    float* __restrict__ PT, const float* __restrict__ APT)
{
  __shared__ float redw[12];
  int row = blockIdx.x;
  int t = threadIdx.x;
  int lane = t & 63, w = t >> 6;
  size_t base = (size_t)row*KM + (size_t)t*4;
  float4 p4 = *(float4*)&PT[base];
  float4 a4 = *(const float4*)&APT[base];
  float4 r4 = *(float4*)&RT[base];
  float4 x4 = *(float4*)&XT[base];
  float prr  = (r4.x*r4.x + r4.y*r4.y) + (r4.z*r4.z + r4.w*r4.w);
  float ppap = (p4.x*a4.x + p4.y*a4.y) + (p4.z*a4.z + p4.w*a4.w);
  prr = wred(prr); ppap = wred(ppap);
  if (lane == 0) { redw[w] = prr; redw[4+w] = ppap; }
  __syncthreads();
  float rr  = (redw[0]+redw[1]) + (redw[2]+redw[3]);
  float pap = (redw[4]+redw[5]) + (redw[6]+redw[7]);
  float alpha = (pap > 1e-30f) ? rr/pap : 0.f;
  x4.x += alpha*p4.x; x4.y += alpha*p4.y; x4.z += alpha*p4.z; x4.w += alpha*p4.w;
  r4.x -= alpha*a4.x; r4.y -= alpha*a4.y; r4.z -= alpha*a4.z; r4.w -= alpha*a4.w;
  *(float4*)&XT[base] = x4;
  *(float4*)&RT[base] = r4;
  float s = (r4.x*r4.x + r4.y*r4.y) + (r4.z*r4.z + r4.w*r4.w);
  s = wred(s);
  if (lane == 0) redw[8+w] = s;
  __syncthreads();
  float rrnew = (redw[8]+redw[9]) + (redw[10]+redw[11]);
  float beta = (rr > 1e-30f) ? rrnew/rr : 0.f;
  p4.x = r4.x + beta*p4.x; p4.y = r4.y + beta*p4.y;
  p4.z = r4.z + beta*p4.z; p4.w = r4.w + beta*p4.w;
  *(float4*)&PT[base] = p4;
}

// ---------------- RoPE (coalesced, de-interleaved QKV) ----------------
// QKV layout per row: [q 0..255 | k 256..511 | v 512..767]; pair rotation is
// in-thread. 0.125*log2e folded into Q. 2 rows per 256-thread block.
__global__ __launch_bounds__(256) void rope_split_kernel(
    const bf16* __restrict__ qkv, const float* __restrict__ enc0,
    const float* __restrict__ enc1, bf16* __restrict__ Qo,
    bf16* __restrict__ Ko)
{
  int t = threadIdx.x;
  int r = blockIdx.x*2 + (t >> 7);
  int c = (t & 127)*2;                    // even col
  int ts = r >> 10, i = r & 1023;
  int d = c & 63;
  const float* enc = (ts < BB) ? enc0 : enc1;
  int s = (ts < BB) ? ts : ts - BB;
  const float* eb = enc + (((size_t)s*2)*KM + i)*HD;
  float2 cs = *(const float2*)&eb[d];
  float2 sn = *(const float2*)&eb[(size_t)KM*HD + d];
  size_t base = (size_t)r*768;
  bf16x2 qv = *(const bf16x2*)&qkv[base + c];
  bf16x2 kv = *(const bf16x2*)&qkv[base + 256 + c];
  float q0 = (float)qv[0], q1 = (float)qv[1];
  float k0 = (float)kv[0], k1 = (float)kv[1];
  float oq0 = q0*cs.x - q1*sn.x, oq1 = q1*cs.y + q0*sn.y;
  float ok0 = k0*cs.x - k1*sn.x, ok1 = k1*cs.y + k0*sn.y;
  size_t o = (size_t)r*DD + c;
  bf16x2 qo = {(bf16)(0.1803368801f*oq0), (bf16)(0.1803368801f*oq1)};
  bf16x2 ko = {(bf16)ok0, (bf16)ok1};
  *(bf16x2*)&Qo[o] = qo;
  *(bf16x2*)&Ko[o] = ko;
}

// ---------------- V -> V^T transpose (per (stream,head)), strided src -------
// src row k of (ts,h): Vin[((size_t)ts*KM + k)*vstride + h*HD + d]
// out: VT[((ts*4+h)*HD + d)*KM + k]
__global__ __launch_bounds__(256) void vt_kernel(
    const bf16* __restrict__ Vin, int vstride, bf16* __restrict__ VT)
{
  __shared__ __align__(16) bf16 Ls[64*72];
  int tid = threadIdx.x;
  int zh = blockIdx.x;
  int ts = zh >> 2, h = zh & 3;
  int k0 = blockIdx.y * 64;
#pragma unroll
  for (int p = 0; p < 2; ++p) {
    int idx = p*256 + tid;
    int kr = idx >> 3, c8 = (idx & 7)*8;
    *(uint4*)&Ls[kr*72 + c8] =
      *(const uint4*)&Vin[((size_t)ts*KM + k0 + kr)*vstride + h*HD + c8];
  }
  __syncthreads();
#pragma unroll
  for (int p = 0; p < 2; ++p) {
    int idx = p*256 + tid;
    int dr = idx >> 3, k8 = (idx & 7)*8;
    bf16 tmp[8] __attribute__((aligned(16)));
#pragma unroll
    for (int j = 0; j < 8; ++j) tmp[j] = Ls[(k8+j)*72 + dr];
    *(uint4*)&VT[((size_t)zh*HD + dr)*KM + k0 + k8] = *(uint4*)tmp;
  }
}

// ---------------- MFMA flash attention body (S^T scheme, V^T input) ----------
// Round-8 proven structure: single-buffer, 2 barriers/tile, setprio,
// MFMA-computed row-sum, branch-local max shfls, bias-in-accumulator softmax
// (QK MFMA C-operand = -m_; common path is exp2(st) with no subtract).
__device__ __forceinline__ void mha_body(
    const bf16* __restrict__ Qg, const bf16* __restrict__ Kg,
    const bf16* __restrict__ VTg, bf16* __restrict__ Og,
    size_t qkbase, size_t obase, size_t vbase, int qkstride,
    int q0, int tid, bf16* Qs, bf16* Ks, bf16* Vt)
{
  int lane = tid & 63, w = tid >> 6;
  int lm = lane & 15, lq = lane >> 4;
  int r0 = tid >> 3, c8 = (tid & 7)*8;
  int r1 = r0 + 32;
  *(uint4*)&Qs[SWZ(r0,c8)] = *(const uint4*)&Qg[qkbase + (size_t)(q0+r0)*qkstride + c8];
  *(uint4*)&Qs[SWZ(r1,c8)] = *(const uint4*)&Qg[qkbase + (size_t)(q0+r1)*qkstride + c8];
  __syncthreads();
  bf16x8 qa0 = *(bf16x8*)&Qs[SWZ(w*16 + lm, lq*8)];
  bf16x8 qa1 = *(bf16x8*)&Qs[SWZ(w*16 + lm, 32 + lq*8)];
  short4v ones4;
  { bf16x4 o1 = {(bf16)1.f,(bf16)1.f,(bf16)1.f,(bf16)1.f};
    __builtin_memcpy(&ones4, &o1, 8); }
  float m_ = 0.f;
  floatx4 lacc = (floatx4){0.f,0.f,0.f,0.f};
  floatx4 oacc[4];
#pragma unroll
  for (int db = 0; db < 4; ++db) oacc[db] = (floatx4){0.f,0.f,0.f,0.f};

  for (int kt = 0; kt < KM; kt += 64) {
    __syncthreads();
    *(uint4*)&Ks[SWZ(r0,c8)] = *(const uint4*)&Kg[qkbase + (size_t)(kt+r0)*qkstride + c8];
    *(uint4*)&Ks[SWZ(r1,c8)] = *(const uint4*)&Kg[qkbase + (size_t)(kt+r1)*qkstride + c8];
    *(uint4*)&Vt[SWZ(r0,c8)] = *(const uint4*)&VTg[vbase + (size_t)r0*KM + kt + c8];
    *(uint4*)&Vt[SWZ(r1,c8)] = *(const uint4*)&VTg[vbase + (size_t)r1*KM + kt + c8];
    __syncthreads();
    floatx4 st[4];
    float negm = -m_;
    __builtin_amdgcn_s_setprio(1);
#pragma unroll
    for (int kb = 0; kb < 4; ++kb) {
      bf16x8 a0 = *(bf16x8*)&Ks[SWZ(kb*16 + lm, lq*8)];
      bf16x8 a1 = *(bf16x8*)&Ks[SWZ(kb*16 + lm, 32 + lq*8)];
      floatx4 acc = (floatx4){negm, negm, negm, negm};
      acc = MFMA16(a0, qa0, acc);
      acc = MFMA16(a1, qa1, acc);
      st[kb] = acc;
    }
    __builtin_amdgcn_s_setprio(0);
    // local max, max3-shaped (16 -> 8 ops)
    float ma = fmaxf(fmaxf(st[0][0], st[0][1]), st[0][2]);
    float mb = fmaxf(fmaxf(st[0][3], st[1][0]), st[1][1]);
    float mc = fmaxf(fmaxf(st[1][2], st[1][3]), st[2][0]);
    float md = fmaxf(fmaxf(st[2][1], st[2][2]), st[2][3]);
    float me = fmaxf(fmaxf(st[3][0], st[3][1]), st[3][2]);
    float mf = fmaxf(fmaxf(ma, mb), st[3][3]);
    float mg = fmaxf(fmaxf(mc, md), me);
    float mx = fmaxf(mf, mg);
    // defer-max: wave-uniform test; shfls + subs only when a rescale is needed
    if (!__all(mx <= 8.f)) {
      float wmx = fmaxf(mx, __shfl_xor(mx, 16));
      wmx = fmaxf(wmx, __shfl_xor(wmx, 32));
      float delta = fmaxf(wmx, 0.f);
      float al = exp2f(-delta);
      m_ += delta;
      lacc[0] *= al; lacc[1] *= al; lacc[2] *= al; lacc[3] *= al;
#pragma unroll
      for (int db = 0; db < 4; ++db) {
        oacc[db][0] *= al; oacc[db][1] *= al;
        oacc[db][2] *= al; oacc[db][3] *= al;
      }
#pragma unroll
      for (int kb = 0; kb < 4; ++kb) {
        st[kb][0] -= delta; st[kb][1] -= delta;
        st[kb][2] -= delta; st[kb][3] -= delta;
      }
    }
    __builtin_amdgcn_s_setprio(1);
#pragma unroll
    for (int kb = 0; kb < 4; ++kb) {
      float p0 = exp2f(st[kb][0]);
      float p1 = exp2f(st[kb][1]);
      float p2 = exp2f(st[kb][2]);
      float p3 = exp2f(st[kb][3]);
      short4v pb = pack4(p0, p1, p2, p3);
      lacc = MFMA1K(ones4, pb, lacc);
#pragma unroll
      for (int db = 0; db < 4; ++db) {
        short4v va = *(const short4v*)&Vt[SWZ(db*16 + lm, kb*16 + lq*4)];
        oacc[db] = MFMA1K(va, pb, oacc[db]);
      }
    }
    __builtin_amdgcn_s_setprio(0);
  }
  float inv = 1.f / lacc[0];
  int q = q0 + w*16 + lm;
#pragma unroll
  for (int db = 0; db < 4; ++db) {
    bf16x4 o4 = { (bf16)(oacc[db][0]*inv), (bf16)(oacc[db][1]*inv),
                  (bf16)(oacc[db][2]*inv), (bf16)(oacc[db][3]*inv) };
    *(bf16x4*)&Og[obase + (size_t)q*DD + db*16 + lq*4] = o4;
  }
}

// self attention: grid (zh=64, qtile=16); Q/K row stride 256
__global__ __launch_bounds__(256) void mha_kernel(
    const bf16* __restrict__ Qg, const bf16* __restrict__ Kg,
    const bf16* __restrict__ VTg, bf16* __restrict__ Og)
{
  __shared__ __align__(16) bf16 Qs[64*64];
  __shared__ __align__(16) bf16 Ks[64*64];
  __shared__ __align__(16) bf16 Vt[64*64];
  int zh = blockIdx.x;
  int z = zh >> 2, h = zh & 3;
  size_t base = ((size_t)z*KM)*DD + (size_t)h*HD;
  size_t vbase = (size_t)zh*HD*KM;
  mha_body(Qg, Kg, VTg, Og, base, base, vbase, DD,
           blockIdx.y*64, threadIdx.x, Qs, Ks, Vt);
}

// cross attention, both directions: grid (zh=32, qtile=16, dir=2)
// Q/K live in QKV2 (row stride 512, q at col 0..255, v projected separately)
__global__ __launch_bounds__(256) void mha_cross_kernel(
    const bf16* __restrict__ QKV2, const bf16* __restrict__ VT2,
    bf16* __restrict__ ATTO2)
{
  __shared__ __align__(16) bf16 Qs[64*64];
  __shared__ __align__(16) bf16 Ks[64*64];
  __shared__ __align__(16) bf16 Vt[64*64];
  int dir = blockIdx.z;
  const bf16* Qg  = QKV2 + (dir ? (size_t)BN*512 : 0);
  const bf16* Kg  = QKV2 + (dir ? 0 : (size_t)BN*512);
  const bf16* VTg = VT2  + (dir ? 0 : (size_t)32*HD*KM);
  bf16*       Og  = ATTO2 + (dir ? (size_t)BN*DD : 0);
  int zh = blockIdx.x;
  int z = zh >> 2, h = zh & 3;
  size_t qkbase = ((size_t)z*KM)*512 + (size_t)h*HD;
  size_t obase  = ((size_t)z*KM)*DD  + (size_t)h*HD;
  size_t vbase  = (size_t)zh*HD*KM;
  mha_body(Qg, Kg, VTg, Og, qkbase, obase, vbase, 512,
           blockIdx.y*64, threadIdx.x, Qs, Ks, Vt);
}

// ---------------- in-place LayerNorm + exact GELU (bf16, width 512) --------
// One wave per row (4 rows per block): bf16x8 loads, pure shuffle-butterfly
// reductions, zero __syncthreads. Deterministic fixed-order sums.
__global__ __launch_bounds__(256) void ln_gelu_kernel(
    bf16* __restrict__ Hb, const float* __restrict__ g,
    const float* __restrict__ be)
{
  int t = threadIdx.x;
  int lane = t & 63, w = t >> 6;
  size_t r = (size_t)blockIdx.x*4 + w;
  bf16* rowp = Hb + r*512 + lane*8;
  bf16x8 hv = *(bf16x8*)rowp;
  float x[8];
#pragma unroll
  for (int j = 0; j < 8; ++j) x[j] = (float)hv[j];
  float s = ((x[0]+x[1]) + (x[2]+x[3])) + ((x[4]+x[5]) + (x[6]+x[7]));
  s = wred(s);
  float mu = s * (1.f/512.f);
  float v = 0.f;
#pragma unroll
  for (int j = 0; j < 8; ++j) { float d = x[j] - mu; v += d*d; }
  v = wred(v);
  float rstd = rsqrtf(v*(1.f/512.f) + 1e-5f);
  float4 g0 = *(const float4*)&g[lane*8];
  float4 g1 = *(const float4*)&g[lane*8 + 4];
  float4 b0 = *(const float4*)&be[lane*8];
  float4 b1 = *(const float4*)&be[lane*8 + 4];
  float gv[8] = {g0.x,g0.y,g0.z,g0.w,g1.x,g1.y,g1.z,g1.w};
  float bv[8] = {b0.x,b0.y,b0.z,b0.w,b1.x,b1.y,b1.z,b1.w};
  bf16x8 ov;
#pragma unroll
  for (int j = 0; j < 8; ++j) {
    float h = (x[j] - mu)*rstd*gv[j] + bv[j];
    h = 0.5f*h*(1.f + erff(h*0.70710678118f));
    ov[j] = (bf16)h;
  }
  *(bf16x8*)rowp = ov;
}

// ---------------- final head 2 ----------------
__global__ __launch_bounds__(256) void head2_kernel(
    const float* __restrict__ Hb, const float* __restrict__ w,
    const float* __restrict__ b, float* __restrict__ out)
{
  int r = blockIdx.x*256 + threadIdx.x;
  float acc = b[0];
#pragma unroll
  for (int k = 0; k < 64; ++k) acc += Hb[(size_t)r*64 + k]*w[k];
  out[r] = 1.f/(1.f + expf(-acc));
}

extern "C" void kernel_launch(void* const* d_in, const int* in_sizes, int n_in,
                              void* d_out, int out_size, void* d_ws, size_t ws_size,
                              hipStream_t stream)
{
  (void)in_sizes; (void)n_in; (void)out_size; (void)ws_size;
  const float* fa      = (const float*)d_in[0];
  const float* fb      = (const float*)d_in[1];
  const int*   matches = (const int*)d_in[2];
  const float* ka      = (const float*)d_in[3];
  const float* kb      = (const float*)d_in[4];
  const float* lam     = (const float*)d_in[5];
  const float* beta    = (const float*)d_in[6];
  const float* Wr      = (const float*)d_in[7];
  const float* pW1     = (const float*)d_in[8];
  const float* pb1     = (const float*)d_in[9];
  const float* pW2     = (const float*)d_in[10];
  const float* pb2     = (const float*)d_in[11];
  const float* sWqkv   = (const float*)d_in[12];
  const float* sbqkv   = (const float*)d_in[13];
  const float* sWo     = (const float*)d_in[14];
  const float* sbo     = (const float*)d_in[15];
  const float* sW1     = (const float*)d_in[16];
  const float* sb1     = (const float*)d_in[17];
  const float* sg      = (const float*)d_in[18];
  const float* sbe     = (const float*)d_in[19];
  const float* sW2     = (const float*)d_in[20];
  const float* sb2     = (const float*)d_in[21];
  const float* cWqk    = (const float*)d_in[22];
  const float* cbqk    = (const float*)d_in[23];
  const float* cWv     = (const float*)d_in[24];
  const float* cbv     = (const float*)d_in[25];
  const float* cWo     = (const float*)d_in[26];
  const float* cbo     = (const float*)d_in[27];
  const float* cW1     = (const float*)d_in[28];
  const float* cb1     = (const float*)d_in[29];
  const float* cgw     = (const float*)d_in[30];
  const float* cbe     = (const float*)d_in[31];
  const float* cW2     = (const float*)d_in[32];
  const float* cb2     = (const float*)d_in[33];

  char* wsb = (char*)d_ws;
  float* DCAT = (float*)wsb;                      // 16,777,216 B
  float* ENC0 = (float*)(wsb + 16777216);
  float* ENC1 = (float*)(wsb + 20971520);
  float* XY0  = (float*)(wsb + 25165824);
  float* XY1  = (float*)(wsb + 25231360);
  float* ROWS = (float*)(wsb + 25296896);
  char*  POOL = wsb + 25354240;
  const size_t SLOT = 8388608;
  // CG phase
  fp16*  KMATH = (fp16*)POOL;                    // slots 0-1
  float* FBUF  = (float*)(POOL + 2*SLOT);
  float* PT    = (float*)(POOL + 3*SLOT);
  float* RT    = (float*)(POOL + 4*SLOT);
  float* XT    = (float*)(POOL + 5*SLOT);
  float* APT   = (float*)(POOL + 6*SLOT);
  // transformer phase
  bf16*  QKV   = (bf16*)POOL;                    // slots 0-2 (q|k|v cols)
  bf16*  QR    = (bf16*)(POOL + 3*SLOT);
  bf16*  KR    = (bf16*)(POOL + 4*SLOT);
  bf16*  VTG   = (bf16*)(POOL + 8*SLOT);         // slot 8 (V^T, self)
  bf16*  ATTO  = (bf16*)POOL;                    // slot 0
  bf16*  MSG   = (bf16*)(POOL + 1*SLOT);
  bf16*  H1    = (bf16*)(POOL + 6*SLOT);         // slots 6-7
  bf16*  QKV2  = (bf16*)POOL;                    // slots 0-1 (cross q|v cols)
  bf16*  ATTO2 = (bf16*)(POOL + 2*SLOT);
  bf16*  MSG2  = (bf16*)(POOL + 3*SLOT);
  bf16*  VT2   = (bf16*)(POOL + 4*SLOT);         // slot 4 (V^T, cross)
  bf16*  H1C   = H1;
  float* HBUF  = (float*)POOL;

  const float scq = 0.42466090f;   // 64^-0.25 * sqrt(log2 e)

  // ---- gather / posenc / Kmat ----
  gather_kernel<<<BN, 256, 0, stream>>>(fa, fb, matches, ka, kb, FBUF, DCAT, XY0, XY1);
  posenc_kernel<<<BN/4, 256, 0, stream>>>(XY0, Wr, ENC0);
  posenc_kernel<<<BN/4, 256, 0, stream>>>(XY1, Wr, ENC1);
  kmat_kernel<<<BN, 256, 0, stream>>>(XY0, beta, KMATH, ROWS);

  // ---- CG (transposed state, deterministic: no fp atomics anywhere) ----
  tinit_kernel<<<dim3(16,4,BB), 256, 0, stream>>>(FBUF, PT, RT, XT);
  for (int it = 0; it < CG_ITERS; ++it) {
    mv64_kernel<float,fp16,float><<<dim3(4,16,BB), 256, 0, stream>>>(
        PT, 1024, KMATH, APT, 1024, PT, lam, (const float*)0,
        262144, 1048576, 262144, 262144);
    cg_update_kernel<<<2048, 256, 0, stream>>>(XT, RT, PT, APT);
  }

  // ---- d1 = rownorm(Kmat) @ C  (d0 = f_i already written by gather) ----
  mv64_kernel<fp16,float,float><<<dim3(16,4,BB), 256, 0, stream>>>(
      KMATH, 1024, XT, DCAT + (size_t)BN*DD, 256,
      (const float*)0, (const float*)0, ROWS,
      1048576, 262144, 262144, 0);

  // ---- transformer layers ----
  for (int l = 0; l < NLAYER; ++l) {
    // self block
    mm_kernel<128,1,0,float,float,float,bf16><<<dim3(128,6,1), 256, 0, stream>>>(
        DCAT, (const float*)0, 256, 256, sWqkv + (size_t)l*768*256, sbqkv + l*768,
        (const float*)0, (const float*)0, QKV, 768, 1.f, 1.f, (const float*)0);
    rope_split_kernel<<<8192, 256, 0, stream>>>(QKV, ENC0, ENC1, QR, KR);
    vt_kernel<<<dim3(64,16), 256, 0, stream>>>(QKV + 512, 768, VTG);
    mha_kernel<<<dim3(64,16), 256, 0, stream>>>(QR, KR, VTG, ATTO);
    mm64_kernel<bf16><<<dim3(128,4,1), 256, 0, stream>>>(
        ATTO, 256, sWo + (size_t)l*256*256, sbo + l*256, MSG, 256,
        (const float*)0);
    mm_kernel<128,0,0,float,bf16,float,bf16><<<dim3(128,4,1), 256, 0, stream>>>(
        DCAT, MSG, 256, 512, sW1 + (size_t)l*512*512, sb1 + l*512,
        (const float*)0, (const float*)0, H1, 512, 1.f, 1.f, (const float*)0);
    ln_gelu_kernel<<<N2/4, 256, 0, stream>>>(H1, sg + l*512, sbe + l*512);
    mm64_kernel<float><<<dim3(128,4,1), 256, 0, stream>>>(
        H1, 512, sW2 + (size_t)l*256*512, sb2 + l*256, DCAT, 256, DCAT);
    // cross block: fused qk|v projection into QKV2 (row stride 512)
    mm_kernel<128,0,1,float,float,float,bf16><<<dim3(128,4,1), 256, 0, stream>>>(
        DCAT, (const float*)0, 256, 256, cWqk + (size_t)l*256*256, cbqk + l*256,
        cWv + (size_t)l*256*256, cbv + l*256, QKV2, 512, scq, 1.f,
        (const float*)0);
    vt_kernel<<<dim3(64,16), 256, 0, stream>>>(QKV2 + 256, 512, VT2);
    mha_cross_kernel<<<dim3(32,16,2), 256, 0, stream>>>(QKV2, VT2, ATTO2);
    mm64_kernel<bf16><<<dim3(128,4,1), 256, 0, stream>>>(
        ATTO2, 256, cWo + (size_t)l*256*256, cbo + l*256, MSG2, 256,
        (const float*)0);
    mm_kernel<128,0,0,float,bf16,float,bf16><<<dim3(128,4,1), 256, 0, stream>>>(
        DCAT, MSG2, 256, 512, cW1 + (size_t)l*512*512, cb1 + l*512,
        (const float*)0, (const float*)0, H1C, 512, 1.f, 1.f, (const float*)0);
    ln_gelu_kernel<<<N2/4, 256, 0, stream>>>(H1C, cgw + l*512, cbe + l*512);
    mm64_kernel<float><<<dim3(128,4,1), 256, 0, stream>>>(
        H1C, 512, cW2 + (size_t)l*256*512, cb2 + l*256, DCAT, 256, DCAT);
  }

  // ---- head ----
  gemm_f32_kernel<<<dim3(128,1), 256, 0, stream>>>(DCAT, 256, pW1, pb1, HBUF, 64);
  head2_kernel<<<32, 256, 0, stream>>>(HBUF, pW2, pb2, (float*)d_out);
}

// Round 13
// 1024.688 us; speedup vs baseline: 1.1277x; 1.1277x over previous
//
#include <hip/hip_runtime.h>
#include <math.h>

// Problem constants
#define BB 8
#define MM 2048
#define KM 1024
#define DD 256
#define HH 4
#define HD 64
#define NLAYER 2
#define BN (BB*KM)        // 8192 rows per "decoder half"
#define N2 (2*BN)         // 16384 rows d0||d1
#define CG_ITERS 5

// XOR-swizzled LDS addressing for the attention tiles: stride 64 (no pad),
// 16-byte blocks permuted by row. Conflict-free for uint4 stores, bf16x8
// reads, and short4v reads — and keeps every access 16B/8B aligned.
#define SWZ(r,c) (((r)<<6) + ((((c)>>3) ^ ((r)&7))<<3) + ((c)&7))

typedef __bf16 bf16;
typedef __bf16 bf16x8 __attribute__((ext_vector_type(8)));
typedef __bf16 bf16x4 __attribute__((ext_vector_type(4)));
typedef __bf16 bf16x2 __attribute__((ext_vector_type(2)));
typedef _Float16 fp16;
typedef _Float16 fp16x8 __attribute__((ext_vector_type(8)));
typedef short  short4v __attribute__((ext_vector_type(4)));
typedef float  floatx4 __attribute__((ext_vector_type(4)));
#define MFMA16(a,b,c)  __builtin_amdgcn_mfma_f32_16x16x32_bf16(a,b,c,0,0,0)
#define MFMA16H(a,b,c) __builtin_amdgcn_mfma_f32_16x16x32_f16(a,b,c,0,0,0)

// K=16 bf16 MFMA (PV stage: S^T C-frag == its B-operand layout).
#if defined(__HIP_DEVICE_COMPILE__)
  #if __has_builtin(__builtin_amdgcn_mfma_f32_16x16x16bf16_1k)
    #define MFMA1K(a,b,c) __builtin_amdgcn_mfma_f32_16x16x16bf16_1k(a,b,c,0,0,0)
  #else
    #error "device pass lacks mfma_f32_16x16x16bf16_1k"
  #endif
#else
  #define MFMA1K(a,b,c) (c)   /* host stub, never executed */
#endif

__device__ __forceinline__ float softplusf(float x) {
  return fmaxf(x, 0.f) + log1pf(expf(-fabsf(x)));
}

__device__ __forceinline__ float wred(float x) {
  x += __shfl_xor(x, 1);  x += __shfl_xor(x, 2);  x += __shfl_xor(x, 4);
  x += __shfl_xor(x, 8);  x += __shfl_xor(x, 16); x += __shfl_xor(x, 32);
  return x;
}

__device__ __forceinline__ short4v pack4(float a, float b, float c, float d) {
  bf16x4 v = {(bf16)a,(bf16)b,(bf16)c,(bf16)d};
  short4v s;
  __builtin_memcpy(&s, &v, 8);
  return s;
}

// stage 8 elements (convert to bf16 if needed), 16B LDS store
__device__ __forceinline__ void stage8(bf16* dst, const float* src) {
  float4 a = *(const float4*)src;
  float4 b = *(const float4*)(src + 4);
  bf16x8 v = { (bf16)a.x,(bf16)a.y,(bf16)a.z,(bf16)a.w,
               (bf16)b.x,(bf16)b.y,(bf16)b.z,(bf16)b.w };
  *(bf16x8*)dst = v;
}
__device__ __forceinline__ void stage8(bf16* dst, const bf16* src) {
  *(uint4*)dst = *(const uint4*)src;
}

// raw staging to fp16 LDS (CG phase)
template<typename T> struct Raw8;
template<> struct Raw8<float> {
  float4 a, b;
  __device__ __forceinline__ void load(const float* s) {
    a = *(const float4*)s; b = *(const float4*)(s + 4);
  }
  __device__ __forceinline__ void store(fp16* d) const {
    fp16x8 v = { (fp16)a.x,(fp16)a.y,(fp16)a.z,(fp16)a.w,
                 (fp16)b.x,(fp16)b.y,(fp16)b.z,(fp16)b.w };
    *(fp16x8*)d = v;
  }
};
template<> struct Raw8<fp16> {
  uint4 u;
  __device__ __forceinline__ void load(const fp16* s) { u = *(const uint4*)s; }
  __device__ __forceinline__ void store(fp16* d) const { *(uint4*)d = u; }
};

// ---------------- gather (writes F to both FBUF and DCAT; no copy pass) -----
__global__ __launch_bounds__(256) void gather_kernel(
    const float* __restrict__ fa, const float* __restrict__ fb,
    const int* __restrict__ matches, const float* __restrict__ ka,
    const float* __restrict__ kb, float* __restrict__ F,
    float* __restrict__ Fd,
    float* __restrict__ xy0, float* __restrict__ xy1)
{
  int si = blockIdx.x;
  int s  = si >> 10;
  int t  = threadIdx.x;
  int ia = matches[(size_t)si*2+0];
  int ib = matches[(size_t)si*2+1];
  float v = fb[((size_t)s*MM + ib)*DD + t] - fa[((size_t)s*MM + ia)*DD + t];
  F[(size_t)si*DD + t]  = v;
  Fd[(size_t)si*DD + t] = v;
  if (t == 0) {
    xy0[(size_t)si*2+0] = ka[((size_t)s*MM + ia)*2+0];
    xy0[(size_t)si*2+1] = ka[((size_t)s*MM + ia)*2+1];
    xy1[(size_t)si*2+0] = kb[((size_t)s*MM + ib)*2+0];
    xy1[(size_t)si*2+1] = kb[((size_t)s*MM + ib)*2+1];
  }
}

// ---------------- positional encoding (4 rows per 256-thread block) ---------
__global__ __launch_bounds__(256) void posenc_kernel(
    const float* __restrict__ xy, const float* __restrict__ Wr,
    float* __restrict__ enc)
{
  int t = threadIdx.x;
  int si = blockIdx.x*4 + (t >> 6);
  int s = si >> 10, i = si & 1023;
  int d = t & 63; int p = d >> 1;
  float x = xy[(size_t)si*2], y = xy[(size_t)si*2+1];
  float pr = Wr[p*2]*x + Wr[p*2+1]*y;
  enc[(((size_t)s*2+0)*KM + i)*HD + d] = cosf(pr);
  enc[(((size_t)s*2+1)*KM + i)*HD + d] = sinf(pr);
}

// ---------------- Kmat (fp16) + rowsum (wave butterflies) -------------------
// exp2f with beta*log2e folded: single v_exp_f32 instead of libm expf; the
// <=1ulp f32 delta is far below the fp16 quantization of Km.
__global__ __launch_bounds__(256) void kmat_kernel(
    const float* __restrict__ xy0, const float* __restrict__ beta_ptr,
    fp16* __restrict__ Km, float* __restrict__ rowsum)
{
  __shared__ float redw[4];
  int si = blockIdx.x; int s = si >> 10;
  int t = threadIdx.x;
  int lane = t & 63, w = t >> 6;
  float beta_l2 = softplusf(beta_ptr[0]) * 1.442695040888963f;
  float xi = xy0[(size_t)si*2], yi = xy0[(size_t)si*2+1];
  const float* xys = xy0 + (size_t)s*KM*2;
  float sum = 0.f;
  for (int jj = 0; jj < 4; ++jj) {
    int j = jj*256 + t;
    float dx = xi - xys[j*2], dy = yi - xys[j*2+1];
    float v = exp2f(-beta_l2*(dx*dx + dy*dy));
    Km[(size_t)si*KM + j] = (fp16)v;
    sum += v;
  }
  sum = wred(sum);
  if (lane == 0) redw[w] = sum;
  __syncthreads();
  if (t == 0)
    rowsum[si] = ((redw[0]+redw[1]) + (redw[2]+redw[3])) + 1e-6f;
}

// ---------------- MFMA GEMM, tile 128xNT (NT=128 or 64), BK=64 ----------------
// C = [A1|A2] @ Wsel.T, epilogue (v+bias)*scale (+resid).
// WPERM: W row index perm(j)=(j&255)*3+(j>>8)  (qkv channel de-interleave)
// DUALW: cols [0,256) from W/bias/scale, cols [256,512) from Wb/biasb/scaleb
// Round-8 staging structure (stage8 direct to LDS, 2 barriers/step) with
// k-independent A/W row pointers hoisted out of the K-loop.
template<int NT, int WPERM, int DUALW,
         typename TA1, typename TA2, typename TW, typename TO>
__global__ __launch_bounds__(256) void mm_kernel(
    const TA1* __restrict__ A1, const TA2* __restrict__ A2, int K1, int K,
    const TW* __restrict__ W, const float* __restrict__ bias,
    const TW* __restrict__ Wb, const float* __restrict__ biasb,
    TO* __restrict__ C, int O, float scale, float scaleb,
    const float* __restrict__ resid)
{
  __shared__ __align__(16) bf16 Al[128*72];
  __shared__ __align__(16) bf16 Wl[NT*72];
  constexpr int MB = (NT == 128) ? 4 : 2;
  constexpr int WP = NT/32;
  int tid = threadIdx.x;
  int row0 = blockIdx.x*128, col0 = blockIdx.y*NT;
  int lane = tid & 63, w = tid >> 6;
  int wr = (NT == 128) ? (w>>1)*64 : w*32;
  int wc = (NT == 128) ? (w&1)*64 : 0;
  int lm = lane & 15, lq = lane >> 4;
  int srow = tid >> 3, sc8 = (tid & 7)*8;

  // k-independent source row pointers
  const TA1* aptr1[4]; const TA2* aptr2[4];
#pragma unroll
  for (int p = 0; p < 4; ++p) {
    int row = p*32 + srow;
    aptr1[p] = A1 + (size_t)(row0+row)*K1 + sc8;
    aptr2[p] = A2 + (size_t)(row0+row)*(K-K1) + sc8;
  }
  const TW* wptr[WP];
#pragma unroll
  for (int p = 0; p < WP; ++p) {
    int wg = col0 + p*32 + srow;
    const TW* wsrc; int wrow;
    if (DUALW && wg >= 256) { wsrc = Wb; wrow = wg - 256; }
    else { wsrc = W; wrow = WPERM ? ((wg & 255)*3 + (wg >> 8)) : wg; }
    wptr[p] = wsrc + (size_t)wrow*K + sc8;
  }

  floatx4 acc[MB][4];
#pragma unroll
  for (int mb = 0; mb < MB; ++mb)
#pragma unroll
    for (int nb = 0; nb < 4; ++nb) acc[mb][nb] = (floatx4){0.f,0.f,0.f,0.f};
  for (int k0 = 0; k0 < K; k0 += 64) {
    bool use1 = (k0 < K1);
#pragma unroll
    for (int p = 0; p < 4; ++p) {
      bf16* d = &Al[(p*32+srow)*72 + sc8];
      if (use1) stage8(d, aptr1[p] + k0);
      else      stage8(d, aptr2[p] + (k0 - K1));
    }
#pragma unroll
    for (int p = 0; p < WP; ++p)
      stage8(&Wl[(p*32+srow)*72 + sc8], wptr[p] + k0);
    __syncthreads();
    bf16x8 af[MB][2], bfr[4][2];
#pragma unroll
    for (int mb = 0; mb < MB; ++mb) {
      af[mb][0] = *(bf16x8*)&Al[(wr + mb*16 + lm)*72 + lq*8];
      af[mb][1] = *(bf16x8*)&Al[(wr + mb*16 + lm)*72 + 32 + lq*8];
    }
#pragma unroll
    for (int nb = 0; nb < 4; ++nb) {
      bfr[nb][0] = *(bf16x8*)&Wl[(wc + nb*16 + lm)*72 + lq*8];
      bfr[nb][1] = *(bf16x8*)&Wl[(wc + nb*16 + lm)*72 + 32 + lq*8];
    }
#pragma unroll
    for (int mb = 0; mb < MB; ++mb)
#pragma unroll
      for (int nb = 0; nb < 4; ++nb) {
        acc[mb][nb] = MFMA16(af[mb][0], bfr[nb][0], acc[mb][nb]);
        acc[mb][nb] = MFMA16(af[mb][1], bfr[nb][1], acc[mb][nb]);
      }
    __syncthreads();
  }
#pragma unroll
  for (int mb = 0; mb < MB; ++mb) {
#pragma unroll
    for (int nb = 0; nb < 4; ++nb) {
#pragma unroll
      for (int r = 0; r < 4; ++r) {
        int grow = row0 + wr + mb*16 + lq*4 + r;
        int gcol = col0 + wc + nb*16 + lm;
        float v = acc[mb][nb][r];
        float bv = 0.f, scl = scale;
        if (DUALW && gcol >= 256) {
          if (biasb) bv = biasb[gcol - 256];
          scl = scaleb;
        } else if (bias) {
          bv = bias[WPERM ? ((gcol & 255)*3 + (gcol >> 8)) : gcol];
        }
        v = (v + bv) * scl;
        if (resid) v += resid[(size_t)grow*O + gcol];
        C[(size_t)grow*O + gcol] = (TO)v;
      }
    }
  }
}

// ---------------- MFMA matvec-GEMM, 64x64 tile, BK=64, batched over z --------
// fp16 staging/MFMA (CG phase). Double-buffered LDS + register prefetch:
// one barrier per K-step, global latency hidden under MFMA. Deterministic.
template<typename TA, typename TW, typename TO>
__global__ __launch_bounds__(256) void mv64_kernel(
    const TA* __restrict__ A, int K, const TW* __restrict__ W,
    TO* __restrict__ C, int O,
    const float* __restrict__ resid, const float* __restrict__ lam_ptr,
    const float* __restrict__ rowdiv,
    long zsA, long zsW, long zsC, long zsR)
{
  __shared__ __align__(16) fp16 Al[2][64*72];
  __shared__ __align__(16) fp16 Wl[2][64*72];
  int tid = threadIdx.x;
  int z = blockIdx.z;
  const TA* Az = A + (size_t)z*zsA;
  const TW* Wz = W + (size_t)z*zsW;
  TO* Cz = C + (size_t)z*zsC;
  const float* Rz = resid ? (resid + (size_t)z*zsR) : (const float*)0;
  int row0 = blockIdx.x*64, col0 = blockIdx.y*64;
  int lane = tid & 63, w = tid >> 6;
  int wr = (w>>1)*32, wc = (w&1)*32;
  int lm = lane & 15, lq = lane >> 4;
  int sr0 = tid >> 3, c8 = (tid & 7)*8;
  int sr1 = sr0 + 32;
  floatx4 acc[2][2];
#pragma unroll
  for (int mb = 0; mb < 2; ++mb)
#pragma unroll
    for (int nb = 0; nb < 2; ++nb) acc[mb][nb] = (floatx4){0.f,0.f,0.f,0.f};

  Raw8<TA> a0p, a1p; Raw8<TW> w0p, w1p;
  a0p.load(&Az[(size_t)(row0+sr0)*K + c8]);
  a1p.load(&Az[(size_t)(row0+sr1)*K + c8]);
  w0p.load(&Wz[(size_t)(col0+sr0)*K + c8]);
  w1p.load(&Wz[(size_t)(col0+sr1)*K + c8]);
  a0p.store(&Al[0][sr0*72 + c8]); a1p.store(&Al[0][sr1*72 + c8]);
  w0p.store(&Wl[0][sr0*72 + c8]); w1p.store(&Wl[0][sr1*72 + c8]);
  __syncthreads();

  for (int k0 = 0; k0 < K; k0 += 64) {
    int cur = (k0 >> 6) & 1;
    bool pre = (k0 + 64 < K);
    if (pre) {
      a0p.load(&Az[(size_t)(row0+sr0)*K + k0+64 + c8]);
      a1p.load(&Az[(size_t)(row0+sr1)*K + k0+64 + c8]);
      w0p.load(&Wz[(size_t)(col0+sr0)*K + k0+64 + c8]);
      w1p.load(&Wz[(size_t)(col0+sr1)*K + k0+64 + c8]);
    }
    fp16x8 a0[2], a1[2], b0[2], b1[2];
#pragma unroll
    for (int mb = 0; mb < 2; ++mb) {
      a0[mb] = *(fp16x8*)&Al[cur][(wr + mb*16 + lm)*72 + lq*8];
      a1[mb] = *(fp16x8*)&Al[cur][(wr + mb*16 + lm)*72 + 32 + lq*8];
    }
#pragma unroll
    for (int nb = 0; nb < 2; ++nb) {
      b0[nb] = *(fp16x8*)&Wl[cur][(wc + nb*16 + lm)*72 + lq*8];
      b1[nb] = *(fp16x8*)&Wl[cur][(wc + nb*16 + lm)*72 + 32 + lq*8];
    }
#pragma unroll
    for (int mb = 0; mb < 2; ++mb)
#pragma unroll
      for (int nb = 0; nb < 2; ++nb) {
        acc[mb][nb] = MFMA16H(a0[mb], b0[nb], acc[mb][nb]);
        acc[mb][nb] = MFMA16H(a1[mb], b1[nb], acc[mb][nb]);
      }
    if (pre) {
      a0p.store(&Al[cur^1][sr0*72 + c8]); a1p.store(&Al[cur^1][sr1*72 + c8]);
      w0p.store(&Wl[cur^1][sr0*72 + c8]); w1p.store(&Wl[cur^1][sr1*72 + c8]);
    }
    __syncthreads();
  }
  float lamv = 1.f;
  if (lam_ptr) lamv = softplusf(lam_ptr[0]) + 1e-6f;
#pragma unroll
  for (int mb = 0; mb < 2; ++mb) {
#pragma unroll
    for (int nb = 0; nb < 2; ++nb) {
#pragma unroll
      for (int r = 0; r < 4; ++r) {
        int grow = row0 + wr + mb*16 + lq*4 + r;
        int gcol = col0 + wc + nb*16 + lm;
        float v = acc[mb][nb][r];
        if (rowdiv) v /= rowdiv[(size_t)z*KM + grow];
        if (Rz) v += lamv * Rz[(size_t)grow*O + gcol];
        Cz[(size_t)grow*O + gcol] = (TO)v;
      }
    }
  }
}

// ---------------- fp32 tile GEMM (head only, O=64) ----------------
__global__ __launch_bounds__(256) void gemm_f32_kernel(
    const float* __restrict__ A, int K,
    const float* __restrict__ W, const float* __restrict__ bias,
    float* __restrict__ C, int O)
{
  __shared__ float As[32][68];
  __shared__ float Ws[32][68];
  int t = threadIdx.x;
  int row0 = blockIdx.x * 64;
  int col0 = blockIdx.y * 64;
  int ti = t & 15, tj = t >> 4;
  float acc[4][4] = {};
  for (int k0 = 0; k0 < K; k0 += 32) {
#pragma unroll
    for (int p = 0; p < 2; ++p) {
      int idx = p*256 + t;
      int ar = idx >> 3, af = (idx & 7)*4;
      float4 av = *(const float4*)&A[(size_t)(row0+ar)*K + k0 + af];
      As[af+0][ar] = av.x; As[af+1][ar] = av.y;
      As[af+2][ar] = av.z; As[af+3][ar] = av.w;
      float4 wv = *(const float4*)&W[(size_t)(col0+ar)*K + k0 + af];
      Ws[af+0][ar] = wv.x; Ws[af+1][ar] = wv.y;
      Ws[af+2][ar] = wv.z; Ws[af+3][ar] = wv.w;
    }
    __syncthreads();
#pragma unroll
    for (int kk = 0; kk < 32; ++kk) {
      float4 a4 = *(float4*)&As[kk][ti*4];
      float4 b4 = *(float4*)&Ws[kk][tj*4];
      float a[4] = {a4.x, a4.y, a4.z, a4.w};
      float b[4] = {b4.x, b4.y, b4.z, b4.w};
#pragma unroll
      for (int x = 0; x < 4; ++x)
#pragma unroll
        for (int y = 0; y < 4; ++y) acc[x][y] += a[x]*b[y];
    }
    __syncthreads();
  }
#pragma unroll
  for (int x = 0; x < 4; ++x) {
    int r = row0 + ti*4 + x;
#pragma unroll
    for (int y = 0; y < 4; ++y) {
      int c = col0 + tj*4 + y;
      float v = fmaxf(acc[x][y] + bias[c], 0.f);
      C[(size_t)r*O + c] = v;
    }
  }
}

// ---------------- transpose-init: PT=RT=F^T, XT=0 (no atomics) --------------
__global__ __launch_bounds__(256) void tinit_kernel(
    const float* __restrict__ F, float* __restrict__ PT, float* __restrict__ RT,
    float* __restrict__ XT)
{
  __shared__ float Ls[64][68];
  int t = threadIdx.x;
  int k0 = blockIdx.x*64, n0 = blockIdx.y*64, z = blockIdx.z;
#pragma unroll
  for (int p = 0; p < 4; ++p) {
    int idx = p*256 + t;
    int kr = idx >> 4, c4 = (idx & 15)*4;
    *(float4*)&Ls[kr][c4] = *(const float4*)&F[((size_t)z*KM + k0+kr)*DD + n0 + c4];
  }
  __syncthreads();
#pragma unroll
  for (int p = 0; p < 4; ++p) {
    int idx = p*256 + t;
    int nl = idx >> 4, k4 = (idx & 15)*4;
    float4 v = { Ls[k4+0][nl], Ls[k4+1][nl], Ls[k4+2][nl], Ls[k4+3][nl] };
    size_t o = ((size_t)z*DD + n0+nl)*KM + k0 + k4;
    *(float4*)&PT[o] = v;
    *(float4*)&RT[o] = v;
    float4 zr = {0.f,0.f,0.f,0.f};
    *(float4*)&XT[o] = zr;
  }
}

// ---------------- merged CG update (self-contained, deterministic) ----------
// One block per state row (KM=1024, float4 per thread). rr and pAp via
// fixed-order wave butterflies + 4-slot LDS combine — no fp atomics.
__global__ __launch_bounds__(256) void cg_update_kernel(
    float* __restrict__ XT, float* __restrict__ RT,
    float* __restrict__ PT, const float* __restrict__ APT)
{
  __shared__ float redw[12];
  int row = blockIdx.x;
  int t = threadIdx.x;
  int lane = t & 63, w = t >> 6;
  size_t base = (size_t)row*KM + (size_t)t*4;
  float4 p4 = *(float4*)&PT[base];
  float4 a4 = *(const float4*)&APT[base];
  float4 r4 = *(float4*)&RT[base];
  float4 x4 = *(float4*)&XT[base];
  float prr  = (r4.x*r4.x + r4.y*r4.y) + (r4.z*r4.z + r4.w*r4.w);
  float ppap = (p4.x*a4.x + p4.y*a4.y) + (p4.z*a4.z + p4.w*a4.w);
  prr = wred(prr); ppap = wred(ppap);
  if (lane == 0) { redw[w] = prr; redw[4+w] = ppap; }
  __syncthreads();
  float rr  = (redw[0]+redw[1]) + (redw[2]+redw[3]);
  float pap = (redw[4]+redw[5]) + (redw[6]+redw[7]);
  float alpha = (pap > 1e-30f) ? rr/pap : 0.f;
  x4.x += alpha*p4.x; x4.y += alpha*p4.y; x4.z += alpha*p4.z; x4.w += alpha*p4.w;
  r4.x -= alpha*a4.x; r4.y -= alpha*a4.y; r4.z -= alpha*a4.z; r4.w -= alpha*a4.w;
  *(float4*)&XT[base] = x4;
  *(float4*)&RT[base] = r4;
  float s = (r4.x*r4.x + r4.y*r4.y) + (r4.z*r4.z + r4.w*r4.w);
  s = wred(s);
  if (lane == 0) redw[8+w] = s;
  __syncthreads();
  float rrnew = (redw[8]+redw[9]) + (redw[10]+redw[11]);
  float beta = (rr > 1e-30f) ? rrnew/rr : 0.f;
  p4.x = r4.x + beta*p4.x; p4.y = r4.y + beta*p4.y;
  p4.z = r4.z + beta*p4.z; p4.w = r4.w + beta*p4.w;
  *(float4*)&PT[base] = p4;
}

// ---------------- RoPE (coalesced, de-interleaved QKV) ----------------
// QKV layout per row: [q 0..255 | k 256..511 | v 512..767]; pair rotation is
// in-thread. 0.125*log2e folded into Q. 2 rows per 256-thread block.
__global__ __launch_bounds__(256) void rope_split_kernel(
    const bf16* __restrict__ qkv, const float* __restrict__ enc0,
    const float* __restrict__ enc1, bf16* __restrict__ Qo,
    bf16* __restrict__ Ko)
{
  int t = threadIdx.x;
  int r = blockIdx.x*2 + (t >> 7);
  int c = (t & 127)*2;                    // even col
  int ts = r >> 10, i = r & 1023;
  int d = c & 63;
  const float* enc = (ts < BB) ? enc0 : enc1;
  int s = (ts < BB) ? ts : ts - BB;
  const float* eb = enc + (((size_t)s*2)*KM + i)*HD;
  float2 cs = *(const float2*)&eb[d];
  float2 sn = *(const float2*)&eb[(size_t)KM*HD + d];
  size_t base = (size_t)r*768;
  bf16x2 qv = *(const bf16x2*)&qkv[base + c];
  bf16x2 kv = *(const bf16x2*)&qkv[base + 256 + c];
  float q0 = (float)qv[0], q1 = (float)qv[1];
  float k0 = (float)kv[0], k1 = (float)kv[1];
  float oq0 = q0*cs.x - q1*sn.x, oq1 = q1*cs.y + q0*sn.y;
  float ok0 = k0*cs.x - k1*sn.x, ok1 = k1*cs.y + k0*sn.y;
  size_t o = (size_t)r*DD + c;
  bf16x2 qo = {(bf16)(0.1803368801f*oq0), (bf16)(0.1803368801f*oq1)};
  bf16x2 ko = {(bf16)ok0, (bf16)ok1};
  *(bf16x2*)&Qo[o] = qo;
  *(bf16x2*)&Ko[o] = ko;
}

// ---------------- V -> V^T transpose (per (stream,head)), strided src -------
// src row k of (ts,h): Vin[((size_t)ts*KM + k)*vstride + h*HD + d]
// out: VT[((ts*4+h)*HD + d)*KM + k]
__global__ __launch_bounds__(256) void vt_kernel(
    const bf16* __restrict__ Vin, int vstride, bf16* __restrict__ VT)
{
  __shared__ __align__(16) bf16 Ls[64*72];
  int tid = threadIdx.x;
  int zh = blockIdx.x;
  int ts = zh >> 2, h = zh & 3;
  int k0 = blockIdx.y * 64;
#pragma unroll
  for (int p = 0; p < 2; ++p) {
    int idx = p*256 + tid;
    int kr = idx >> 3, c8 = (idx & 7)*8;
    *(uint4*)&Ls[kr*72 + c8] =
      *(const uint4*)&Vin[((size_t)ts*KM + k0 + kr)*vstride + h*HD + c8];
  }
  __syncthreads();
#pragma unroll
  for (int p = 0; p < 2; ++p) {
    int idx = p*256 + tid;
    int dr = idx >> 3, k8 = (idx & 7)*8;
    bf16 tmp[8] __attribute__((aligned(16)));
#pragma unroll
    for (int j = 0; j < 8; ++j) tmp[j] = Ls[(k8+j)*72 + dr];
    *(uint4*)&VT[((size_t)zh*HD + dr)*KM + k0 + k8] = *(uint4*)tmp;
  }
}

// ---------------- MFMA flash attention body (S^T scheme, V^T input) ----------
// Round-8 proven structure: single-buffer, 2 barriers/tile, setprio,
// MFMA-computed row-sum, branch-local max shfls, bias-in-accumulator softmax
// (QK MFMA C-operand = -m_; common path is exp2(st) with no subtract).
__device__ __forceinline__ void mha_body(
    const bf16* __restrict__ Qg, const bf16* __restrict__ Kg,
    const bf16* __restrict__ VTg, bf16* __restrict__ Og,
    size_t qkbase, size_t obase, size_t vbase, int qkstride,
    int q0, int tid, bf16* Qs, bf16* Ks, bf16* Vt)
{
  int lane = tid & 63, w = tid >> 6;
  int lm = lane & 15, lq = lane >> 4;
  int r0 = tid >> 3, c8 = (tid & 7)*8;
  int r1 = r0 + 32;
  *(uint4*)&Qs[SWZ(r0,c8)] = *(const uint4*)&Qg[qkbase + (size_t)(q0+r0)*qkstride + c8];
  *(uint4*)&Qs[SWZ(r1,c8)] = *(const uint4*)&Qg[qkbase + (size_t)(q0+r1)*qkstride + c8];
  __syncthreads();
  bf16x8 qa0 = *(bf16x8*)&Qs[SWZ(w*16 + lm, lq*8)];
  bf16x8 qa1 = *(bf16x8*)&Qs[SWZ(w*16 + lm, 32 + lq*8)];
  short4v ones4;
  { bf16x4 o1 = {(bf16)1.f,(bf16)1.f,(bf16)1.f,(bf16)1.f};
    __builtin_memcpy(&ones4, &o1, 8); }
  float m_ = 0.f;
  floatx4 lacc = (floatx4){0.f,0.f,0.f,0.f};
  floatx4 oacc[4];
#pragma unroll
  for (int db = 0; db < 4; ++db) oacc[db] = (floatx4){0.f,0.f,0.f,0.f};

  for (int kt = 0; kt < KM; kt += 64) {
    __syncthreads();
    *(uint4*)&Ks[SWZ(r0,c8)] = *(const uint4*)&Kg[qkbase + (size_t)(kt+r0)*qkstride + c8];
    *(uint4*)&Ks[SWZ(r1,c8)] = *(const uint4*)&Kg[qkbase + (size_t)(kt+r1)*qkstride + c8];
    *(uint4*)&Vt[SWZ(r0,c8)] = *(const uint4*)&VTg[vbase + (size_t)r0*KM + kt + c8];
    *(uint4*)&Vt[SWZ(r1,c8)] = *(const uint4*)&VTg[vbase + (size_t)r1*KM + kt + c8];
    __syncthreads();
    floatx4 st[4];
    float negm = -m_;
    __builtin_amdgcn_s_setprio(1);
#pragma unroll
    for (int kb = 0; kb < 4; ++kb) {
      bf16x8 a0 = *(bf16x8*)&Ks[SWZ(kb*16 + lm, lq*8)];
      bf16x8 a1 = *(bf16x8*)&Ks[SWZ(kb*16 + lm, 32 + lq*8)];
      floatx4 acc = (floatx4){negm, negm, negm, negm};
      acc = MFMA16(a0, qa0, acc);
      acc = MFMA16(a1, qa1, acc);
      st[kb] = acc;
    }
    __builtin_amdgcn_s_setprio(0);
    // local max, max3-shaped (16 -> 8 ops)
    float ma = fmaxf(fmaxf(st[0][0], st[0][1]), st[0][2]);
    float mb = fmaxf(fmaxf(st[0][3], st[1][0]), st[1][1]);
    float mc = fmaxf(fmaxf(st[1][2], st[1][3]), st[2][0]);
    float md = fmaxf(fmaxf(st[2][1], st[2][2]), st[2][3]);
    float me = fmaxf(fmaxf(st[3][0], st[3][1]), st[3][2]);
    float mf = fmaxf(fmaxf(ma, mb), st[3][3]);
    float mg = fmaxf(fmaxf(mc, md), me);
    float mx = fmaxf(mf, mg);
    // defer-max: wave-uniform test; shfls + subs only when a rescale is needed
    if (!__all(mx <= 8.f)) {
      float wmx = fmaxf(mx, __shfl_xor(mx, 16));
      wmx = fmaxf(wmx, __shfl_xor(wmx, 32));
      float delta = fmaxf(wmx, 0.f);
      float al = exp2f(-delta);
      m_ += delta;
      lacc[0] *= al; lacc[1] *= al; lacc[2] *= al; lacc[3] *= al;
#pragma unroll
      for (int db = 0; db < 4; ++db) {
        oacc[db][0] *= al; oacc[db][1] *= al;
        oacc[db][2] *= al; oacc[db][3] *= al;
      }
#pragma unroll
      for (int kb = 0; kb < 4; ++kb) {
        st[kb][0] -= delta; st[kb][1] -= delta;
        st[kb][2] -= delta; st[kb][3] -= delta;
      }
    }
    __builtin_amdgcn_s_setprio(1);
#pragma unroll
    for (int kb = 0; kb < 4; ++kb) {
      float p0 = exp2f(st[kb][0]);
      float p1 = exp2f(st[kb][1]);
      float p2 = exp2f(st[kb][2]);
      float p3 = exp2f(st[kb][3]);
      short4v pb = pack4(p0, p1, p2, p3);
      lacc = MFMA1K(ones4, pb, lacc);
#pragma unroll
      for (int db = 0; db < 4; ++db) {
        short4v va = *(const short4v*)&Vt[SWZ(db*16 + lm, kb*16 + lq*4)];
        oacc[db] = MFMA1K(va, pb, oacc[db]);
      }
    }
    __builtin_amdgcn_s_setprio(0);
  }
  float inv = 1.f / lacc[0];
  int q = q0 + w*16 + lm;
#pragma unroll
  for (int db = 0; db < 4; ++db) {
    bf16x4 o4 = { (bf16)(oacc[db][0]*inv), (bf16)(oacc[db][1]*inv),
                  (bf16)(oacc[db][2]*inv), (bf16)(oacc[db][3]*inv) };
    *(bf16x4*)&Og[obase + (size_t)q*DD + db*16 + lq*4] = o4;
  }
}

// self attention: grid (zh=64, qtile=16); Q/K row stride 256
__global__ __launch_bounds__(256) void mha_kernel(
    const bf16* __restrict__ Qg, const bf16* __restrict__ Kg,
    const bf16* __restrict__ VTg, bf16* __restrict__ Og)
{
  __shared__ __align__(16) bf16 Qs[64*64];
  __shared__ __align__(16) bf16 Ks[64*64];
  __shared__ __align__(16) bf16 Vt[64*64];
  int zh = blockIdx.x;
  int z = zh >> 2, h = zh & 3;
  size_t base = ((size_t)z*KM)*DD + (size_t)h*HD;
  size_t vbase = (size_t)zh*HD*KM;
  mha_body(Qg, Kg, VTg, Og, base, base, vbase, DD,
           blockIdx.y*64, threadIdx.x, Qs, Ks, Vt);
}

// cross attention, both directions: grid (zh=32, qtile=16, dir=2)
// Q/K live in QKV2 (row stride 512, q at col 0..255, v projected separately)
__global__ __launch_bounds__(256) void mha_cross_kernel(
    const bf16* __restrict__ QKV2, const bf16* __restrict__ VT2,
    bf16* __restrict__ ATTO2)
{
  __shared__ __align__(16) bf16 Qs[64*64];
  __shared__ __align__(16) bf16 Ks[64*64];
  __shared__ __align__(16) bf16 Vt[64*64];
  int dir = blockIdx.z;
  const bf16* Qg  = QKV2 + (dir ? (size_t)BN*512 : 0);
  const bf16* Kg  = QKV2 + (dir ? 0 : (size_t)BN*512);
  const bf16* VTg = VT2  + (dir ? 0 : (size_t)32*HD*KM);
  bf16*       Og  = ATTO2 + (dir ? (size_t)BN*DD : 0);
  int zh = blockIdx.x;
  int z = zh >> 2, h = zh & 3;
  size_t qkbase = ((size_t)z*KM)*512 + (size_t)h*HD;
  size_t obase  = ((size_t)z*KM)*DD  + (size_t)h*HD;
  size_t vbase  = (size_t)zh*HD*KM;
  mha_body(Qg, Kg, VTg, Og, qkbase, obase, vbase, 512,
           blockIdx.y*64, threadIdx.x, Qs, Ks, Vt);
}

// ---------------- in-place LayerNorm + exact GELU (bf16, width 512) --------
// One wave per row (4 rows per block): bf16x8 loads, pure shuffle-butterfly
// reductions, zero __syncthreads. Deterministic fixed-order sums.
__global__ __launch_bounds__(256) void ln_gelu_kernel(
    bf16* __restrict__ Hb, const float* __restrict__ g,
    const float* __restrict__ be)
{
  int t = threadIdx.x;
  int lane = t & 63, w = t >> 6;
  size_t r = (size_t)blockIdx.x*4 + w;
  bf16* rowp = Hb + r*512 + lane*8;
  bf16x8 hv = *(bf16x8*)rowp;
  float x[8];
#pragma unroll
  for (int j = 0; j < 8; ++j) x[j] = (float)hv[j];
  float s = ((x[0]+x[1]) + (x[2]+x[3])) + ((x[4]+x[5]) + (x[6]+x[7]));
  s = wred(s);
  float mu = s * (1.f/512.f);
  float v = 0.f;
#pragma unroll
  for (int j = 0; j < 8; ++j) { float d = x[j] - mu; v += d*d; }
  v = wred(v);
  float rstd = rsqrtf(v*(1.f/512.f) + 1e-5f);
  float4 g0 = *(const float4*)&g[lane*8];
  float4 g1 = *(const float4*)&g[lane*8 + 4];
  float4 b0 = *(const float4*)&be[lane*8];
  float4 b1 = *(const float4*)&be[lane*8 + 4];
  float gv[8] = {g0.x,g0.y,g0.z,g0.w,g1.x,g1.y,g1.z,g1.w};
  float bv[8] = {b0.x,b0.y,b0.z,b0.w,b1.x,b1.y,b1.z,b1.w};
  bf16x8 ov;
#pragma unroll
  for (int j = 0; j < 8; ++j) {
    float h = (x[j] - mu)*rstd*gv[j] + bv[j];
    h = 0.5f*h*(1.f + erff(h*0.70710678118f));
    ov[j] = (bf16)h;
  }
  *(bf16x8*)rowp = ov;
}

// ---------------- final head 2 ----------------
__global__ __launch_bounds__(256) void head2_kernel(
    const float* __restrict__ Hb, const float* __restrict__ w,
    const float* __restrict__ b, float* __restrict__ out)
{
  int r = blockIdx.x*256 + threadIdx.x;
  float acc = b[0];
#pragma unroll
  for (int k = 0; k < 64; ++k) acc += Hb[(size_t)r*64 + k]*w[k];
  out[r] = 1.f/(1.f + expf(-acc));
}

extern "C" void kernel_launch(void* const* d_in, const int* in_sizes, int n_in,
                              void* d_out, int out_size, void* d_ws, size_t ws_size,
                              hipStream_t stream)
{
  (void)in_sizes; (void)n_in; (void)out_size; (void)ws_size;
  const float* fa      = (const float*)d_in[0];
  const float* fb      = (const float*)d_in[1];
  const int*   matches = (const int*)d_in[2];
  const float* ka      = (const float*)d_in[3];
  const float* kb      = (const float*)d_in[4];
  const float* lam     = (const float*)d_in[5];
  const float* beta    = (const float*)d_in[6];
  const float* Wr      = (const float*)d_in[7];
  const float* pW1     = (const float*)d_in[8];
  const float* pb1     = (const float*)d_in[9];
  const float* pW2     = (const float*)d_in[10];
  const float* pb2     = (const float*)d_in[11];
  const float* sWqkv   = (const float*)d_in[12];
  const float* sbqkv   = (const float*)d_in[13];
  const float* sWo     = (const float*)d_in[14];
  const float* sbo     = (const float*)d_in[15];
  const float* sW1     = (const float*)d_in[16];
  const float* sb1     = (const float*)d_in[17];
  const float* sg      = (const float*)d_in[18];
  const float* sbe     = (const float*)d_in[19];
  const float* sW2     = (const float*)d_in[20];
  const float* sb2     = (const float*)d_in[21];
  const float* cWqk    = (const float*)d_in[22];
  const float* cbqk    = (const float*)d_in[23];
  const float* cWv     = (const float*)d_in[24];
  const float* cbv     = (const float*)d_in[25];
  const float* cWo     = (const float*)d_in[26];
  const float* cbo     = (const float*)d_in[27];
  const float* cW1     = (const float*)d_in[28];
  const float* cb1     = (const float*)d_in[29];
  const float* cgw     = (const float*)d_in[30];
  const float* cbe     = (const float*)d_in[31];
  const float* cW2     = (const float*)d_in[32];
  const float* cb2     = (const float*)d_in[33];

  char* wsb = (char*)d_ws;
  float* DCAT = (float*)wsb;                      // 16,777,216 B
  float* ENC0 = (float*)(wsb + 16777216);
  float* ENC1 = (float*)(wsb + 20971520);
  float* XY0  = (float*)(wsb + 25165824);
  float* XY1  = (float*)(wsb + 25231360);
  float* ROWS = (float*)(wsb + 25296896);
  char*  POOL = wsb + 25354240;
  const size_t SLOT = 8388608;
  // CG phase
  fp16*  KMATH = (fp16*)POOL;                    // slots 0-1
  float* FBUF  = (float*)(POOL + 2*SLOT);
  float* PT    = (float*)(POOL + 3*SLOT);
  float* RT    = (float*)(POOL + 4*SLOT);
  float* XT    = (float*)(POOL + 5*SLOT);
  float* APT   = (float*)(POOL + 6*SLOT);
  // transformer phase
  bf16*  QKV   = (bf16*)POOL;                    // slots 0-2 (q|k|v cols)
  bf16*  QR    = (bf16*)(POOL + 3*SLOT);
  bf16*  KR    = (bf16*)(POOL + 4*SLOT);
  bf16*  VTG   = (bf16*)(POOL + 8*SLOT);         // slot 8 (V^T, self)
  bf16*  ATTO  = (bf16*)POOL;                    // slot 0
  bf16*  MSG   = (bf16*)(POOL + 1*SLOT);
  bf16*  H1    = (bf16*)(POOL + 6*SLOT);         // slots 6-7
  bf16*  QKV2  = (bf16*)POOL;                    // slots 0-1 (cross q|v cols)
  bf16*  ATTO2 = (bf16*)(POOL + 2*SLOT);
  bf16*  MSG2  = (bf16*)(POOL + 3*SLOT);
  bf16*  VT2   = (bf16*)(POOL + 4*SLOT);         // slot 4 (V^T, cross)
  bf16*  H1C   = H1;
  float* HBUF  = (float*)POOL;

  const float scq = 0.42466090f;   // 64^-0.25 * sqrt(log2 e)

  // ---- gather / posenc / Kmat ----
  gather_kernel<<<BN, 256, 0, stream>>>(fa, fb, matches, ka, kb, FBUF, DCAT, XY0, XY1);
  posenc_kernel<<<BN/4, 256, 0, stream>>>(XY0, Wr, ENC0);
  posenc_kernel<<<BN/4, 256, 0, stream>>>(XY1, Wr, ENC1);
  kmat_kernel<<<BN, 256, 0, stream>>>(XY0, beta, KMATH, ROWS);

  // ---- CG (transposed state, deterministic: no fp atomics anywhere) ----
  tinit_kernel<<<dim3(16,4,BB), 256, 0, stream>>>(FBUF, PT, RT, XT);
  for (int it = 0; it < CG_ITERS; ++it) {
    mv64_kernel<float,fp16,float><<<dim3(4,16,BB), 256, 0, stream>>>(
        PT, 1024, KMATH, APT, 1024, PT, lam, (const float*)0,
        262144, 1048576, 262144, 262144);
    cg_update_kernel<<<2048, 256, 0, stream>>>(XT, RT, PT, APT);
  }

  // ---- d1 = rownorm(Kmat) @ C  (d0 = f_i already written by gather) ----
  mv64_kernel<fp16,float,float><<<dim3(16,4,BB), 256, 0, stream>>>(
      KMATH, 1024, XT, DCAT + (size_t)BN*DD, 256,
      (const float*)0, (const float*)0, ROWS,
      1048576, 262144, 262144, 0);

  // ---- transformer layers ----
  for (int l = 0; l < NLAYER; ++l) {
    // self block
    mm_kernel<128,1,0,float,float,float,bf16><<<dim3(128,6,1), 256, 0, stream>>>(
        DCAT, (const float*)0, 256, 256, sWqkv + (size_t)l*768*256, sbqkv + l*768,
        (const float*)0, (const float*)0, QKV, 768, 1.f, 1.f, (const float*)0);
    rope_split_kernel<<<8192, 256, 0, stream>>>(QKV, ENC0, ENC1, QR, KR);
    vt_kernel<<<dim3(64,16), 256, 0, stream>>>(QKV + 512, 768, VTG);
    mha_kernel<<<dim3(64,16), 256, 0, stream>>>(QR, KR, VTG, ATTO);
    mm_kernel<64,0,0,bf16,bf16,float,bf16><<<dim3(128,4,1), 256, 0, stream>>>(
        ATTO, (const bf16*)0, 256, 256, sWo + (size_t)l*256*256, sbo + l*256,
        (const float*)0, (const float*)0, MSG, 256, 1.f, 1.f, (const float*)0);
    mm_kernel<128,0,0,float,bf16,float,bf16><<<dim3(128,4,1), 256, 0, stream>>>(
        DCAT, MSG, 256, 512, sW1 + (size_t)l*512*512, sb1 + l*512,
        (const float*)0, (const float*)0, H1, 512, 1.f, 1.f, (const float*)0);
    ln_gelu_kernel<<<N2/4, 256, 0, stream>>>(H1, sg + l*512, sbe + l*512);
    mm_kernel<64,0,0,bf16,bf16,float,float><<<dim3(128,4,1), 256, 0, stream>>>(
        H1, (const bf16*)0, 512, 512, sW2 + (size_t)l*256*512, sb2 + l*256,
        (const float*)0, (const float*)0, DCAT, 256, 1.f, 1.f, DCAT);
    // cross block: fused qk|v projection into QKV2 (row stride 512)
    mm_kernel<128,0,1,float,float,float,bf16><<<dim3(128,4,1), 256, 0, stream>>>(
        DCAT, (const float*)0, 256, 256, cWqk + (size_t)l*256*256, cbqk + l*256,
        cWv + (size_t)l*256*256, cbv + l*256, QKV2, 512, scq, 1.f,
        (const float*)0);
    vt_kernel<<<dim3(64,16), 256, 0, stream>>>(QKV2 + 256, 512, VT2);
    mha_cross_kernel<<<dim3(32,16,2), 256, 0, stream>>>(QKV2, VT2, ATTO2);
    mm_kernel<64,0,0,bf16,bf16,float,bf16><<<dim3(128,4,1), 256, 0, stream>>>(
        ATTO2, (const bf16*)0, 256, 256, cWo + (size_t)l*256*256, cbo + l*256,
        (const float*)0, (const float*)0, MSG2, 256, 1.f, 1.f, (const float*)0);
    mm_kernel<128,0,0,float,bf16,float,bf16><<<dim3(128,4,1), 256, 0, stream>>>(
        DCAT, MSG2, 256, 512, cW1 + (size_t)l*512*512, cb1 + l*512,
        (const float*)0, (const float*)0, H1C, 512, 1.f, 1.f, (const float*)0);
    ln_gelu_kernel<<<N2/4, 256, 0, stream>>>(H1C, cgw + l*512, cbe + l*512);
    mm_kernel<64,0,0,bf16,bf16,float,float><<<dim3(128,4,1), 256, 0, stream>>>(
        H1C, (const bf16*)0, 512, 512, cW2 + (size_t)l*256*512, cb2 + l*256,
        (const float*)0, (const float*)0, DCAT, 256, 1.f, 1.f, DCAT);
  }

  // ---- head ----
  gemm_f32_kernel<<<dim3(128,1), 256, 0, stream>>>(DCAT, 256, pW1, pb1, HBUF, 64);
  head2_kernel<<<32, 256, 0, stream>>>(HBUF, pW2, pb2, (float*)d_out);
}

// Round 14
// 986.590 us; speedup vs baseline: 1.1712x; 1.0386x over previous
//
#include <hip/hip_runtime.h>
#include <math.h>

// Problem constants
#define BB 8
#define MM 2048
#define KM 1024
#define DD 256
#define HH 4
#define HD 64
#define NLAYER 2
#define BN (BB*KM)        // 8192 rows per "decoder half"
#define N2 (2*BN)         // 16384 rows d0||d1
#define CG_ITERS 5

// XOR-swizzled LDS addressing for the attention tiles: stride 64 (no pad),
// 16-byte blocks permuted by row. Conflict-free for uint4 stores, bf16x8
// reads, and short4v reads — and keeps every access 16B/8B aligned.
#define SWZ(r,c) (((r)<<6) + ((((c)>>3) ^ ((r)&7))<<3) + ((c)&7))

typedef __bf16 bf16;
typedef __bf16 bf16x8 __attribute__((ext_vector_type(8)));
typedef __bf16 bf16x4 __attribute__((ext_vector_type(4)));
typedef __bf16 bf16x2 __attribute__((ext_vector_type(2)));
typedef _Float16 fp16;
typedef _Float16 fp16x8 __attribute__((ext_vector_type(8)));
typedef short  short4v __attribute__((ext_vector_type(4)));
typedef float  floatx4 __attribute__((ext_vector_type(4)));
#define MFMA16(a,b,c)  __builtin_amdgcn_mfma_f32_16x16x32_bf16(a,b,c,0,0,0)
#define MFMA16H(a,b,c) __builtin_amdgcn_mfma_f32_16x16x32_f16(a,b,c,0,0,0)

// K=16 bf16 MFMA (PV stage: S^T C-frag == its B-operand layout).
#if defined(__HIP_DEVICE_COMPILE__)
  #if __has_builtin(__builtin_amdgcn_mfma_f32_16x16x16bf16_1k)
    #define MFMA1K(a,b,c) __builtin_amdgcn_mfma_f32_16x16x16bf16_1k(a,b,c,0,0,0)
  #else
    #error "device pass lacks mfma_f32_16x16x16bf16_1k"
  #endif
#else
  #define MFMA1K(a,b,c) (c)   /* host stub, never executed */
#endif

__device__ __forceinline__ float softplusf(float x) {
  return fmaxf(x, 0.f) + log1pf(expf(-fabsf(x)));
}

__device__ __forceinline__ float wred(float x) {
  x += __shfl_xor(x, 1);  x += __shfl_xor(x, 2);  x += __shfl_xor(x, 4);
  x += __shfl_xor(x, 8);  x += __shfl_xor(x, 16); x += __shfl_xor(x, 32);
  return x;
}

__device__ __forceinline__ short4v pack4(float a, float b, float c, float d) {
  bf16x4 v = {(bf16)a,(bf16)b,(bf16)c,(bf16)d};
  short4v s;
  __builtin_memcpy(&s, &v, 8);
  return s;
}

// stage 8 elements (convert to bf16 if needed), 16B LDS store
__device__ __forceinline__ void stage8(bf16* dst, const float* src) {
  float4 a = *(const float4*)src;
  float4 b = *(const float4*)(src + 4);
  bf16x8 v = { (bf16)a.x,(bf16)a.y,(bf16)a.z,(bf16)a.w,
               (bf16)b.x,(bf16)b.y,(bf16)b.z,(bf16)b.w };
  *(bf16x8*)dst = v;
}
__device__ __forceinline__ void stage8(bf16* dst, const bf16* src) {
  *(uint4*)dst = *(const uint4*)src;
}

// raw staging to fp16 LDS (CG phase)
template<typename T> struct Raw8;
template<> struct Raw8<float> {
  float4 a, b;
  __device__ __forceinline__ void load(const float* s) {
    a = *(const float4*)s; b = *(const float4*)(s + 4);
  }
  __device__ __forceinline__ void store(fp16* d) const {
    fp16x8 v = { (fp16)a.x,(fp16)a.y,(fp16)a.z,(fp16)a.w,
                 (fp16)b.x,(fp16)b.y,(fp16)b.z,(fp16)b.w };
    *(fp16x8*)d = v;
  }
};
template<> struct Raw8<fp16> {
  uint4 u;
  __device__ __forceinline__ void load(const fp16* s) { u = *(const uint4*)s; }
  __device__ __forceinline__ void store(fp16* d) const { *(uint4*)d = u; }
};

// ---------------- gather (writes F to both FBUF and DCAT; no copy pass) -----
__global__ __launch_bounds__(256) void gather_kernel(
    const float* __restrict__ fa, const float* __restrict__ fb,
    const int* __restrict__ matches, const float* __restrict__ ka,
    const float* __restrict__ kb, float* __restrict__ F,
    float* __restrict__ Fd,
    float* __restrict__ xy0, float* __restrict__ xy1)
{
  int si = blockIdx.x;
  int s  = si >> 10;
  int t  = threadIdx.x;
  int ia = matches[(size_t)si*2+0];
  int ib = matches[(size_t)si*2+1];
  float v = fb[((size_t)s*MM + ib)*DD + t] - fa[((size_t)s*MM + ia)*DD + t];
  F[(size_t)si*DD + t]  = v;
  Fd[(size_t)si*DD + t] = v;
  if (t == 0) {
    xy0[(size_t)si*2+0] = ka[((size_t)s*MM + ia)*2+0];
    xy0[(size_t)si*2+1] = ka[((size_t)s*MM + ia)*2+1];
    xy1[(size_t)si*2+0] = kb[((size_t)s*MM + ib)*2+0];
    xy1[(size_t)si*2+1] = kb[((size_t)s*MM + ib)*2+1];
  }
}

// ---------------- positional encoding (4 rows per 256-thread block) ---------
__global__ __launch_bounds__(256) void posenc_kernel(
    const float* __restrict__ xy, const float* __restrict__ Wr,
    float* __restrict__ enc)
{
  int t = threadIdx.x;
  int si = blockIdx.x*4 + (t >> 6);
  int s = si >> 10, i = si & 1023;
  int d = t & 63; int p = d >> 1;
  float x = xy[(size_t)si*2], y = xy[(size_t)si*2+1];
  float pr = Wr[p*2]*x + Wr[p*2+1]*y;
  enc[(((size_t)s*2+0)*KM + i)*HD + d] = cosf(pr);
  enc[(((size_t)s*2+1)*KM + i)*HD + d] = sinf(pr);
}

// ---------------- Kmat (fp16) + rowsum (wave butterflies) -------------------
// exp2f with beta*log2e folded: single v_exp_f32 instead of libm expf; the
// <=1ulp f32 delta is far below the fp16 quantization of Km.
__global__ __launch_bounds__(256) void kmat_kernel(
    const float* __restrict__ xy0, const float* __restrict__ beta_ptr,
    fp16* __restrict__ Km, float* __restrict__ rowsum)
{
  __shared__ float redw[4];
  int si = blockIdx.x; int s = si >> 10;
  int t = threadIdx.x;
  int lane = t & 63, w = t >> 6;
  float beta_l2 = softplusf(beta_ptr[0]) * 1.442695040888963f;
  float xi = xy0[(size_t)si*2], yi = xy0[(size_t)si*2+1];
  const float* xys = xy0 + (size_t)s*KM*2;
  float sum = 0.f;
  for (int jj = 0; jj < 4; ++jj) {
    int j = jj*256 + t;
    float dx = xi - xys[j*2], dy = yi - xys[j*2+1];
    float v = exp2f(-beta_l2*(dx*dx + dy*dy));
    Km[(size_t)si*KM + j] = (fp16)v;
    sum += v;
  }
  sum = wred(sum);
  if (lane == 0) redw[w] = sum;
  __syncthreads();
  if (t == 0)
    rowsum[si] = ((redw[0]+redw[1]) + (redw[2]+redw[3])) + 1e-6f;
}

// ---------------- MFMA GEMM, tile 128xNT (NT=128 or 64), BK=64 ----------------
// C = [A1|A2] @ Wsel.T, epilogue (v+bias)*scale (+resid).
// WPERM: W row index perm(j)=(j&255)*3+(j>>8)  (qkv channel de-interleave)
// DUALW: cols [0,256) from W/bias/scale, cols [256,512) from Wb/biasb/scaleb
// Round-8 staging structure (stage8 direct to LDS, 2 barriers/step) with
// k-independent A/W row pointers hoisted out of the K-loop, plus T5
// s_setprio around the MFMA cluster (independent blocks at different
// K-phases -> prioritized MFMA waves preempt other blocks' staging).
template<int NT, int WPERM, int DUALW,
         typename TA1, typename TA2, typename TW, typename TO>
__global__ __launch_bounds__(256) void mm_kernel(
    const TA1* __restrict__ A1, const TA2* __restrict__ A2, int K1, int K,
    const TW* __restrict__ W, const float* __restrict__ bias,
    const TW* __restrict__ Wb, const float* __restrict__ biasb,
    TO* __restrict__ C, int O, float scale, float scaleb,
    const float* __restrict__ resid)
{
  __shared__ __align__(16) bf16 Al[128*72];
  __shared__ __align__(16) bf16 Wl[NT*72];
  constexpr int MB = (NT == 128) ? 4 : 2;
  constexpr int WP = NT/32;
  int tid = threadIdx.x;
  int row0 = blockIdx.x*128, col0 = blockIdx.y*NT;
  int lane = tid & 63, w = tid >> 6;
  int wr = (NT == 128) ? (w>>1)*64 : w*32;
  int wc = (NT == 128) ? (w&1)*64 : 0;
  int lm = lane & 15, lq = lane >> 4;
  int srow = tid >> 3, sc8 = (tid & 7)*8;

  // k-independent source row pointers
  const TA1* aptr1[4]; const TA2* aptr2[4];
#pragma unroll
  for (int p = 0; p < 4; ++p) {
    int row = p*32 + srow;
    aptr1[p] = A1 + (size_t)(row0+row)*K1 + sc8;
    aptr2[p] = A2 + (size_t)(row0+row)*(K-K1) + sc8;
  }
  const TW* wptr[WP];
#pragma unroll
  for (int p = 0; p < WP; ++p) {
    int wg = col0 + p*32 + srow;
    const TW* wsrc; int wrow;
    if (DUALW && wg >= 256) { wsrc = Wb; wrow = wg - 256; }
    else { wsrc = W; wrow = WPERM ? ((wg & 255)*3 + (wg >> 8)) : wg; }
    wptr[p] = wsrc + (size_t)wrow*K + sc8;
  }

  floatx4 acc[MB][4];
#pragma unroll
  for (int mb = 0; mb < MB; ++mb)
#pragma unroll
    for (int nb = 0; nb < 4; ++nb) acc[mb][nb] = (floatx4){0.f,0.f,0.f,0.f};
  for (int k0 = 0; k0 < K; k0 += 64) {
    bool use1 = (k0 < K1);
#pragma unroll
    for (int p = 0; p < 4; ++p) {
      bf16* d = &Al[(p*32+srow)*72 + sc8];
      if (use1) stage8(d, aptr1[p] + k0);
      else      stage8(d, aptr2[p] + (k0 - K1));
    }
#pragma unroll
    for (int p = 0; p < WP; ++p)
      stage8(&Wl[(p*32+srow)*72 + sc8], wptr[p] + k0);
    __syncthreads();
    bf16x8 af[MB][2], bfr[4][2];
#pragma unroll
    for (int mb = 0; mb < MB; ++mb) {
      af[mb][0] = *(bf16x8*)&Al[(wr + mb*16 + lm)*72 + lq*8];
      af[mb][1] = *(bf16x8*)&Al[(wr + mb*16 + lm)*72 + 32 + lq*8];
    }
#pragma unroll
    for (int nb = 0; nb < 4; ++nb) {
      bfr[nb][0] = *(bf16x8*)&Wl[(wc + nb*16 + lm)*72 + lq*8];
      bfr[nb][1] = *(bf16x8*)&Wl[(wc + nb*16 + lm)*72 + 32 + lq*8];
    }
    __builtin_amdgcn_s_setprio(1);
#pragma unroll
    for (int mb = 0; mb < MB; ++mb)
#pragma unroll
      for (int nb = 0; nb < 4; ++nb) {
        acc[mb][nb] = MFMA16(af[mb][0], bfr[nb][0], acc[mb][nb]);
        acc[mb][nb] = MFMA16(af[mb][1], bfr[nb][1], acc[mb][nb]);
      }
    __builtin_amdgcn_s_setprio(0);
    __syncthreads();
  }
#pragma unroll
  for (int mb = 0; mb < MB; ++mb) {
#pragma unroll
    for (int nb = 0; nb < 4; ++nb) {
#pragma unroll
      for (int r = 0; r < 4; ++r) {
        int grow = row0 + wr + mb*16 + lq*4 + r;
        int gcol = col0 + wc + nb*16 + lm;
        float v = acc[mb][nb][r];
        float bv = 0.f, scl = scale;
        if (DUALW && gcol >= 256) {
          if (biasb) bv = biasb[gcol - 256];
          scl = scaleb;
        } else if (bias) {
          bv = bias[WPERM ? ((gcol & 255)*3 + (gcol >> 8)) : gcol];
        }
        v = (v + bv) * scl;
        if (resid) v += resid[(size_t)grow*O + gcol];
        C[(size_t)grow*O + gcol] = (TO)v;
      }
    }
  }
}

// ---------------- MFMA matvec-GEMM, 64x64 tile, BK=64, batched over z --------
// fp16 staging/MFMA (CG phase). Double-buffered LDS + register prefetch:
// one barrier per K-step, global latency hidden under MFMA. Deterministic.
// T5 setprio around the MFMA cluster.
template<typename TA, typename TW, typename TO>
__global__ __launch_bounds__(256) void mv64_kernel(
    const TA* __restrict__ A, int K, const TW* __restrict__ W,
    TO* __restrict__ C, int O,
    const float* __restrict__ resid, const float* __restrict__ lam_ptr,
    const float* __restrict__ rowdiv,
    long zsA, long zsW, long zsC, long zsR)
{
  __shared__ __align__(16) fp16 Al[2][64*72];
  __shared__ __align__(16) fp16 Wl[2][64*72];
  int tid = threadIdx.x;
  int z = blockIdx.z;
  const TA* Az = A + (size_t)z*zsA;
  const TW* Wz = W + (size_t)z*zsW;
  TO* Cz = C + (size_t)z*zsC;
  const float* Rz = resid ? (resid + (size_t)z*zsR) : (const float*)0;
  int row0 = blockIdx.x*64, col0 = blockIdx.y*64;
  int lane = tid & 63, w = tid >> 6;
  int wr = (w>>1)*32, wc = (w&1)*32;
  int lm = lane & 15, lq = lane >> 4;
  int sr0 = tid >> 3, c8 = (tid & 7)*8;
  int sr1 = sr0 + 32;
  floatx4 acc[2][2];
#pragma unroll
  for (int mb = 0; mb < 2; ++mb)
#pragma unroll
    for (int nb = 0; nb < 2; ++nb) acc[mb][nb] = (floatx4){0.f,0.f,0.f,0.f};

  Raw8<TA> a0p, a1p; Raw8<TW> w0p, w1p;
  a0p.load(&Az[(size_t)(row0+sr0)*K + c8]);
  a1p.load(&Az[(size_t)(row0+sr1)*K + c8]);
  w0p.load(&Wz[(size_t)(col0+sr0)*K + c8]);
  w1p.load(&Wz[(size_t)(col0+sr1)*K + c8]);
  a0p.store(&Al[0][sr0*72 + c8]); a1p.store(&Al[0][sr1*72 + c8]);
  w0p.store(&Wl[0][sr0*72 + c8]); w1p.store(&Wl[0][sr1*72 + c8]);
  __syncthreads();

  for (int k0 = 0; k0 < K; k0 += 64) {
    int cur = (k0 >> 6) & 1;
    bool pre = (k0 + 64 < K);
    if (pre) {
      a0p.load(&Az[(size_t)(row0+sr0)*K + k0+64 + c8]);
      a1p.load(&Az[(size_t)(row0+sr1)*K + k0+64 + c8]);
      w0p.load(&Wz[(size_t)(col0+sr0)*K + k0+64 + c8]);
      w1p.load(&Wz[(size_t)(col0+sr1)*K + k0+64 + c8]);
    }
    fp16x8 a0[2], a1[2], b0[2], b1[2];
#pragma unroll
    for (int mb = 0; mb < 2; ++mb) {
      a0[mb] = *(fp16x8*)&Al[cur][(wr + mb*16 + lm)*72 + lq*8];
      a1[mb] = *(fp16x8*)&Al[cur][(wr + mb*16 + lm)*72 + 32 + lq*8];
    }
#pragma unroll
    for (int nb = 0; nb < 2; ++nb) {
      b0[nb] = *(fp16x8*)&Wl[cur][(wc + nb*16 + lm)*72 + lq*8];
      b1[nb] = *(fp16x8*)&Wl[cur][(wc + nb*16 + lm)*72 + 32 + lq*8];
    }
    __builtin_amdgcn_s_setprio(1);
#pragma unroll
    for (int mb = 0; mb < 2; ++mb)
#pragma unroll
      for (int nb = 0; nb < 2; ++nb) {
        acc[mb][nb] = MFMA16H(a0[mb], b0[nb], acc[mb][nb]);
        acc[mb][nb] = MFMA16H(a1[mb], b1[nb], acc[mb][nb]);
      }
    __builtin_amdgcn_s_setprio(0);
    if (pre) {
      a0p.store(&Al[cur^1][sr0*72 + c8]); a1p.store(&Al[cur^1][sr1*72 + c8]);
      w0p.store(&Wl[cur^1][sr0*72 + c8]); w1p.store(&Wl[cur^1][sr1*72 + c8]);
    }
    __syncthreads();
  }
  float lamv = 1.f;
  if (lam_ptr) lamv = softplusf(lam_ptr[0]) + 1e-6f;
#pragma unroll
  for (int mb = 0; mb < 2; ++mb) {
#pragma unroll
    for (int nb = 0; nb < 2; ++nb) {
#pragma unroll
      for (int r = 0; r < 4; ++r) {
        int grow = row0 + wr + mb*16 + lq*4 + r;
        int gcol = col0 + wc + nb*16 + lm;
        float v = acc[mb][nb][r];
        if (rowdiv) v /= rowdiv[(size_t)z*KM + grow];
        if (Rz) v += lamv * Rz[(size_t)grow*O + gcol];
        Cz[(size_t)grow*O + gcol] = (TO)v;
      }
    }
  }
}

// ---------------- fp32 tile GEMM (head only, O=64) ----------------
__global__ __launch_bounds__(256) void gemm_f32_kernel(
    const float* __restrict__ A, int K,
    const float* __restrict__ W, const float* __restrict__ bias,
    float* __restrict__ C, int O)
{
  __shared__ float As[32][68];
  __shared__ float Ws[32][68];
  int t = threadIdx.x;
  int row0 = blockIdx.x * 64;
  int col0 = blockIdx.y * 64;
  int ti = t & 15, tj = t >> 4;
  float acc[4][4] = {};
  for (int k0 = 0; k0 < K; k0 += 32) {
#pragma unroll
    for (int p = 0; p < 2; ++p) {
      int idx = p*256 + t;
      int ar = idx >> 3, af = (idx & 7)*4;
      float4 av = *(const float4*)&A[(size_t)(row0+ar)*K + k0 + af];
      As[af+0][ar] = av.x; As[af+1][ar] = av.y;
      As[af+2][ar] = av.z; As[af+3][ar] = av.w;
      float4 wv = *(const float4*)&W[(size_t)(col0+ar)*K + k0 + af];
      Ws[af+0][ar] = wv.x; Ws[af+1][ar] = wv.y;
      Ws[af+2][ar] = wv.z; Ws[af+3][ar] = wv.w;
    }
    __syncthreads();
#pragma unroll
    for (int kk = 0; kk < 32; ++kk) {
      float4 a4 = *(float4*)&As[kk][ti*4];
      float4 b4 = *(float4*)&Ws[kk][tj*4];
      float a[4] = {a4.x, a4.y, a4.z, a4.w};
      float b[4] = {b4.x, b4.y, b4.z, b4.w};
#pragma unroll
      for (int x = 0; x < 4; ++x)
#pragma unroll
        for (int y = 0; y < 4; ++y) acc[x][y] += a[x]*b[y];
    }
    __syncthreads();
  }
#pragma unroll
  for (int x = 0; x < 4; ++x) {
    int r = row0 + ti*4 + x;
#pragma unroll
    for (int y = 0; y < 4; ++y) {
      int c = col0 + tj*4 + y;
      float v = fmaxf(acc[x][y] + bias[c], 0.f);
      C[(size_t)r*O + c] = v;
    }
  }
}

// ---------------- transpose-init: PT=RT=F^T, XT=0 (no atomics) --------------
__global__ __launch_bounds__(256) void tinit_kernel(
    const float* __restrict__ F, float* __restrict__ PT, float* __restrict__ RT,
    float* __restrict__ XT)
{
  __shared__ float Ls[64][68];
  int t = threadIdx.x;
  int k0 = blockIdx.x*64, n0 = blockIdx.y*64, z = blockIdx.z;
#pragma unroll
  for (int p = 0; p < 4; ++p) {
    int idx = p*256 + t;
    int kr = idx >> 4, c4 = (idx & 15)*4;
    *(float4*)&Ls[kr][c4] = *(const float4*)&F[((size_t)z*KM + k0+kr)*DD + n0 + c4];
  }
  __syncthreads();
#pragma unroll
  for (int p = 0; p < 4; ++p) {
    int idx = p*256 + t;
    int nl = idx >> 4, k4 = (idx & 15)*4;
    float4 v = { Ls[k4+0][nl], Ls[k4+1][nl], Ls[k4+2][nl], Ls[k4+3][nl] };
    size_t o = ((size_t)z*DD + n0+nl)*KM + k0 + k4;
    *(float4*)&PT[o] = v;
    *(float4*)&RT[o] = v;
    float4 zr = {0.f,0.f,0.f,0.f};
    *(float4*)&XT[o] = zr;
  }
}

// ---------------- merged CG update (self-contained, deterministic) ----------
// One block per state row (KM=1024, float4 per thread). rr and pAp via
// fixed-order wave butterflies + 4-slot LDS combine — no fp atomics.
__global__ __launch_bounds__(256) void cg_update_kernel(
    float* __restrict__ XT, float* __restrict__ RT,
    float* __restrict__ PT, const float* __restrict__ APT)
{
  __shared__ float redw[12];
  int row = blockIdx.x;
  int t = threadIdx.x;
  int lane = t & 63, w = t >> 6;
  size_t base = (size_t)row*KM + (size_t)t*4;
  float4 p4 = *(float4*)&PT[base];
  float4 a4 = *(const float4*)&APT[base];
  float4 r4 = *(float4*)&RT[base];
  float4 x4 = *(float4*)&XT[base];
  float prr  = (r4.x*r4.x + r4.y*r4.y) + (r4.z*r4.z + r4.w*r4.w);
  float ppap = (p4.x*a4.x + p4.y*a4.y) + (p4.z*a4.z + p4.w*a4.w);
  prr = wred(prr); ppap = wred(ppap);
  if (lane == 0) { redw[w] = prr; redw[4+w] = ppap; }
  __syncthreads();
  float rr  = (redw[0]+redw[1]) + (redw[2]+redw[3]);
  float pap = (redw[4]+redw[5]) + (redw[6]+redw[7]);
  float alpha = (pap > 1e-30f) ? rr/pap : 0.f;
  x4.x += alpha*p4.x; x4.y += alpha*p4.y; x4.z += alpha*p4.z; x4.w += alpha*p4.w;
  r4.x -= alpha*a4.x; r4.y -= alpha*a4.y; r4.z -= alpha*a4.z; r4.w -= alpha*a4.w;
  *(float4*)&XT[base] = x4;
  *(float4*)&RT[base] = r4;
  float s = (r4.x*r4.x + r4.y*r4.y) + (r4.z*r4.z + r4.w*r4.w);
  s = wred(s);
  if (lane == 0) redw[8+w] = s;
  __syncthreads();
  float rrnew = (redw[8]+redw[9]) + (redw[10]+redw[11]);
  float beta = (rr > 1e-30f) ? rrnew/rr : 0.f;
  p4.x = r4.x + beta*p4.x; p4.y = r4.y + beta*p4.y;
  p4.z = r4.z + beta*p4.z; p4.w = r4.w + beta*p4.w;
  *(float4*)&PT[base] = p4;
}

// ---------------- RoPE (coalesced, de-interleaved QKV) ----------------
// QKV layout per row: [q 0..255 | k 256..511 | v 512..767]; pair rotation is
// in-thread. 0.125*log2e folded into Q. 2 rows per 256-thread block.
__global__ __launch_bounds__(256) void rope_split_kernel(
    const bf16* __restrict__ qkv, const float* __restrict__ enc0,
    const float* __restrict__ enc1, bf16* __restrict__ Qo,
    bf16* __restrict__ Ko)
{
  int t = threadIdx.x;
  int r = blockIdx.x*2 + (t >> 7);
  int c = (t & 127)*2;                    // even col
  int ts = r >> 10, i = r & 1023;
  int d = c & 63;
  const float* enc = (ts < BB) ? enc0 : enc1;
  int s = (ts < BB) ? ts : ts - BB;
  const float* eb = enc + (((size_t)s*2)*KM + i)*HD;
  float2 cs = *(const float2*)&eb[d];
  float2 sn = *(const float2*)&eb[(size_t)KM*HD + d];
  size_t base = (size_t)r*768;
  bf16x2 qv = *(const bf16x2*)&qkv[base + c];
  bf16x2 kv = *(const bf16x2*)&qkv[base + 256 + c];
  float q0 = (float)qv[0], q1 = (float)qv[1];
  float k0 = (float)kv[0], k1 = (float)kv[1];
  float oq0 = q0*cs.x - q1*sn.x, oq1 = q1*cs.y + q0*sn.y;
  float ok0 = k0*cs.x - k1*sn.x, ok1 = k1*cs.y + k0*sn.y;
  size_t o = (size_t)r*DD + c;
  bf16x2 qo = {(bf16)(0.1803368801f*oq0), (bf16)(0.1803368801f*oq1)};
  bf16x2 ko = {(bf16)ok0, (bf16)ok1};
  *(bf16x2*)&Qo[o] = qo;
  *(bf16x2*)&Ko[o] = ko;
}

// ---------------- V -> V^T transpose (per (stream,head)), strided src -------
// src row k of (ts,h): Vin[((size_t)ts*KM + k)*vstride + h*HD + d]
// out: VT[((ts*4+h)*HD + d)*KM + k]
__global__ __launch_bounds__(256) void vt_kernel(
    const bf16* __restrict__ Vin, int vstride, bf16* __restrict__ VT)
{
  __shared__ __align__(16) bf16 Ls[64*72];
  int tid = threadIdx.x;
  int zh = blockIdx.x;
  int ts = zh >> 2, h = zh & 3;
  int k0 = blockIdx.y * 64;
#pragma unroll
  for (int p = 0; p < 2; ++p) {
    int idx = p*256 + tid;
    int kr = idx >> 3, c8 = (idx & 7)*8;
    *(uint4*)&Ls[kr*72 + c8] =
      *(const uint4*)&Vin[((size_t)ts*KM + k0 + kr)*vstride + h*HD + c8];
  }
  __syncthreads();
#pragma unroll
  for (int p = 0; p < 2; ++p) {
    int idx = p*256 + tid;
    int dr = idx >> 3, k8 = (idx & 7)*8;
    bf16 tmp[8] __attribute__((aligned(16)));
#pragma unroll
    for (int j = 0; j < 8; ++j) tmp[j] = Ls[(k8+j)*72 + dr];
    *(uint4*)&VT[((size_t)zh*HD + dr)*KM + k0 + k8] = *(uint4*)tmp;
  }
}

// ---------------- MFMA flash attention body (S^T scheme, V^T input) ----------
// Round-8 proven structure: single-buffer, 2 barriers/tile, setprio,
// MFMA-computed row-sum, branch-local max shfls, bias-in-accumulator softmax
// (QK MFMA C-operand = -m_; common path is exp2(st) with no subtract).
__device__ __forceinline__ void mha_body(
    const bf16* __restrict__ Qg, const bf16* __restrict__ Kg,
    const bf16* __restrict__ VTg, bf16* __restrict__ Og,
    size_t qkbase, size_t obase, size_t vbase, int qkstride,
    int q0, int tid, bf16* Qs, bf16* Ks, bf16* Vt)
{
  int lane = tid & 63, w = tid >> 6;
  int lm = lane & 15, lq = lane >> 4;
  int r0 = tid >> 3, c8 = (tid & 7)*8;
  int r1 = r0 + 32;
  *(uint4*)&Qs[SWZ(r0,c8)] = *(const uint4*)&Qg[qkbase + (size_t)(q0+r0)*qkstride + c8];
  *(uint4*)&Qs[SWZ(r1,c8)] = *(const uint4*)&Qg[qkbase + (size_t)(q0+r1)*qkstride + c8];
  __syncthreads();
  bf16x8 qa0 = *(bf16x8*)&Qs[SWZ(w*16 + lm, lq*8)];
  bf16x8 qa1 = *(bf16x8*)&Qs[SWZ(w*16 + lm, 32 + lq*8)];
  short4v ones4;
  { bf16x4 o1 = {(bf16)1.f,(bf16)1.f,(bf16)1.f,(bf16)1.f};
    __builtin_memcpy(&ones4, &o1, 8); }
  float m_ = 0.f;
  floatx4 lacc = (floatx4){0.f,0.f,0.f,0.f};
  floatx4 oacc[4];
#pragma unroll
  for (int db = 0; db < 4; ++db) oacc[db] = (floatx4){0.f,0.f,0.f,0.f};

  for (int kt = 0; kt < KM; kt += 64) {
    __syncthreads();
    *(uint4*)&Ks[SWZ(r0,c8)] = *(const uint4*)&Kg[qkbase + (size_t)(kt+r0)*qkstride + c8];
    *(uint4*)&Ks[SWZ(r1,c8)] = *(const uint4*)&Kg[qkbase + (size_t)(kt+r1)*qkstride + c8];
    *(uint4*)&Vt[SWZ(r0,c8)] = *(const uint4*)&VTg[vbase + (size_t)r0*KM + kt + c8];
    *(uint4*)&Vt[SWZ(r1,c8)] = *(const uint4*)&VTg[vbase + (size_t)r1*KM + kt + c8];
    __syncthreads();
    floatx4 st[4];
    float negm = -m_;
    __builtin_amdgcn_s_setprio(1);
#pragma unroll
    for (int kb = 0; kb < 4; ++kb) {
      bf16x8 a0 = *(bf16x8*)&Ks[SWZ(kb*16 + lm, lq*8)];
      bf16x8 a1 = *(bf16x8*)&Ks[SWZ(kb*16 + lm, 32 + lq*8)];
      floatx4 acc = (floatx4){negm, negm, negm, negm};
      acc = MFMA16(a0, qa0, acc);
      acc = MFMA16(a1, qa1, acc);
      st[kb] = acc;
    }
    __builtin_amdgcn_s_setprio(0);
    // local max, max3-shaped (16 -> 8 ops)
    float ma = fmaxf(fmaxf(st[0][0], st[0][1]), st[0][2]);
    float mb = fmaxf(fmaxf(st[0][3], st[1][0]), st[1][1]);
    float mc = fmaxf(fmaxf(st[1][2], st[1][3]), st[2][0]);
    float md = fmaxf(fmaxf(st[2][1], st[2][2]), st[2][3]);
    float me = fmaxf(fmaxf(st[3][0], st[3][1]), st[3][2]);
    float mf = fmaxf(fmaxf(ma, mb), st[3][3]);
    float mg = fmaxf(fmaxf(mc, md), me);
    float mx = fmaxf(mf, mg);
    // defer-max: wave-uniform test; shfls + subs only when a rescale is needed
    if (!__all(mx <= 8.f)) {
      float wmx = fmaxf(mx, __shfl_xor(mx, 16));
      wmx = fmaxf(wmx, __shfl_xor(wmx, 32));
      float delta = fmaxf(wmx, 0.f);
      float al = exp2f(-delta);
      m_ += delta;
      lacc[0] *= al; lacc[1] *= al; lacc[2] *= al; lacc[3] *= al;
#pragma unroll
      for (int db = 0; db < 4; ++db) {
        oacc[db][0] *= al; oacc[db][1] *= al;
        oacc[db][2] *= al; oacc[db][3] *= al;
      }
#pragma unroll
      for (int kb = 0; kb < 4; ++kb) {
        st[kb][0] -= delta; st[kb][1] -= delta;
        st[kb][2] -= delta; st[kb][3] -= delta;
      }
    }
    __builtin_amdgcn_s_setprio(1);
#pragma unroll
    for (int kb = 0; kb < 4; ++kb) {
      float p0 = exp2f(st[kb][0]);
      float p1 = exp2f(st[kb][1]);
      float p2 = exp2f(st[kb][2]);
      float p3 = exp2f(st[kb][3]);
      short4v pb = pack4(p0, p1, p2, p3);
      lacc = MFMA1K(ones4, pb, lacc);
#pragma unroll
      for (int db = 0; db < 4; ++db) {
        short4v va = *(const short4v*)&Vt[SWZ(db*16 + lm, kb*16 + lq*4)];
        oacc[db] = MFMA1K(va, pb, oacc[db]);
      }
    }
    __builtin_amdgcn_s_setprio(0);
  }
  float inv = 1.f / lacc[0];
  int q = q0 + w*16 + lm;
#pragma unroll
  for (int db = 0; db < 4; ++db) {
    bf16x4 o4 = { (bf16)(oacc[db][0]*inv), (bf16)(oacc[db][1]*inv),
                  (bf16)(oacc[db][2]*inv), (bf16)(oacc[db][3]*inv) };
    *(bf16x4*)&Og[obase + (size_t)q*DD + db*16 + lq*4] = o4;
  }
}

// self attention: grid (zh=64, qtile=16); Q/K row stride 256
__global__ __launch_bounds__(256) void mha_kernel(
    const bf16* __restrict__ Qg, const bf16* __restrict__ Kg,
    const bf16* __restrict__ VTg, bf16* __restrict__ Og)
{
  __shared__ __align__(16) bf16 Qs[64*64];
  __shared__ __align__(16) bf16 Ks[64*64];
  __shared__ __align__(16) bf16 Vt[64*64];
  int zh = blockIdx.x;
  int z = zh >> 2, h = zh & 3;
  size_t base = ((size_t)z*KM)*DD + (size_t)h*HD;
  size_t vbase = (size_t)zh*HD*KM;
  mha_body(Qg, Kg, VTg, Og, base, base, vbase, DD,
           blockIdx.y*64, threadIdx.x, Qs, Ks, Vt);
}

// cross attention, both directions: grid (zh=32, qtile=16, dir=2)
// Q/K live in QKV2 (row stride 512, q at col 0..255, v projected separately)
__global__ __launch_bounds__(256) void mha_cross_kernel(
    const bf16* __restrict__ QKV2, const bf16* __restrict__ VT2,
    bf16* __restrict__ ATTO2)
{
  __shared__ __align__(16) bf16 Qs[64*64];
  __shared__ __align__(16) bf16 Ks[64*64];
  __shared__ __align__(16) bf16 Vt[64*64];
  int dir = blockIdx.z;
  const bf16* Qg  = QKV2 + (dir ? (size_t)BN*512 : 0);
  const bf16* Kg  = QKV2 + (dir ? 0 : (size_t)BN*512);
  const bf16* VTg = VT2  + (dir ? 0 : (size_t)32*HD*KM);
  bf16*       Og  = ATTO2 + (dir ? (size_t)BN*DD : 0);
  int zh = blockIdx.x;
  int z = zh >> 2, h = zh & 3;
  size_t qkbase = ((size_t)z*KM)*512 + (size_t)h*HD;
  size_t obase  = ((size_t)z*KM)*DD  + (size_t)h*HD;
  size_t vbase  = (size_t)zh*HD*KM;
  mha_body(Qg, Kg, VTg, Og, qkbase, obase, vbase, 512,
           blockIdx.y*64, threadIdx.x, Qs, Ks, Vt);
}

// ---------------- in-place LayerNorm + exact GELU (bf16, width 512) --------
// One wave per row (4 rows per block): bf16x8 loads, pure shuffle-butterfly
// reductions, zero __syncthreads. Deterministic fixed-order sums.
__global__ __launch_bounds__(256) void ln_gelu_kernel(
    bf16* __restrict__ Hb, const float* __restrict__ g,
    const float* __restrict__ be)
{
  int t = threadIdx.x;
  int lane = t & 63, w = t >> 6;
  size_t r = (size_t)blockIdx.x*4 + w;
  bf16* rowp = Hb + r*512 + lane*8;
  bf16x8 hv = *(bf16x8*)rowp;
  float x[8];
#pragma unroll
  for (int j = 0; j < 8; ++j) x[j] = (float)hv[j];
  float s = ((x[0]+x[1]) + (x[2]+x[3])) + ((x[4]+x[5]) + (x[6]+x[7]));
  s = wred(s);
  float mu = s * (1.f/512.f);
  float v = 0.f;
#pragma unroll
  for (int j = 0; j < 8; ++j) { float d = x[j] - mu; v += d*d; }
  v = wred(v);
  float rstd = rsqrtf(v*(1.f/512.f) + 1e-5f);
  float4 g0 = *(const float4*)&g[lane*8];
  float4 g1 = *(const float4*)&g[lane*8 + 4];
  float4 b0 = *(const float4*)&be[lane*8];
  float4 b1 = *(const float4*)&be[lane*8 + 4];
  float gv[8] = {g0.x,g0.y,g0.z,g0.w,g1.x,g1.y,g1.z,g1.w};
  float bv[8] = {b0.x,b0.y,b0.z,b0.w,b1.x,b1.y,b1.z,b1.w};
  bf16x8 ov;
#pragma unroll
  for (int j = 0; j < 8; ++j) {
    float h = (x[j] - mu)*rstd*gv[j] + bv[j];
    h = 0.5f*h*(1.f + erff(h*0.70710678118f));
    ov[j] = (bf16)h;
  }
  *(bf16x8*)rowp = ov;
}

// ---------------- final head 2 ----------------
__global__ __launch_bounds__(256) void head2_kernel(
    const float* __restrict__ Hb, const float* __restrict__ w,
    const float* __restrict__ b, float* __restrict__ out)
{
  int r = blockIdx.x*256 + threadIdx.x;
  float acc = b[0];
#pragma unroll
  for (int k = 0; k < 64; ++k) acc += Hb[(size_t)r*64 + k]*w[k];
  out[r] = 1.f/(1.f + expf(-acc));
}

extern "C" void kernel_launch(void* const* d_in, const int* in_sizes, int n_in,
                              void* d_out, int out_size, void* d_ws, size_t ws_size,
                              hipStream_t stream)
{
  (void)in_sizes; (void)n_in; (void)out_size; (void)ws_size;
  const float* fa      = (const float*)d_in[0];
  const float* fb      = (const float*)d_in[1];
  const int*   matches = (const int*)d_in[2];
  const float* ka      = (const float*)d_in[3];
  const float* kb      = (const float*)d_in[4];
  const float* lam     = (const float*)d_in[5];
  const float* beta    = (const float*)d_in[6];
  const float* Wr      = (const float*)d_in[7];
  const float* pW1     = (const float*)d_in[8];
  const float* pb1     = (const float*)d_in[9];
  const float* pW2     = (const float*)d_in[10];
  const float* pb2     = (const float*)d_in[11];
  const float* sWqkv   = (const float*)d_in[12];
  const float* sbqkv   = (const float*)d_in[13];
  const float* sWo     = (const float*)d_in[14];
  const float* sbo     = (const float*)d_in[15];
  const float* sW1     = (const float*)d_in[16];
  const float* sb1     = (const float*)d_in[17];
  const float* sg      = (const float*)d_in[18];
  const float* sbe     = (const float*)d_in[19];
  const float* sW2     = (const float*)d_in[20];
  const float* sb2     = (const float*)d_in[21];
  const float* cWqk    = (const float*)d_in[22];
  const float* cbqk    = (const float*)d_in[23];
  const float* cWv     = (const float*)d_in[24];
  const float* cbv     = (const float*)d_in[25];
  const float* cWo     = (const float*)d_in[26];
  const float* cbo     = (const float*)d_in[27];
  const float* cW1     = (const float*)d_in[28];
  const float* cb1     = (const float*)d_in[29];
  const float* cgw     = (const float*)d_in[30];
  const float* cbe     = (const float*)d_in[31];
  const float* cW2     = (const float*)d_in[32];
  const float* cb2     = (const float*)d_in[33];

  char* wsb = (char*)d_ws;
  float* DCAT = (float*)wsb;                      // 16,777,216 B
  float* ENC0 = (float*)(wsb + 16777216);
  float* ENC1 = (float*)(wsb + 20971520);
  float* XY0  = (float*)(wsb + 25165824);
  float* XY1  = (float*)(wsb + 25231360);
  float* ROWS = (float*)(wsb + 25296896);
  char*  POOL = wsb + 25354240;
  const size_t SLOT = 8388608;
  // CG phase
  fp16*  KMATH = (fp16*)POOL;                    // slots 0-1
  float* FBUF  = (float*)(POOL + 2*SLOT);
  float* PT    = (float*)(POOL + 3*SLOT);
  float* RT    = (float*)(POOL + 4*SLOT);
  float* XT    = (float*)(POOL + 5*SLOT);
  float* APT   = (float*)(POOL + 6*SLOT);
  // transformer phase
  bf16*  QKV   = (bf16*)POOL;                    // slots 0-2 (q|k|v cols)
  bf16*  QR    = (bf16*)(POOL + 3*SLOT);
  bf16*  KR    = (bf16*)(POOL + 4*SLOT);
  bf16*  VTG   = (bf16*)(POOL + 8*SLOT);         // slot 8 (V^T, self)
  bf16*  ATTO  = (bf16*)POOL;                    // slot 0
  bf16*  MSG   = (bf16*)(POOL + 1*SLOT);
  bf16*  H1    = (bf16*)(POOL + 6*SLOT);         // slots 6-7
  bf16*  QKV2  = (bf16*)POOL;                    // slots 0-1 (cross q|v cols)
  bf16*  ATTO2 = (bf16*)(POOL + 2*SLOT);
  bf16*  MSG2  = (bf16*)(POOL + 3*SLOT);
  bf16*  VT2   = (bf16*)(POOL + 4*SLOT);         // slot 4 (V^T, cross)
  bf16*  H1C   = H1;
  float* HBUF  = (float*)POOL;

  const float scq = 0.42466090f;   // 64^-0.25 * sqrt(log2 e)

  // ---- gather / posenc / Kmat ----
  gather_kernel<<<BN, 256, 0, stream>>>(fa, fb, matches, ka, kb, FBUF, DCAT, XY0, XY1);
  posenc_kernel<<<BN/4, 256, 0, stream>>>(XY0, Wr, ENC0);
  posenc_kernel<<<BN/4, 256, 0, stream>>>(XY1, Wr, ENC1);
  kmat_kernel<<<BN, 256, 0, stream>>>(XY0, beta, KMATH, ROWS);

  // ---- CG (transposed state, deterministic: no fp atomics anywhere) ----
  tinit_kernel<<<dim3(16,4,BB), 256, 0, stream>>>(FBUF, PT, RT, XT);
  for (int it = 0; it < CG_ITERS; ++it) {
    mv64_kernel<float,fp16,float><<<dim3(4,16,BB), 256, 0, stream>>>(
        PT, 1024, KMATH, APT, 1024, PT, lam, (const float*)0,
        262144, 1048576, 262144, 262144);
    cg_update_kernel<<<2048, 256, 0, stream>>>(XT, RT, PT, APT);
  }

  // ---- d1 = rownorm(Kmat) @ C  (d0 = f_i already written by gather) ----
  mv64_kernel<fp16,float,float><<<dim3(16,4,BB), 256, 0, stream>>>(
      KMATH, 1024, XT, DCAT + (size_t)BN*DD, 256,
      (const float*)0, (const float*)0, ROWS,
      1048576, 262144, 262144, 0);

  // ---- transformer layers ----
  for (int l = 0; l < NLAYER; ++l) {
    // self block
    mm_kernel<128,1,0,float,float,float,bf16><<<dim3(128,6,1), 256, 0, stream>>>(
        DCAT, (const float*)0, 256, 256, sWqkv + (size_t)l*768*256, sbqkv + l*768,
        (const float*)0, (const float*)0, QKV, 768, 1.f, 1.f, (const float*)0);
    rope_split_kernel<<<8192, 256, 0, stream>>>(QKV, ENC0, ENC1, QR, KR);
    vt_kernel<<<dim3(64,16), 256, 0, stream>>>(QKV + 512, 768, VTG);
    mha_kernel<<<dim3(64,16), 256, 0, stream>>>(QR, KR, VTG, ATTO);
    mm_kernel<64,0,0,bf16,bf16,float,bf16><<<dim3(128,4,1), 256, 0, stream>>>(
        ATTO, (const bf16*)0, 256, 256, sWo + (size_t)l*256*256, sbo + l*256,
        (const float*)0, (const float*)0, MSG, 256, 1.f, 1.f, (const float*)0);
    mm_kernel<128,0,0,float,bf16,float,bf16><<<dim3(128,4,1), 256, 0, stream>>>(
        DCAT, MSG, 256, 512, sW1 + (size_t)l*512*512, sb1 + l*512,
        (const float*)0, (const float*)0, H1, 512, 1.f, 1.f, (const float*)0);
    ln_gelu_kernel<<<N2/4, 256, 0, stream>>>(H1, sg + l*512, sbe + l*512);
    mm_kernel<64,0,0,bf16,bf16,float,float><<<dim3(128,4,1), 256, 0, stream>>>(
        H1, (const bf16*)0, 512, 512, sW2 + (size_t)l*256*512, sb2 + l*256,
        (const float*)0, (const float*)0, DCAT, 256, 1.f, 1.f, DCAT);
    // cross block: fused qk|v projection into QKV2 (row stride 512)
    mm_kernel<128,0,1,float,float,float,bf16><<<dim3(128,4,1), 256, 0, stream>>>(
        DCAT, (const float*)0, 256, 256, cWqk + (size_t)l*256*256, cbqk + l*256,
        cWv + (size_t)l*256*256, cbv + l*256, QKV2, 512, scq, 1.f,
        (const float*)0);
    vt_kernel<<<dim3(64,16), 256, 0, stream>>>(QKV2 + 256, 512, VT2);
    mha_cross_kernel<<<dim3(32,16,2), 256, 0, stream>>>(QKV2, VT2, ATTO2);
    mm_kernel<64,0,0,bf16,bf16,float,bf16><<<dim3(128,4,1), 256, 0, stream>>>(
        ATTO2, (const bf16*)0, 256, 256, cWo + (size_t)l*256*256, cbo + l*256,
        (const float*)0, (const float*)0, MSG2, 256, 1.f, 1.f, (const float*)0);
    mm_kernel<128,0,0,float,bf16,float,bf16><<<dim3(128,4,1), 256, 0, stream>>>(
        DCAT, MSG2, 256, 512, cW1 + (size_t)l*512*512, cb1 + l*512,
        (const float*)0, (const float*)0, H1C, 512, 1.f, 1.f, (const float*)0);
    ln_gelu_kernel<<<N2/4, 256, 0, stream>>>(H1C, cgw + l*512, cbe + l*512);
    mm_kernel<64,0,0,bf16,bf16,float,float><<<dim3(128,4,1), 256, 0, stream>>>(
        H1C, (const bf16*)0, 512, 512, cW2 + (size_t)l*256*512, cb2 + l*256,
        (const float*)0, (const float*)0, DCAT, 256, 1.f, 1.f, DCAT);
  }

  // ---- head ----
  gemm_f32_kernel<<<dim3(128,1), 256, 0, stream>>>(DCAT, 256, pW1, pb1, HBUF, 64);
  head2_kernel<<<32, 256, 0, stream>>>(HBUF, pW2, pb2, (float*)d_out);
}

// Round 15
// 928.720 us; speedup vs baseline: 1.2442x; 1.0623x over previous
//
#include <hip/hip_runtime.h>
#include <math.h>

// Problem constants
#define BB 8
#define MM 2048
#define KM 1024
#define DD 256
#define HH 4
#define HD 64
#define NLAYER 2
#define BN (BB*KM)        // 8192 rows per "decoder half"
#define N2 (2*BN)         // 16384 rows d0||d1
#define CG_ITERS 5

// XOR-swizzled LDS addressing for the attention tiles: stride 64 (no pad),
// 16-byte blocks permuted by row. Conflict-free for uint4 stores, bf16x8
// reads, and short4v reads — and keeps every access 16B/8B aligned.
#define SWZ(r,c) (((r)<<6) + ((((c)>>3) ^ ((r)&7))<<3) + ((c)&7))

typedef __bf16 bf16;
typedef __bf16 bf16x8 __attribute__((ext_vector_type(8)));
typedef __bf16 bf16x4 __attribute__((ext_vector_type(4)));
typedef __bf16 bf16x2 __attribute__((ext_vector_type(2)));
typedef _Float16 fp16;
typedef _Float16 fp16x8 __attribute__((ext_vector_type(8)));
typedef short  short4v __attribute__((ext_vector_type(4)));
typedef float  floatx4 __attribute__((ext_vector_type(4)));
#define MFMA16(a,b,c)  __builtin_amdgcn_mfma_f32_16x16x32_bf16(a,b,c,0,0,0)
#define MFMA16H(a,b,c) __builtin_amdgcn_mfma_f32_16x16x32_f16(a,b,c,0,0,0)

// K=16 bf16 MFMA (PV stage: S^T C-frag == its B-operand layout).
#if defined(__HIP_DEVICE_COMPILE__)
  #if __has_builtin(__builtin_amdgcn_mfma_f32_16x16x16bf16_1k)
    #define MFMA1K(a,b,c) __builtin_amdgcn_mfma_f32_16x16x16bf16_1k(a,b,c,0,0,0)
  #else
    #error "device pass lacks mfma_f32_16x16x16bf16_1k"
  #endif
#else
  #define MFMA1K(a,b,c) (c)   /* host stub, never executed */
#endif

__device__ __forceinline__ float softplusf(float x) {
  return fmaxf(x, 0.f) + log1pf(expf(-fabsf(x)));
}

__device__ __forceinline__ float wred(float x) {
  x += __shfl_xor(x, 1);  x += __shfl_xor(x, 2);  x += __shfl_xor(x, 4);
  x += __shfl_xor(x, 8);  x += __shfl_xor(x, 16); x += __shfl_xor(x, 32);
  return x;
}

__device__ __forceinline__ short4v pack4(float a, float b, float c, float d) {
  bf16x4 v = {(bf16)a,(bf16)b,(bf16)c,(bf16)d};
  short4v s;
  __builtin_memcpy(&s, &v, 8);
  return s;
}

// stage 8 elements (convert to bf16 if needed), 16B LDS store
__device__ __forceinline__ void stage8(bf16* dst, const float* src) {
  float4 a = *(const float4*)src;
  float4 b = *(const float4*)(src + 4);
  bf16x8 v = { (bf16)a.x,(bf16)a.y,(bf16)a.z,(bf16)a.w,
               (bf16)b.x,(bf16)b.y,(bf16)b.z,(bf16)b.w };
  *(bf16x8*)dst = v;
}
__device__ __forceinline__ void stage8(bf16* dst, const bf16* src) {
  *(uint4*)dst = *(const uint4*)src;
}

// raw staging (load early / convert+store late)
template<typename T> struct Raw8;
template<> struct Raw8<float> {
  float4 a, b;
  __device__ __forceinline__ void load(const float* s) {
    a = *(const float4*)s; b = *(const float4*)(s + 4);
  }
  __device__ __forceinline__ void store(fp16* d) const {
    fp16x8 v = { (fp16)a.x,(fp16)a.y,(fp16)a.z,(fp16)a.w,
                 (fp16)b.x,(fp16)b.y,(fp16)b.z,(fp16)b.w };
    *(fp16x8*)d = v;
  }
  __device__ __forceinline__ void storeb(bf16* d) const {
    bf16x8 v = { (bf16)a.x,(bf16)a.y,(bf16)a.z,(bf16)a.w,
                 (bf16)b.x,(bf16)b.y,(bf16)b.z,(bf16)b.w };
    *(bf16x8*)d = v;
  }
};
template<> struct Raw8<fp16> {
  uint4 u;
  __device__ __forceinline__ void load(const fp16* s) { u = *(const uint4*)s; }
  __device__ __forceinline__ void store(fp16* d) const { *(uint4*)d = u; }
};

// ---------------- gather (writes F to both FBUF and DCAT; no copy pass) -----
__global__ __launch_bounds__(256) void gather_kernel(
    const float* __restrict__ fa, const float* __restrict__ fb,
    const int* __restrict__ matches, const float* __restrict__ ka,
    const float* __restrict__ kb, float* __restrict__ F,
    float* __restrict__ Fd,
    float* __restrict__ xy0, float* __restrict__ xy1)
{
  int si = blockIdx.x;
  int s  = si >> 10;
  int t  = threadIdx.x;
  int ia = matches[(size_t)si*2+0];
  int ib = matches[(size_t)si*2+1];
  float v = fb[((size_t)s*MM + ib)*DD + t] - fa[((size_t)s*MM + ia)*DD + t];
  F[(size_t)si*DD + t]  = v;
  Fd[(size_t)si*DD + t] = v;
  if (t == 0) {
    xy0[(size_t)si*2+0] = ka[((size_t)s*MM + ia)*2+0];
    xy0[(size_t)si*2+1] = ka[((size_t)s*MM + ia)*2+1];
    xy1[(size_t)si*2+0] = kb[((size_t)s*MM + ib)*2+0];
    xy1[(size_t)si*2+1] = kb[((size_t)s*MM + ib)*2+1];
  }
}

// ---------------- positional encoding (4 rows per 256-thread block) ---------
__global__ __launch_bounds__(256) void posenc_kernel(
    const float* __restrict__ xy, const float* __restrict__ Wr,
    float* __restrict__ enc)
{
  int t = threadIdx.x;
  int si = blockIdx.x*4 + (t >> 6);
  int s = si >> 10, i = si & 1023;
  int d = t & 63; int p = d >> 1;
  float x = xy[(size_t)si*2], y = xy[(size_t)si*2+1];
  float pr = Wr[p*2]*x + Wr[p*2+1]*y;
  enc[(((size_t)s*2+0)*KM + i)*HD + d] = cosf(pr);
  enc[(((size_t)s*2+1)*KM + i)*HD + d] = sinf(pr);
}

// ---------------- Kmat (fp16) + rowsum (wave butterflies) -------------------
__global__ __launch_bounds__(256) void kmat_kernel(
    const float* __restrict__ xy0, const float* __restrict__ beta_ptr,
    fp16* __restrict__ Km, float* __restrict__ rowsum)
{
  __shared__ float redw[4];
  int si = blockIdx.x; int s = si >> 10;
  int t = threadIdx.x;
  int lane = t & 63, w = t >> 6;
  float beta_l2 = softplusf(beta_ptr[0]) * 1.442695040888963f;
  float xi = xy0[(size_t)si*2], yi = xy0[(size_t)si*2+1];
  const float* xys = xy0 + (size_t)s*KM*2;
  float sum = 0.f;
  for (int jj = 0; jj < 4; ++jj) {
    int j = jj*256 + t;
    float dx = xi - xys[j*2], dy = yi - xys[j*2+1];
    float v = exp2f(-beta_l2*(dx*dx + dy*dy));
    Km[(size_t)si*KM + j] = (fp16)v;
    sum += v;
  }
  sum = wred(sum);
  if (lane == 0) redw[w] = sum;
  __syncthreads();
  if (t == 0)
    rowsum[si] = ((redw[0]+redw[1]) + (redw[2]+redw[3])) + 1e-6f;
}

// ---------------- MFMA GEMM, tile 128xNT (NT=128 or 64), BK=64 ----------------
// C = [A1|A2] @ Wsel.T, epilogue (v+bias)*scale (+resid).
// WPERM: W row index perm(j)=(j&255)*3+(j>>8)  (qkv channel de-interleave)
// DUALW: cols [0,256) from W/bias/scale, cols [256,512) from Wb/biasb/scaleb
template<int NT, int WPERM, int DUALW,
         typename TA1, typename TA2, typename TW, typename TO>
__global__ __launch_bounds__(256) void mm_kernel(
    const TA1* __restrict__ A1, const TA2* __restrict__ A2, int K1, int K,
    const TW* __restrict__ W, const float* __restrict__ bias,
    const TW* __restrict__ Wb, const float* __restrict__ biasb,
    TO* __restrict__ C, int O, float scale, float scaleb,
    const float* __restrict__ resid)
{
  __shared__ __align__(16) bf16 Al[128*72];
  __shared__ __align__(16) bf16 Wl[NT*72];
  constexpr int MB = (NT == 128) ? 4 : 2;
  constexpr int WP = NT/32;
  int tid = threadIdx.x;
  int row0 = blockIdx.x*128, col0 = blockIdx.y*NT;
  int lane = tid & 63, w = tid >> 6;
  int wr = (NT == 128) ? (w>>1)*64 : w*32;
  int wc = (NT == 128) ? (w&1)*64 : 0;
  int lm = lane & 15, lq = lane >> 4;
  int srow = tid >> 3, sc8 = (tid & 7)*8;

  const TA1* aptr1[4]; const TA2* aptr2[4];
#pragma unroll
  for (int p = 0; p < 4; ++p) {
    int row = p*32 + srow;
    aptr1[p] = A1 + (size_t)(row0+row)*K1 + sc8;
    aptr2[p] = A2 + (size_t)(row0+row)*(K-K1) + sc8;
  }
  const TW* wptr[WP];
#pragma unroll
  for (int p = 0; p < WP; ++p) {
    int wg = col0 + p*32 + srow;
    const TW* wsrc; int wrow;
    if (DUALW && wg >= 256) { wsrc = Wb; wrow = wg - 256; }
    else { wsrc = W; wrow = WPERM ? ((wg & 255)*3 + (wg >> 8)) : wg; }
    wptr[p] = wsrc + (size_t)wrow*K + sc8;
  }

  floatx4 acc[MB][4];
#pragma unroll
  for (int mb = 0; mb < MB; ++mb)
#pragma unroll
    for (int nb = 0; nb < 4; ++nb) acc[mb][nb] = (floatx4){0.f,0.f,0.f,0.f};
  for (int k0 = 0; k0 < K; k0 += 64) {
    bool use1 = (k0 < K1);
#pragma unroll
    for (int p = 0; p < 4; ++p) {
      bf16* d = &Al[(p*32+srow)*72 + sc8];
      if (use1) stage8(d, aptr1[p] + k0);
      else      stage8(d, aptr2[p] + (k0 - K1));
    }
#pragma unroll
    for (int p = 0; p < WP; ++p)
      stage8(&Wl[(p*32+srow)*72 + sc8], wptr[p] + k0);
    __syncthreads();
    bf16x8 af[MB][2], bfr[4][2];
#pragma unroll
    for (int mb = 0; mb < MB; ++mb) {
      af[mb][0] = *(bf16x8*)&Al[(wr + mb*16 + lm)*72 + lq*8];
      af[mb][1] = *(bf16x8*)&Al[(wr + mb*16 + lm)*72 + 32 + lq*8];
    }
#pragma unroll
    for (int nb = 0; nb < 4; ++nb) {
      bfr[nb][0] = *(bf16x8*)&Wl[(wc + nb*16 + lm)*72 + lq*8];
      bfr[nb][1] = *(bf16x8*)&Wl[(wc + nb*16 + lm)*72 + 32 + lq*8];
    }
    __builtin_amdgcn_s_setprio(1);
#pragma unroll
    for (int mb = 0; mb < MB; ++mb)
#pragma unroll
      for (int nb = 0; nb < 4; ++nb) {
        acc[mb][nb] = MFMA16(af[mb][0], bfr[nb][0], acc[mb][nb]);
        acc[mb][nb] = MFMA16(af[mb][1], bfr[nb][1], acc[mb][nb]);
      }
    __builtin_amdgcn_s_setprio(0);
    __syncthreads();
  }
#pragma unroll
  for (int mb = 0; mb < MB; ++mb) {
#pragma unroll
    for (int nb = 0; nb < 4; ++nb) {
#pragma unroll
      for (int r = 0; r < 4; ++r) {
        int grow = row0 + wr + mb*16 + lq*4 + r;
        int gcol = col0 + wc + nb*16 + lm;
        float v = acc[mb][nb][r];
        float bv = 0.f, scl = scale;
        if (DUALW && gcol >= 256) {
          if (biasb) bv = biasb[gcol - 256];
          scl = scaleb;
        } else if (bias) {
          bv = bias[WPERM ? ((gcol & 255)*3 + (gcol >> 8)) : gcol];
        }
        v = (v + bv) * scl;
        if (resid) v += resid[(size_t)grow*O + gcol];
        C[(size_t)grow*O + gcol] = (TO)v;
      }
    }
  }
}

// ---------------- mm64d: 64x64 tile GEMM, exact mv64 schedule ----------------
// C = A(bf16) @ W(float)^T + bias (+resid). The mv64 configuration verbatim:
// 36 KB doubled LDS (4 blocks/CU), ~80 VGPR, register prefetch, ONE barrier
// per K-step. mv64 measures ~290 TF effective on this problem at this exact
// occupancy; rounds 9/12 failed by violating it (single-buffer / 70 KB LDS).
// Per-output accumulation order identical to mm_kernel<64> (same bf16
// conversions, ascending-k MFMA pairs) -> bit-identical results.
template<typename TO>
__global__ __launch_bounds__(256) void mm64d_kernel(
    const bf16* __restrict__ A, int K, const float* __restrict__ W,
    const float* __restrict__ bias, TO* __restrict__ C, int O,
    const float* __restrict__ resid)
{
  __shared__ __align__(16) bf16 Al[2][64*72];
  __shared__ __align__(16) bf16 Wl[2][64*72];
  int tid = threadIdx.x;
  int row0 = blockIdx.x*64, col0 = blockIdx.y*64;
  int lane = tid & 63, w = tid >> 6;
  int wr = (w>>1)*32, wc = (w&1)*32;
  int lm = lane & 15, lq = lane >> 4;
  int sr0 = tid >> 3, c8 = (tid & 7)*8;
  int sr1 = sr0 + 32;
  const bf16*  a0ptr = A + (size_t)(row0+sr0)*K + c8;
  const bf16*  a1ptr = A + (size_t)(row0+sr1)*K + c8;
  const float* w0ptr = W + (size_t)(col0+sr0)*K + c8;
  const float* w1ptr = W + (size_t)(col0+sr1)*K + c8;

  floatx4 acc[2][2];
#pragma unroll
  for (int mb = 0; mb < 2; ++mb)
#pragma unroll
    for (int nb = 0; nb < 2; ++nb) acc[mb][nb] = (floatx4){0.f,0.f,0.f,0.f};

  uint4 ra0 = *(const uint4*)a0ptr;
  uint4 ra1 = *(const uint4*)a1ptr;
  Raw8<float> rw0, rw1;
  rw0.load(w0ptr); rw1.load(w1ptr);
  *(uint4*)&Al[0][sr0*72 + c8] = ra0;
  *(uint4*)&Al[0][sr1*72 + c8] = ra1;
  rw0.storeb(&Wl[0][sr0*72 + c8]);
  rw1.storeb(&Wl[0][sr1*72 + c8]);
  __syncthreads();

  for (int k0 = 0; k0 < K; k0 += 64) {
    int cur = (k0 >> 6) & 1;
    bool pre = (k0 + 64 < K);
    if (pre) {
      ra0 = *(const uint4*)(a0ptr + k0 + 64);
      ra1 = *(const uint4*)(a1ptr + k0 + 64);
      rw0.load(w0ptr + k0 + 64);
      rw1.load(w1ptr + k0 + 64);
    }
    bf16x8 af0[2], af1[2], b0[2], b1[2];
#pragma unroll
    for (int mb = 0; mb < 2; ++mb) {
      af0[mb] = *(bf16x8*)&Al[cur][(wr + mb*16 + lm)*72 + lq*8];
      af1[mb] = *(bf16x8*)&Al[cur][(wr + mb*16 + lm)*72 + 32 + lq*8];
    }
#pragma unroll
    for (int nb = 0; nb < 2; ++nb) {
      b0[nb] = *(bf16x8*)&Wl[cur][(wc + nb*16 + lm)*72 + lq*8];
      b1[nb] = *(bf16x8*)&Wl[cur][(wc + nb*16 + lm)*72 + 32 + lq*8];
    }
    __builtin_amdgcn_s_setprio(1);
#pragma unroll
    for (int mb = 0; mb < 2; ++mb)
#pragma unroll
      for (int nb = 0; nb < 2; ++nb) {
        acc[mb][nb] = MFMA16(af0[mb], b0[nb], acc[mb][nb]);
        acc[mb][nb] = MFMA16(af1[mb], b1[nb], acc[mb][nb]);
      }
    __builtin_amdgcn_s_setprio(0);
    if (pre) {
      *(uint4*)&Al[cur^1][sr0*72 + c8] = ra0;
      *(uint4*)&Al[cur^1][sr1*72 + c8] = ra1;
      rw0.storeb(&Wl[cur^1][sr0*72 + c8]);
      rw1.storeb(&Wl[cur^1][sr1*72 + c8]);
    }
    __syncthreads();
  }
#pragma unroll
  for (int mb = 0; mb < 2; ++mb) {
#pragma unroll
    for (int nb = 0; nb < 2; ++nb) {
#pragma unroll
      for (int r = 0; r < 4; ++r) {
        int grow = row0 + wr + mb*16 + lq*4 + r;
        int gcol = col0 + wc + nb*16 + lm;
        float v = acc[mb][nb][r] + bias[gcol];
        if (resid) v += resid[(size_t)grow*O + gcol];
        C[(size_t)grow*O + gcol] = (TO)v;
      }
    }
  }
}

// ---------------- MFMA matvec-GEMM, 64x64 tile, BK=64, batched over z --------
// fp16 staging/MFMA (CG phase). Double-buffered LDS + register prefetch:
// one barrier per K-step, global latency hidden under MFMA. Deterministic.
template<typename TA, typename TW, typename TO>
__global__ __launch_bounds__(256) void mv64_kernel(
    const TA* __restrict__ A, int K, const TW* __restrict__ W,
    TO* __restrict__ C, int O,
    const float* __restrict__ resid, const float* __restrict__ lam_ptr,
    const float* __restrict__ rowdiv,
    long zsA, long zsW, long zsC, long zsR)
{
  __shared__ __align__(16) fp16 Al[2][64*72];
  __shared__ __align__(16) fp16 Wl[2][64*72];
  int tid = threadIdx.x;
  int z = blockIdx.z;
  const TA* Az = A + (size_t)z*zsA;
  const TW* Wz = W + (size_t)z*zsW;
  TO* Cz = C + (size_t)z*zsC;
  const float* Rz = resid ? (resid + (size_t)z*zsR) : (const float*)0;
  int row0 = blockIdx.x*64, col0 = blockIdx.y*64;
  int lane = tid & 63, w = tid >> 6;
  int wr = (w>>1)*32, wc = (w&1)*32;
  int lm = lane & 15, lq = lane >> 4;
  int sr0 = tid >> 3, c8 = (tid & 7)*8;
  int sr1 = sr0 + 32;
  floatx4 acc[2][2];
#pragma unroll
  for (int mb = 0; mb < 2; ++mb)
#pragma unroll
    for (int nb = 0; nb < 2; ++nb) acc[mb][nb] = (floatx4){0.f,0.f,0.f,0.f};

  Raw8<TA> a0p, a1p; Raw8<TW> w0p, w1p;
  a0p.load(&Az[(size_t)(row0+sr0)*K + c8]);
  a1p.load(&Az[(size_t)(row0+sr1)*K + c8]);
  w0p.load(&Wz[(size_t)(col0+sr0)*K + c8]);
  w1p.load(&Wz[(size_t)(col0+sr1)*K + c8]);
  a0p.store(&Al[0][sr0*72 + c8]); a1p.store(&Al[0][sr1*72 + c8]);
  w0p.store(&Wl[0][sr0*72 + c8]); w1p.store(&Wl[0][sr1*72 + c8]);
  __syncthreads();

  for (int k0 = 0; k0 < K; k0 += 64) {
    int cur = (k0 >> 6) & 1;
    bool pre = (k0 + 64 < K);
    if (pre) {
      a0p.load(&Az[(size_t)(row0+sr0)*K + k0+64 + c8]);
      a1p.load(&Az[(size_t)(row0+sr1)*K + k0+64 + c8]);
      w0p.load(&Wz[(size_t)(col0+sr0)*K + k0+64 + c8]);
      w1p.load(&Wz[(size_t)(col0+sr1)*K + k0+64 + c8]);
    }
    fp16x8 a0[2], a1[2], b0[2], b1[2];
#pragma unroll
    for (int mb = 0; mb < 2; ++mb) {
      a0[mb] = *(fp16x8*)&Al[cur][(wr + mb*16 + lm)*72 + lq*8];
      a1[mb] = *(fp16x8*)&Al[cur][(wr + mb*16 + lm)*72 + 32 + lq*8];
    }
#pragma unroll
    for (int nb = 0; nb < 2; ++nb) {
      b0[nb] = *(fp16x8*)&Wl[cur][(wc + nb*16 + lm)*72 + lq*8];
      b1[nb] = *(fp16x8*)&Wl[cur][(wc + nb*16 + lm)*72 + 32 + lq*8];
    }
    __builtin_amdgcn_s_setprio(1);
#pragma unroll
    for (int mb = 0; mb < 2; ++mb)
#pragma unroll
      for (int nb = 0; nb < 2; ++nb) {
        acc[mb][nb] = MFMA16H(a0[mb], b0[nb], acc[mb][nb]);
        acc[mb][nb] = MFMA16H(a1[mb], b1[nb], acc[mb][nb]);
      }
    __builtin_amdgcn_s_setprio(0);
    if (pre) {
      a0p.store(&Al[cur^1][sr0*72 + c8]); a1p.store(&Al[cur^1][sr1*72 + c8]);
      w0p.store(&Wl[cur^1][sr0*72 + c8]); w1p.store(&Wl[cur^1][sr1*72 + c8]);
    }
    __syncthreads();
  }
  float lamv = 1.f;
  if (lam_ptr) lamv = softplusf(lam_ptr[0]) + 1e-6f;
#pragma unroll
  for (int mb = 0; mb < 2; ++mb) {
#pragma unroll
    for (int nb = 0; nb < 2; ++nb) {
#pragma unroll
      for (int r = 0; r < 4; ++r) {
        int grow = row0 + wr + mb*16 + lq*4 + r;
        int gcol = col0 + wc + nb*16 + lm;
        float v = acc[mb][nb][r];
        if (rowdiv) v /= rowdiv[(size_t)z*KM + grow];
        if (Rz) v += lamv * Rz[(size_t)grow*O + gcol];
        Cz[(size_t)grow*O + gcol] = (TO)v;
      }
    }
  }
}

// ---------------- fp32 tile GEMM (head only, O=64) ----------------
__global__ __launch_bounds__(256) void gemm_f32_kernel(
    const float* __restrict__ A, int K,
    const float* __restrict__ W, const float* __restrict__ bias,
    float* __restrict__ C, int O)
{
  __shared__ float As[32][68];
  __shared__ float Ws[32][68];
  int t = threadIdx.x;
  int row0 = blockIdx.x * 64;
  int col0 = blockIdx.y * 64;
  int ti = t & 15, tj = t >> 4;
  float acc[4][4] = {};
  for (int k0 = 0; k0 < K; k0 += 32) {
#pragma unroll
    for (int p = 0; p < 2; ++p) {
      int idx = p*256 + t;
      int ar = idx >> 3, af = (idx & 7)*4;
      float4 av = *(const float4*)&A[(size_t)(row0+ar)*K + k0 + af];
      As[af+0][ar] = av.x; As[af+1][ar] = av.y;
      As[af+2][ar] = av.z; As[af+3][ar] = av.w;
      float4 wv = *(const float4*)&W[(size_t)(col0+ar)*K + k0 + af];
      Ws[af+0][ar] = wv.x; Ws[af+1][ar] = wv.y;
      Ws[af+2][ar] = wv.z; Ws[af+3][ar] = wv.w;
    }
    __syncthreads();
#pragma unroll
    for (int kk = 0; kk < 32; ++kk) {
      float4 a4 = *(float4*)&As[kk][ti*4];
      float4 b4 = *(float4*)&Ws[kk][tj*4];
      float a[4] = {a4.x, a4.y, a4.z, a4.w};
      float b[4] = {b4.x, b4.y, b4.z, b4.w};
#pragma unroll
      for (int x = 0; x < 4; ++x)
#pragma unroll
        for (int y = 0; y < 4; ++y) acc[x][y] += a[x]*b[y];
    }
    __syncthreads();
  }
#pragma unroll
  for (int x = 0; x < 4; ++x) {
    int r = row0 + ti*4 + x;
#pragma unroll
    for (int y = 0; y < 4; ++y) {
      int c = col0 + tj*4 + y;
      float v = fmaxf(acc[x][y] + bias[c], 0.f);
      C[(size_t)r*O + c] = v;
    }
  }
}

// ---------------- transpose-init: PT=RT=F^T, XT=0 (no atomics) --------------
__global__ __launch_bounds__(256) void tinit_kernel(
    const float* __restrict__ F, float* __restrict__ PT, float* __restrict__ RT,
    float* __restrict__ XT)
{
  __shared__ float Ls[64][68];
  int t = threadIdx.x;
  int k0 = blockIdx.x*64, n0 = blockIdx.y*64, z = blockIdx.z;
#pragma unroll
  for (int p = 0; p < 4; ++p) {
    int idx = p*256 + t;
    int kr = idx >> 4, c4 = (idx & 15)*4;
    *(float4*)&Ls[kr][c4] = *(const float4*)&F[((size_t)z*KM + k0+kr)*DD + n0 + c4];
  }
  __syncthreads();
#pragma unroll
  for (int p = 0; p < 4; ++p) {
    int idx = p*256 + t;
    int nl = idx >> 4, k4 = (idx & 15)*4;
    float4 v = { Ls[k4+0][nl], Ls[k4+1][nl], Ls[k4+2][nl], Ls[k4+3][nl] };
    size_t o = ((size_t)z*DD + n0+nl)*KM + k0 + k4;
    *(float4*)&PT[o] = v;
    *(float4*)&RT[o] = v;
    float4 zr = {0.f,0.f,0.f,0.f};
    *(float4*)&XT[o] = zr;
  }
}

// ---------------- merged CG update (self-contained, deterministic) ----------
__global__ __launch_bounds__(256) void cg_update_kernel(
    float* __restrict__ XT, float* __restrict__ RT,
    float* __restrict__ PT, const float* __restrict__ APT)
{
  __shared__ float redw[12];
  int row = blockIdx.x;
  int t = threadIdx.x;
  int lane = t & 63, w = t >> 6;
  size_t base = (size_t)row*KM + (size_t)t*4;
  float4 p4 = *(float4*)&PT[base];
  float4 a4 = *(const float4*)&APT[base];
  float4 r4 = *(float4*)&RT[base];
  float4 x4 = *(float4*)&XT[base];
  float prr  = (r4.x*r4.x + r4.y*r4.y) + (r4.z*r4.z + r4.w*r4.w);
  float ppap = (p4.x*a4.x + p4.y*a4.y) + (p4.z*a4.z + p4.w*a4.w);
  prr = wred(prr); ppap = wred(ppap);
  if (lane == 0) { redw[w] = prr; redw[4+w] = ppap; }
  __syncthreads();
  float rr  = (redw[0]+redw[1]) + (redw[2]+redw[3]);
  float pap = (redw[4]+redw[5]) + (redw[6]+redw[7]);
  float alpha = (pap > 1e-30f) ? rr/pap : 0.f;
  x4.x += alpha*p4.x; x4.y += alpha*p4.y; x4.z += alpha*p4.z; x4.w += alpha*p4.w;
  r4.x -= alpha*a4.x; r4.y -= alpha*a4.y; r4.z -= alpha*a4.z; r4.w -= alpha*a4.w;
  *(float4*)&XT[base] = x4;
  *(float4*)&RT[base] = r4;
  float s = (r4.x*r4.x + r4.y*r4.y) + (r4.z*r4.z + r4.w*r4.w);
  s = wred(s);
  if (lane == 0) redw[8+w] = s;
  __syncthreads();
  float rrnew = (redw[8]+redw[9]) + (redw[10]+redw[11]);
  float beta = (rr > 1e-30f) ? rrnew/rr : 0.f;
  p4.x = r4.x + beta*p4.x; p4.y = r4.y + beta*p4.y;
  p4.z = r4.z + beta*p4.z; p4.w = r4.w + beta*p4.w;
  *(float4*)&PT[base] = p4;
}

// ---------------- RoPE (coalesced, de-interleaved QKV) ----------------
__global__ __launch_bounds__(256) void rope_split_kernel(
    const bf16* __restrict__ qkv, const float* __restrict__ enc0,
    const float* __restrict__ enc1, bf16* __restrict__ Qo,
    bf16* __restrict__ Ko)
{
  int t = threadIdx.x;
  int r = blockIdx.x*2 + (t >> 7);
  int c = (t & 127)*2;                    // even col
  int ts = r >> 10, i = r & 1023;
  int d = c & 63;
  const float* enc = (ts < BB) ? enc0 : enc1;
  int s = (ts < BB) ? ts : ts - BB;
  const float* eb = enc + (((size_t)s*2)*KM + i)*HD;
  float2 cs = *(const float2*)&eb[d];
  float2 sn = *(const float2*)&eb[(size_t)KM*HD + d];
  size_t base = (size_t)r*768;
  bf16x2 qv = *(const bf16x2*)&qkv[base + c];
  bf16x2 kv = *(const bf16x2*)&qkv[base + 256 + c];
  float q0 = (float)qv[0], q1 = (float)qv[1];
  float k0 = (float)kv[0], k1 = (float)kv[1];
  float oq0 = q0*cs.x - q1*sn.x, oq1 = q1*cs.y + q0*sn.y;
  float ok0 = k0*cs.x - k1*sn.x, ok1 = k1*cs.y + k0*sn.y;
  size_t o = (size_t)r*DD + c;
  bf16x2 qo = {(bf16)(0.1803368801f*oq0), (bf16)(0.1803368801f*oq1)};
  bf16x2 ko = {(bf16)ok0, (bf16)ok1};
  *(bf16x2*)&Qo[o] = qo;
  *(bf16x2*)&Ko[o] = ko;
}

// ---------------- V -> V^T transpose (per (stream,head)), strided src -------
__global__ __launch_bounds__(256) void vt_kernel(
    const bf16* __restrict__ Vin, int vstride, bf16* __restrict__ VT)
{
  __shared__ __align__(16) bf16 Ls[64*72];
  int tid = threadIdx.x;
  int zh = blockIdx.x;
  int ts = zh >> 2, h = zh & 3;
  int k0 = blockIdx.y * 64;
#pragma unroll
  for (int p = 0; p < 2; ++p) {
    int idx = p*256 + tid;
    int kr = idx >> 3, c8 = (idx & 7)*8;
    *(uint4*)&Ls[kr*72 + c8] =
      *(const uint4*)&Vin[((size_t)ts*KM + k0 + kr)*vstride + h*HD + c8];
  }
  __syncthreads();
#pragma unroll
  for (int p = 0; p < 2; ++p) {
    int idx = p*256 + tid;
    int dr = idx >> 3, k8 = (idx & 7)*8;
    bf16 tmp[8] __attribute__((aligned(16)));
#pragma unroll
    for (int j = 0; j < 8; ++j) tmp[j] = Ls[(k8+j)*72 + dr];
    *(uint4*)&VT[((size_t)zh*HD + dr)*KM + k0 + k8] = *(uint4*)tmp;
  }
}

// ---------------- MFMA flash attention body (S^T scheme, V^T input) ----------
__device__ __forceinline__ void mha_body(
    const bf16* __restrict__ Qg, const bf16* __restrict__ Kg,
    const bf16* __restrict__ VTg, bf16* __restrict__ Og,
    size_t qkbase, size_t obase, size_t vbase, int qkstride,
    int q0, int tid, bf16* Qs, bf16* Ks, bf16* Vt)
{
  int lane = tid & 63, w = tid >> 6;
  int lm = lane & 15, lq = lane >> 4;
  int r0 = tid >> 3, c8 = (tid & 7)*8;
  int r1 = r0 + 32;
  *(uint4*)&Qs[SWZ(r0,c8)] = *(const uint4*)&Qg[qkbase + (size_t)(q0+r0)*qkstride + c8];
  *(uint4*)&Qs[SWZ(r1,c8)] = *(const uint4*)&Qg[qkbase + (size_t)(q0+r1)*qkstride + c8];
  __syncthreads();
  bf16x8 qa0 = *(bf16x8*)&Qs[SWZ(w*16 + lm, lq*8)];
  bf16x8 qa1 = *(bf16x8*)&Qs[SWZ(w*16 + lm, 32 + lq*8)];
  short4v ones4;
  { bf16x4 o1 = {(bf16)1.f,(bf16)1.f,(bf16)1.f,(bf16)1.f};
    __builtin_memcpy(&ones4, &o1, 8); }
  float m_ = 0.f;
  floatx4 lacc = (floatx4){0.f,0.f,0.f,0.f};
  floatx4 oacc[4];
#pragma unroll
  for (int db = 0; db < 4; ++db) oacc[db] = (floatx4){0.f,0.f,0.f,0.f};

  for (int kt = 0; kt < KM; kt += 64) {
    __syncthreads();
    *(uint4*)&Ks[SWZ(r0,c8)] = *(const uint4*)&Kg[qkbase + (size_t)(kt+r0)*qkstride + c8];
    *(uint4*)&Ks[SWZ(r1,c8)] = *(const uint4*)&Kg[qkbase + (size_t)(kt+r1)*qkstride + c8];
    *(uint4*)&Vt[SWZ(r0,c8)] = *(const uint4*)&VTg[vbase + (size_t)r0*KM + kt + c8];
    *(uint4*)&Vt[SWZ(r1,c8)] = *(const uint4*)&VTg[vbase + (size_t)r1*KM + kt + c8];
    __syncthreads();
    floatx4 st[4];
    float negm = -m_;
    __builtin_amdgcn_s_setprio(1);
#pragma unroll
    for (int kb = 0; kb < 4; ++kb) {
      bf16x8 a0 = *(bf16x8*)&Ks[SWZ(kb*16 + lm, lq*8)];
      bf16x8 a1 = *(bf16x8*)&Ks[SWZ(kb*16 + lm, 32 + lq*8)];
      floatx4 acc = (floatx4){negm, negm, negm, negm};
      acc = MFMA16(a0, qa0, acc);
      acc = MFMA16(a1, qa1, acc);
      st[kb] = acc;
    }
    __builtin_amdgcn_s_setprio(0);
    // local max, max3-shaped (16 -> 8 ops)
    float ma = fmaxf(fmaxf(st[0][0], st[0][1]), st[0][2]);
    float mb = fmaxf(fmaxf(st[0][3], st[1][0]), st[1][1]);
    float mc = fmaxf(fmaxf(st[1][2], st[1][3]), st[2][0]);
    float md = fmaxf(fmaxf(st[2][1], st[2][2]), st[2][3]);
    float me = fmaxf(fmaxf(st[3][0], st[3][1]), st[3][2]);
    float mf = fmaxf(fmaxf(ma, mb), st[3][3]);
    float mg = fmaxf(fmaxf(mc, md), me);
    float mx = fmaxf(mf, mg);
    // defer-max: wave-uniform test; shfls + subs only when a rescale is needed
    if (!__all(mx <= 8.f)) {
      float wmx = fmaxf(mx, __shfl_xor(mx, 16));
      wmx = fmaxf(wmx, __shfl_xor(wmx, 32));
      float delta = fmaxf(wmx, 0.f);
      float al = exp2f(-delta);
      m_ += delta;
      lacc[0] *= al; lacc[1] *= al; lacc[2] *= al; lacc[3] *= al;
#pragma unroll
      for (int db = 0; db < 4; ++db) {
        oacc[db][0] *= al; oacc[db][1] *= al;
        oacc[db][2] *= al; oacc[db][3] *= al;
      }
#pragma unroll
      for (int kb = 0; kb < 4; ++kb) {
        st[kb][0] -= delta; st[kb][1] -= delta;
        st[kb][2] -= delta; st[kb][3] -= delta;
      }
    }
    __builtin_amdgcn_s_setprio(1);
#pragma unroll
    for (int kb = 0; kb < 4; ++kb) {
      float p0 = exp2f(st[kb][0]);
      float p1 = exp2f(st[kb][1]);
      float p2 = exp2f(st[kb][2]);
      float p3 = exp2f(st[kb][3]);
      short4v pb = pack4(p0, p1, p2, p3);
      lacc = MFMA1K(ones4, pb, lacc);
#pragma unroll
      for (int db = 0; db < 4; ++db) {
        short4v va = *(const short4v*)&Vt[SWZ(db*16 + lm, kb*16 + lq*4)];
        oacc[db] = MFMA1K(va, pb, oacc[db]);
      }
    }
    __builtin_amdgcn_s_setprio(0);
  }
  float inv = 1.f / lacc[0];
  int q = q0 + w*16 + lm;
#pragma unroll
  for (int db = 0; db < 4; ++db) {
    bf16x4 o4 = { (bf16)(oacc[db][0]*inv), (bf16)(oacc[db][1]*inv),
                  (bf16)(oacc[db][2]*inv), (bf16)(oacc[db][3]*inv) };
    *(bf16x4*)&Og[obase + (size_t)q*DD + db*16 + lq*4] = o4;
  }
}

// self attention: grid (zh=64, qtile=16); Q/K row stride 256
__global__ __launch_bounds__(256) void mha_kernel(
    const bf16* __restrict__ Qg, const bf16* __restrict__ Kg,
    const bf16* __restrict__ VTg, bf16* __restrict__ Og)
{
  __shared__ __align__(16) bf16 Qs[64*64];
  __shared__ __align__(16) bf16 Ks[64*64];
  __shared__ __align__(16) bf16 Vt[64*64];
  int zh = blockIdx.x;
  int z = zh >> 2, h = zh & 3;
  size_t base = ((size_t)z*KM)*DD + (size_t)h*HD;
  size_t vbase = (size_t)zh*HD*KM;
  mha_body(Qg, Kg, VTg, Og, base, base, vbase, DD,
           blockIdx.y*64, threadIdx.x, Qs, Ks, Vt);
}

// cross attention, both directions: grid (zh=32, qtile=16, dir=2)
__global__ __launch_bounds__(256) void mha_cross_kernel(
    const bf16* __restrict__ QKV2, const bf16* __restrict__ VT2,
    bf16* __restrict__ ATTO2)
{
  __shared__ __align__(16) bf16 Qs[64*64];
  __shared__ __align__(16) bf16 Ks[64*64];
  __shared__ __align__(16) bf16 Vt[64*64];
  int dir = blockIdx.z;
  const bf16* Qg  = QKV2 + (dir ? (size_t)BN*512 : 0);
  const bf16* Kg  = QKV2 + (dir ? 0 : (size_t)BN*512);
  const bf16* VTg = VT2  + (dir ? 0 : (size_t)32*HD*KM);
  bf16*       Og  = ATTO2 + (dir ? (size_t)BN*DD : 0);
  int zh = blockIdx.x;
  int z = zh >> 2, h = zh & 3;
  size_t qkbase = ((size_t)z*KM)*512 + (size_t)h*HD;
  size_t obase  = ((size_t)z*KM)*DD  + (size_t)h*HD;
  size_t vbase  = (size_t)zh*HD*KM;
  mha_body(Qg, Kg, VTg, Og, qkbase, obase, vbase, 512,
           blockIdx.y*64, threadIdx.x, Qs, Ks, Vt);
}

// ---------------- in-place LayerNorm + exact GELU (bf16, width 512) --------
__global__ __launch_bounds__(256) void ln_gelu_kernel(
    bf16* __restrict__ Hb, const float* __restrict__ g,
    const float* __restrict__ be)
{
  int t = threadIdx.x;
  int lane = t & 63, w = t >> 6;
  size_t r = (size_t)blockIdx.x*4 + w;
  bf16* rowp = Hb + r*512 + lane*8;
  bf16x8 hv = *(bf16x8*)rowp;
  float x[8];
#pragma unroll
  for (int j = 0; j < 8; ++j) x[j] = (float)hv[j];
  float s = ((x[0]+x[1]) + (x[2]+x[3])) + ((x[4]+x[5]) + (x[6]+x[7]));
  s = wred(s);
  float mu = s * (1.f/512.f);
  float v = 0.f;
#pragma unroll
  for (int j = 0; j < 8; ++j) { float d = x[j] - mu; v += d*d; }
  v = wred(v);
  float rstd = rsqrtf(v*(1.f/512.f) + 1e-5f);
  float4 g0 = *(const float4*)&g[lane*8];
  float4 g1 = *(const float4*)&g[lane*8 + 4];
  float4 b0 = *(const float4*)&be[lane*8];
  float4 b1 = *(const float4*)&be[lane*8 + 4];
  float gv[8] = {g0.x,g0.y,g0.z,g0.w,g1.x,g1.y,g1.z,g1.w};
  float bv[8] = {b0.x,b0.y,b0.z,b0.w,b1.x,b1.y,b1.z,b1.w};
  bf16x8 ov;
#pragma unroll
  for (int j = 0; j < 8; ++j) {
    float h = (x[j] - mu)*rstd*gv[j] + bv[j];
    h = 0.5f*h*(1.f + erff(h*0.70710678118f));
    ov[j] = (bf16)h;
  }
  *(bf16x8*)rowp = ov;
}

// ---------------- final head 2 ----------------
__global__ __launch_bounds__(256) void head2_kernel(
    const float* __restrict__ Hb, const float* __restrict__ w,
    const float* __restrict__ b, float* __restrict__ out)
{
  int r = blockIdx.x*256 + threadIdx.x;
  float acc = b[0];
#pragma unroll
  for (int k = 0; k < 64; ++k) acc += Hb[(size_t)r*64 + k]*w[k];
  out[r] = 1.f/(1.f + expf(-acc));
}

extern "C" void kernel_launch(void* const* d_in, const int* in_sizes, int n_in,
                              void* d_out, int out_size, void* d_ws, size_t ws_size,
                              hipStream_t stream)
{
  (void)in_sizes; (void)n_in; (void)out_size; (void)ws_size;
  const float* fa      = (const float*)d_in[0];
  const float* fb      = (const float*)d_in[1];
  const int*   matches = (const int*)d_in[2];
  const float* ka      = (const float*)d_in[3];
  const float* kb      = (const float*)d_in[4];
  const float* lam     = (const float*)d_in[5];
  const float* beta    = (const float*)d_in[6];
  const float* Wr      = (const float*)d_in[7];
  const float* pW1     = (const float*)d_in[8];
  const float* pb1     = (const float*)d_in[9];
  const float* pW2     = (const float*)d_in[10];
  const float* pb2     = (const float*)d_in[11];
  const float* sWqkv   = (const float*)d_in[12];
  const float* sbqkv   = (const float*)d_in[13];
  const float* sWo     = (const float*)d_in[14];
  const float* sbo     = (const float*)d_in[15];
  const float* sW1     = (const float*)d_in[16];
  const float* sb1     = (const float*)d_in[17];
  const float* sg      = (const float*)d_in[18];
  const float* sbe     = (const float*)d_in[19];
  const float* sW2     = (const float*)d_in[20];
  const float* sb2     = (const float*)d_in[21];
  const float* cWqk    = (const float*)d_in[22];
  const float* cbqk    = (const float*)d_in[23];
  const float* cWv     = (const float*)d_in[24];
  const float* cbv     = (const float*)d_in[25];
  const float* cWo     = (const float*)d_in[26];
  const float* cbo     = (const float*)d_in[27];
  const float* cW1     = (const float*)d_in[28];
  const float* cb1     = (const float*)d_in[29];
  const float* cgw     = (const float*)d_in[30];
  const float* cbe     = (const float*)d_in[31];
  const float* cW2     = (const float*)d_in[32];
  const float* cb2     = (const float*)d_in[33];

  char* wsb = (char*)d_ws;
  float* DCAT = (float*)wsb;                      // 16,777,216 B
  float* ENC0 = (float*)(wsb + 16777216);
  float* ENC1 = (float*)(wsb + 20971520);
  float* XY0  = (float*)(wsb + 25165824);
  float* XY1  = (float*)(wsb + 25231360);
  float* ROWS = (float*)(wsb + 25296896);
  char*  POOL = wsb + 25354240;
  const size_t SLOT = 8388608;
  // CG phase
  fp16*  KMATH = (fp16*)POOL;                    // slots 0-1
  float* FBUF  = (float*)(POOL + 2*SLOT);
  float* PT    = (float*)(POOL + 3*SLOT);
  float* RT    = (float*)(POOL + 4*SLOT);
  float* XT    = (float*)(POOL + 5*SLOT);
  float* APT   = (float*)(POOL + 6*SLOT);
  // transformer phase
  bf16*  QKV   = (bf16*)POOL;                    // slots 0-2 (q|k|v cols)
  bf16*  QR    = (bf16*)(POOL + 3*SLOT);
  bf16*  KR    = (bf16*)(POOL + 4*SLOT);
  bf16*  VTG   = (bf16*)(POOL + 8*SLOT);         // slot 8 (V^T, self)
  bf16*  ATTO  = (bf16*)POOL;                    // slot 0
  bf16*  MSG   = (bf16*)(POOL + 1*SLOT);
  bf16*  H1    = (bf16*)(POOL + 6*SLOT);         // slots 6-7
  bf16*  QKV2  = (bf16*)POOL;                    // slots 0-1 (cross q|v cols)
  bf16*  ATTO2 = (bf16*)(POOL + 2*SLOT);
  bf16*  MSG2  = (bf16*)(POOL + 3*SLOT);
  bf16*  VT2   = (bf16*)(POOL + 4*SLOT);         // slot 4 (V^T, cross)
  bf16*  H1C   = H1;
  float* HBUF  = (float*)POOL;

  const float scq = 0.42466090f;   // 64^-0.25 * sqrt(log2 e)

  // ---- gather / posenc / Kmat ----
  gather_kernel<<<BN, 256, 0, stream>>>(fa, fb, matches, ka, kb, FBUF, DCAT, XY0, XY1);
  posenc_kernel<<<BN/4, 256, 0, stream>>>(XY0, Wr, ENC0);
  posenc_kernel<<<BN/4, 256, 0, stream>>>(XY1, Wr, ENC1);
  kmat_kernel<<<BN, 256, 0, stream>>>(XY0, beta, KMATH, ROWS);

  // ---- CG (transposed state, deterministic: no fp atomics anywhere) ----
  tinit_kernel<<<dim3(16,4,BB), 256, 0, stream>>>(FBUF, PT, RT, XT);
  for (int it = 0; it < CG_ITERS; ++it) {
    mv64_kernel<float,fp16,float><<<dim3(4,16,BB), 256, 0, stream>>>(
        PT, 1024, KMATH, APT, 1024, PT, lam, (const float*)0,
        262144, 1048576, 262144, 262144);
    cg_update_kernel<<<2048, 256, 0, stream>>>(XT, RT, PT, APT);
  }

  // ---- d1 = rownorm(Kmat) @ C  (d0 = f_i already written by gather) ----
  mv64_kernel<fp16,float,float><<<dim3(16,4,BB), 256, 0, stream>>>(
      KMATH, 1024, XT, DCAT + (size_t)BN*DD, 256,
      (const float*)0, (const float*)0, ROWS,
      1048576, 262144, 262144, 0);

  // ---- transformer layers ----
  for (int l = 0; l < NLAYER; ++l) {
    // self block
    mm_kernel<128,1,0,float,float,float,bf16><<<dim3(128,6,1), 256, 0, stream>>>(
        DCAT, (const float*)0, 256, 256, sWqkv + (size_t)l*768*256, sbqkv + l*768,
        (const float*)0, (const float*)0, QKV, 768, 1.f, 1.f, (const float*)0);
    rope_split_kernel<<<8192, 256, 0, stream>>>(QKV, ENC0, ENC1, QR, KR);
    vt_kernel<<<dim3(64,16), 256, 0, stream>>>(QKV + 512, 768, VTG);
    mha_kernel<<<dim3(64,16), 256, 0, stream>>>(QR, KR, VTG, ATTO);
    mm64d_kernel<bf16><<<dim3(256,4,1), 256, 0, stream>>>(
        ATTO, 256, sWo + (size_t)l*256*256, sbo + l*256, MSG, 256,
        (const float*)0);
    mm_kernel<128,0,0,float,bf16,float,bf16><<<dim3(128,4,1), 256, 0, stream>>>(
        DCAT, MSG, 256, 512, sW1 + (size_t)l*512*512, sb1 + l*512,
        (const float*)0, (const float*)0, H1, 512, 1.f, 1.f, (const float*)0);
    ln_gelu_kernel<<<N2/4, 256, 0, stream>>>(H1, sg + l*512, sbe + l*512);
    mm64d_kernel<float><<<dim3(256,4,1), 256, 0, stream>>>(
        H1, 512, sW2 + (size_t)l*256*512, sb2 + l*256, DCAT, 256, DCAT);
    // cross block: fused qk|v projection into QKV2 (row stride 512)
    mm_kernel<128,0,1,float,float,float,bf16><<<dim3(128,4,1), 256, 0, stream>>>(
        DCAT, (const float*)0, 256, 256, cWqk + (size_t)l*256*256, cbqk + l*256,
        cWv + (size_t)l*256*256, cbv + l*256, QKV2, 512, scq, 1.f,
        (const float*)0);
    vt_kernel<<<dim3(64,16), 256, 0, stream>>>(QKV2 + 256, 512, VT2);
    mha_cross_kernel<<<dim3(32,16,2), 256, 0, stream>>>(QKV2, VT2, ATTO2);
    mm64d_kernel<bf16><<<dim3(256,4,1), 256, 0, stream>>>(
        ATTO2, 256, cWo + (size_t)l*256*256, cbo + l*256, MSG2, 256,
        (const float*)0);
    mm_kernel<128,0,0,float,bf16,float,bf16><<<dim3(128,4,1), 256, 0, stream>>>(
        DCAT, MSG2, 256, 512, cW1 + (size_t)l*512*512, cb1 + l*512,
        (const float*)0, (const float*)0, H1C, 512, 1.f, 1.f, (const float*)0);
    ln_gelu_kernel<<<N2/4, 256, 0, stream>>>(H1C, cgw + l*512, cbe + l*512);
    mm64d_kernel<float><<<dim3(256,4,1), 256, 0, stream>>>(
        H1C, 512, cW2 + (size_t)l*256*512, cb2 + l*256, DCAT, 256, DCAT);
  }

  // ---- head ----
  gemm_f32_kernel<<<dim3(128,1), 256, 0, stream>>>(DCAT, 256, pW1, pb1, HBUF, 64);
  head2_kernel<<<32, 256, 0, stream>>>(HBUF, pW2, pb2, (float*)d_out);
}

// Round 17
// 901.001 us; speedup vs baseline: 1.2825x; 1.0308x over previous
//
#include <hip/hip_runtime.h>
#include <math.h>

// Problem constants
#define BB 8
#define MM 2048
#define KM 1024
#define DD 256
#define HH 4
#define HD 64
#define NLAYER 2
#define BN (BB*KM)        // 8192 rows per "decoder half"
#define N2 (2*BN)         // 16384 rows d0||d1
#define CG_ITERS 5

// XOR-swizzled LDS addressing for the attention tiles: stride 64 (no pad),
// 16-byte blocks permuted by row. Conflict-free for uint4 stores, bf16x8
// reads, and short4v reads — and keeps every access 16B/8B aligned.
#define SWZ(r,c) (((r)<<6) + ((((c)>>3) ^ ((r)&7))<<3) + ((c)&7))

typedef __bf16 bf16;
typedef __bf16 bf16x8 __attribute__((ext_vector_type(8)));
typedef __bf16 bf16x4 __attribute__((ext_vector_type(4)));
typedef __bf16 bf16x2 __attribute__((ext_vector_type(2)));
typedef _Float16 fp16;
typedef _Float16 fp16x8 __attribute__((ext_vector_type(8)));
typedef short  short4v __attribute__((ext_vector_type(4)));
typedef float  floatx4 __attribute__((ext_vector_type(4)));
#define MFMA16(a,b,c)  __builtin_amdgcn_mfma_f32_16x16x32_bf16(a,b,c,0,0,0)
#define MFMA16H(a,b,c) __builtin_amdgcn_mfma_f32_16x16x32_f16(a,b,c,0,0,0)

// K=16 bf16 MFMA (PV stage: S^T C-frag == its B-operand layout).
#if defined(__HIP_DEVICE_COMPILE__)
  #if __has_builtin(__builtin_amdgcn_mfma_f32_16x16x16bf16_1k)
    #define MFMA1K(a,b,c) __builtin_amdgcn_mfma_f32_16x16x16bf16_1k(a,b,c,0,0,0)
  #else
    #error "device pass lacks mfma_f32_16x16x16bf16_1k"
  #endif
#else
  #define MFMA1K(a,b,c) (c)   /* host stub, never executed */
#endif

__device__ __forceinline__ float softplusf(float x) {
  return fmaxf(x, 0.f) + log1pf(expf(-fabsf(x)));
}

__device__ __forceinline__ float wred(float x) {
  x += __shfl_xor(x, 1);  x += __shfl_xor(x, 2);  x += __shfl_xor(x, 4);
  x += __shfl_xor(x, 8);  x += __shfl_xor(x, 16); x += __shfl_xor(x, 32);
  return x;
}

__device__ __forceinline__ short4v pack4(float a, float b, float c, float d) {
  bf16x4 v = {(bf16)a,(bf16)b,(bf16)c,(bf16)d};
  short4v s;
  __builtin_memcpy(&s, &v, 8);
  return s;
}

// raw staging (load early / convert+store late)
template<typename T> struct Raw8;
template<> struct Raw8<float> {
  float4 a, b;
  __device__ __forceinline__ void load(const float* s) {
    a = *(const float4*)s; b = *(const float4*)(s + 4);
  }
  __device__ __forceinline__ void store(fp16* d) const {
    fp16x8 v = { (fp16)a.x,(fp16)a.y,(fp16)a.z,(fp16)a.w,
                 (fp16)b.x,(fp16)b.y,(fp16)b.z,(fp16)b.w };
    *(fp16x8*)d = v;
  }
  __device__ __forceinline__ void storeb(bf16* d) const {
    bf16x8 v = { (bf16)a.x,(bf16)a.y,(bf16)a.z,(bf16)a.w,
                 (bf16)b.x,(bf16)b.y,(bf16)b.z,(bf16)b.w };
    *(bf16x8*)d = v;
  }
};
template<> struct Raw8<fp16> {
  uint4 u;
  __device__ __forceinline__ void load(const fp16* s) { u = *(const uint4*)s; }
  __device__ __forceinline__ void store(fp16* d) const { *(uint4*)d = u; }
};
template<> struct Raw8<bf16> {
  uint4 u;
  __device__ __forceinline__ void load(const bf16* s) { u = *(const uint4*)s; }
  __device__ __forceinline__ void storeb(bf16* d) const { *(uint4*)d = u; }
};

// ---------------- gather (writes F to both FBUF and DCAT; no copy pass) -----
__global__ __launch_bounds__(256) void gather_kernel(
    const float* __restrict__ fa, const float* __restrict__ fb,
    const int* __restrict__ matches, const float* __restrict__ ka,
    const float* __restrict__ kb, float* __restrict__ F,
    float* __restrict__ Fd,
    float* __restrict__ xy0, float* __restrict__ xy1)
{
  int si = blockIdx.x;
  int s  = si >> 10;
  int t  = threadIdx.x;
  int ia = matches[(size_t)si*2+0];
  int ib = matches[(size_t)si*2+1];
  float v = fb[((size_t)s*MM + ib)*DD + t] - fa[((size_t)s*MM + ia)*DD + t];
  F[(size_t)si*DD + t]  = v;
  Fd[(size_t)si*DD + t] = v;
  if (t == 0) {
    xy0[(size_t)si*2+0] = ka[((size_t)s*MM + ia)*2+0];
    xy0[(size_t)si*2+1] = ka[((size_t)s*MM + ia)*2+1];
    xy1[(size_t)si*2+0] = kb[((size_t)s*MM + ib)*2+0];
    xy1[(size_t)si*2+1] = kb[((size_t)s*MM + ib)*2+1];
  }
}

// ---------------- positional encoding (4 rows per 256-thread block) ---------
__global__ __launch_bounds__(256) void posenc_kernel(
    const float* __restrict__ xy, const float* __restrict__ Wr,
    float* __restrict__ enc)
{
  int t = threadIdx.x;
  int si = blockIdx.x*4 + (t >> 6);
  int s = si >> 10, i = si & 1023;
  int d = t & 63; int p = d >> 1;
  float x = xy[(size_t)si*2], y = xy[(size_t)si*2+1];
  float pr = Wr[p*2]*x + Wr[p*2+1]*y;
  enc[(((size_t)s*2+0)*KM + i)*HD + d] = cosf(pr);
  enc[(((size_t)s*2+1)*KM + i)*HD + d] = sinf(pr);
}

// ---------------- Kmat (fp16) + rowsum (wave butterflies) -------------------
__global__ __launch_bounds__(256) void kmat_kernel(
    const float* __restrict__ xy0, const float* __restrict__ beta_ptr,
    fp16* __restrict__ Km, float* __restrict__ rowsum)
{
  __shared__ float redw[4];
  int si = blockIdx.x; int s = si >> 10;
  int t = threadIdx.x;
  int lane = t & 63, w = t >> 6;
  float beta_l2 = softplusf(beta_ptr[0]) * 1.442695040888963f;
  float xi = xy0[(size_t)si*2], yi = xy0[(size_t)si*2+1];
  const float* xys = xy0 + (size_t)s*KM*2;
  float sum = 0.f;
  for (int jj = 0; jj < 4; ++jj) {
    int j = jj*256 + t;
    float dx = xi - xys[j*2], dy = yi - xys[j*2+1];
    float v = exp2f(-beta_l2*(dx*dx + dy*dy));
    Km[(size_t)si*KM + j] = (fp16)v;
    sum += v;
  }
  sum = wred(sum);
  if (lane == 0) redw[w] = sum;
  __syncthreads();
  if (t == 0)
    rowsum[si] = ((redw[0]+redw[1]) + (redw[2]+redw[3])) + 1e-6f;
}

// ---------------- mm64g: 64x64 tile GEMM, mv64/mm64d-proven schedule --------
// C = [A1|A2] @ Wsel^T, epilogue (v+bias)*scale (+resid).
// WPERM: W row perm(j)=(j&255)*3+(j>>8)  (qkv channel de-interleave)
// DUALW: cols [0,256) from W/bias/scale, cols [256,512) from Wb/biasb/scaleb
// Schedule identical to mm64d/mv64 (double-buffered 36 KB LDS -> 4 blocks/CU,
// register prefetch, ONE barrier per K-step). Per-output accumulation order
// identical to the old mm_kernel -> bit-identical results.
template<int WPERM, int DUALW, typename TA1, typename TA2, typename TO>
__global__ __launch_bounds__(256) void mm64g_kernel(
    const TA1* __restrict__ A1, const TA2* __restrict__ A2, int K1, int K,
    const float* __restrict__ W, const float* __restrict__ bias,
    const float* __restrict__ Wb, const float* __restrict__ biasb,
    TO* __restrict__ C, int O, float scale, float scaleb,
    const float* __restrict__ resid)
{
  __shared__ __align__(16) bf16 Al[2][64*72];
  __shared__ __align__(16) bf16 Wl[2][64*72];
  int tid = threadIdx.x;
  int row0 = blockIdx.x*64, col0 = blockIdx.y*64;
  int lane = tid & 63, w = tid >> 6;
  int wr = (w>>1)*32, wc = (w&1)*32;
  int lm = lane & 15, lq = lane >> 4;
  int sr0 = tid >> 3, c8 = (tid & 7)*8;
  int sr1 = sr0 + 32;
  int K2 = K - K1;

  const TA1* a1p0 = A1 + (size_t)(row0+sr0)*K1 + c8;
  const TA1* a1p1 = A1 + (size_t)(row0+sr1)*K1 + c8;
  const TA2* a2p0 = A2 + (size_t)(row0+sr0)*K2 + c8;
  const TA2* a2p1 = A2 + (size_t)(row0+sr1)*K2 + c8;
  const float* wp0; const float* wp1;
  {
    int wg0 = col0 + sr0, wg1 = col0 + sr1;
    const float* ws0; int wrow0;
    if (DUALW && wg0 >= 256) { ws0 = Wb; wrow0 = wg0 - 256; }
    else { ws0 = W; wrow0 = WPERM ? ((wg0 & 255)*3 + (wg0 >> 8)) : wg0; }
    const float* ws1; int wrow1;
    if (DUALW && wg1 >= 256) { ws1 = Wb; wrow1 = wg1 - 256; }
    else { ws1 = W; wrow1 = WPERM ? ((wg1 & 255)*3 + (wg1 >> 8)) : wg1; }
    wp0 = ws0 + (size_t)wrow0*K + c8;
    wp1 = ws1 + (size_t)wrow1*K + c8;
  }

  floatx4 acc[2][2];
#pragma unroll
  for (int mb = 0; mb < 2; ++mb)
#pragma unroll
    for (int nb = 0; nb < 2; ++nb) acc[mb][nb] = (floatx4){0.f,0.f,0.f,0.f};

  Raw8<TA1> ra1_0, ra1_1; Raw8<TA2> ra2_0, ra2_1;
  Raw8<float> rw_0, rw_1;
  // prologue: tile 0 (all call sites have K1 >= 64, so tile 0 is A1)
  {
    bool u0 = (0 < K1);
    if (u0) { ra1_0.load(a1p0); ra1_1.load(a1p1); }
    else    { ra2_0.load(a2p0); ra2_1.load(a2p1); }
    rw_0.load(wp0); rw_1.load(wp1);
    if (u0) { ra1_0.storeb(&Al[0][sr0*72 + c8]); ra1_1.storeb(&Al[0][sr1*72 + c8]); }
    else    { ra2_0.storeb(&Al[0][sr0*72 + c8]); ra2_1.storeb(&Al[0][sr1*72 + c8]); }
    rw_0.storeb(&Wl[0][sr0*72 + c8]);
    rw_1.storeb(&Wl[0][sr1*72 + c8]);
    __syncthreads();
  }

  int nst = K >> 6;
  for (int j = 0; j < nst; ++j) {
    int cur = j & 1;
    bool pre = (j + 1 < nst);
    bool nUse1 = (((j+1) << 6) < K1);
    if (pre) {
      int k1n = (j+1) << 6;
      if (nUse1) { ra1_0.load(a1p0 + k1n); ra1_1.load(a1p1 + k1n); }
      else       { ra2_0.load(a2p0 + (k1n - K1)); ra2_1.load(a2p1 + (k1n - K1)); }
      rw_0.load(wp0 + k1n); rw_1.load(wp1 + k1n);
    }
    bf16x8 af0[2], af1[2], b0[2], b1[2];
#pragma unroll
    for (int mb = 0; mb < 2; ++mb) {
      af0[mb] = *(bf16x8*)&Al[cur][(wr + mb*16 + lm)*72 + lq*8];
      af1[mb] = *(bf16x8*)&Al[cur][(wr + mb*16 + lm)*72 + 32 + lq*8];
    }
#pragma unroll
    for (int nb = 0; nb < 2; ++nb) {
      b0[nb] = *(bf16x8*)&Wl[cur][(wc + nb*16 + lm)*72 + lq*8];
      b1[nb] = *(bf16x8*)&Wl[cur][(wc + nb*16 + lm)*72 + 32 + lq*8];
    }
    __builtin_amdgcn_s_setprio(1);
#pragma unroll
    for (int mb = 0; mb < 2; ++mb)
#pragma unroll
      for (int nb = 0; nb < 2; ++nb) {
        acc[mb][nb] = MFMA16(af0[mb], b0[nb], acc[mb][nb]);
        acc[mb][nb] = MFMA16(af1[mb], b1[nb], acc[mb][nb]);
      }
    __builtin_amdgcn_s_setprio(0);
    if (pre) {
      if (nUse1) {
        ra1_0.storeb(&Al[cur^1][sr0*72 + c8]);
        ra1_1.storeb(&Al[cur^1][sr1*72 + c8]);
      } else {
        ra2_0.storeb(&Al[cur^1][sr0*72 + c8]);
        ra2_1.storeb(&Al[cur^1][sr1*72 + c8]);
      }
      rw_0.storeb(&Wl[cur^1][sr0*72 + c8]);
      rw_1.storeb(&Wl[cur^1][sr1*72 + c8]);
    }
    __syncthreads();
  }
#pragma unroll
  for (int mb = 0; mb < 2; ++mb) {
#pragma unroll
    for (int nb = 0; nb < 2; ++nb) {
#pragma unroll
      for (int r = 0; r < 4; ++r) {
        int grow = row0 + wr + mb*16 + lq*4 + r;
        int gcol = col0 + wc + nb*16 + lm;
        float v = acc[mb][nb][r];
        float bv = 0.f, scl = scale;
        if (DUALW && gcol >= 256) {
          if (biasb) bv = biasb[gcol - 256];
          scl = scaleb;
        } else if (bias) {
          bv = bias[WPERM ? ((gcol & 255)*3 + (gcol >> 8)) : gcol];
        }
        v = (v + bv) * scl;
        if (resid) v += resid[(size_t)grow*O + gcol];
        C[(size_t)grow*O + gcol] = (TO)v;
      }
    }
  }
}

// ---------------- mm64d: 64x64 tile GEMM, exact mv64 schedule ----------------
// C = A(bf16) @ W(float)^T + bias (+resid). Proven round-15 configuration.
template<typename TO>
__global__ __launch_bounds__(256) void mm64d_kernel(
    const bf16* __restrict__ A, int K, const float* __restrict__ W,
    const float* __restrict__ bias, TO* __restrict__ C, int O,
    const float* __restrict__ resid)
{
  __shared__ __align__(16) bf16 Al[2][64*72];
  __shared__ __align__(16) bf16 Wl[2][64*72];
  int tid = threadIdx.x;
  int row0 = blockIdx.x*64, col0 = blockIdx.y*64;
  int lane = tid & 63, w = tid >> 6;
  int wr = (w>>1)*32, wc = (w&1)*32;
  int lm = lane & 15, lq = lane >> 4;
  int sr0 = tid >> 3, c8 = (tid & 7)*8;
  int sr1 = sr0 + 32;
  const bf16*  a0ptr = A + (size_t)(row0+sr0)*K + c8;
  const bf16*  a1ptr = A + (size_t)(row0+sr1)*K + c8;
  const float* w0ptr = W + (size_t)(col0+sr0)*K + c8;
  const float* w1ptr = W + (size_t)(col0+sr1)*K + c8;

  floatx4 acc[2][2];
#pragma unroll
  for (int mb = 0; mb < 2; ++mb)
#pragma unroll
    for (int nb = 0; nb < 2; ++nb) acc[mb][nb] = (floatx4){0.f,0.f,0.f,0.f};

  uint4 ra0 = *(const uint4*)a0ptr;
  uint4 ra1 = *(const uint4*)a1ptr;
  Raw8<float> rw0, rw1;
  rw0.load(w0ptr); rw1.load(w1ptr);
  *(uint4*)&Al[0][sr0*72 + c8] = ra0;
  *(uint4*)&Al[0][sr1*72 + c8] = ra1;
  rw0.storeb(&Wl[0][sr0*72 + c8]);
  rw1.storeb(&Wl[0][sr1*72 + c8]);
  __syncthreads();

  for (int k0 = 0; k0 < K; k0 += 64) {
    int cur = (k0 >> 6) & 1;
    bool pre = (k0 + 64 < K);
    if (pre) {
      ra0 = *(const uint4*)(a0ptr + k0 + 64);
      ra1 = *(const uint4*)(a1ptr + k0 + 64);
      rw0.load(w0ptr + k0 + 64);
      rw1.load(w1ptr + k0 + 64);
    }
    bf16x8 af0[2], af1[2], b0[2], b1[2];
#pragma unroll
    for (int mb = 0; mb < 2; ++mb) {
      af0[mb] = *(bf16x8*)&Al[cur][(wr + mb*16 + lm)*72 + lq*8];
      af1[mb] = *(bf16x8*)&Al[cur][(wr + mb*16 + lm)*72 + 32 + lq*8];
    }
#pragma unroll
    for (int nb = 0; nb < 2; ++nb) {
      b0[nb] = *(bf16x8*)&Wl[cur][(wc + nb*16 + lm)*72 + lq*8];
      b1[nb] = *(bf16x8*)&Wl[cur][(wc + nb*16 + lm)*72 + 32 + lq*8];
    }
    __builtin_amdgcn_s_setprio(1);
#pragma unroll
    for (int mb = 0; mb < 2; ++mb)
#pragma unroll
      for (int nb = 0; nb < 2; ++nb) {
        acc[mb][nb] = MFMA16(af0[mb], b0[nb], acc[mb][nb]);
        acc[mb][nb] = MFMA16(af1[mb], b1[nb], acc[mb][nb]);
      }
    __builtin_amdgcn_s_setprio(0);
    if (pre) {
      *(uint4*)&Al[cur^1][sr0*72 + c8] = ra0;
      *(uint4*)&Al[cur^1][sr1*72 + c8] = ra1;
      rw0.storeb(&Wl[cur^1][sr0*72 + c8]);
      rw1.storeb(&Wl[cur^1][sr1*72 + c8]);
    }
    __syncthreads();
  }
#pragma unroll
  for (int mb = 0; mb < 2; ++mb) {
#pragma unroll
    for (int nb = 0; nb < 2; ++nb) {
#pragma unroll
      for (int r = 0; r < 4; ++r) {
        int grow = row0 + wr + mb*16 + lq*4 + r;
        int gcol = col0 + wc + nb*16 + lm;
        float v = acc[mb][nb][r] + bias[gcol];
        if (resid) v += resid[(size_t)grow*O + gcol];
        C[(size_t)grow*O + gcol] = (TO)v;
      }
    }
  }
}

// ---------------- MFMA matvec-GEMM, 64x64 tile, BK=64, batched over z --------
// fp16 staging/MFMA (CG phase). Double-buffered LDS + register prefetch:
// one barrier per K-step, global latency hidden under MFMA. Deterministic.
template<typename TA, typename TW, typename TO>
__global__ __launch_bounds__(256) void mv64_kernel(
    const TA* __restrict__ A, int K, const TW* __restrict__ W,
    TO* __restrict__ C, int O,
    const float* __restrict__ resid, const float* __restrict__ lam_ptr,
    const float* __restrict__ rowdiv,
    long zsA, long zsW, long zsC, long zsR)
{
  __shared__ __align__(16) fp16 Al[2][64*72];
  __shared__ __align__(16) fp16 Wl[2][64*72];
  int tid = threadIdx.x;
  int z = blockIdx.z;
  const TA* Az = A + (size_t)z*zsA;
  const TW* Wz = W + (size_t)z*zsW;
  TO* Cz = C + (size_t)z*zsC;
  const float* Rz = resid ? (resid + (size_t)z*zsR) : (const float*)0;
  int row0 = blockIdx.x*64, col0 = blockIdx.y*64;
  int lane = tid & 63, w = tid >> 6;
  int wr = (w>>1)*32, wc = (w&1)*32;
  int lm = lane & 15, lq = lane >> 4;
  int sr0 = tid >> 3, c8 = (tid & 7)*8;
  int sr1 = sr0 + 32;
  floatx4 acc[2][2];
#pragma unroll
  for (int mb = 0; mb < 2; ++mb)
#pragma unroll
    for (int nb = 0; nb < 2; ++nb) acc[mb][nb] = (floatx4){0.f,0.f,0.f,0.f};

  Raw8<TA> a0p, a1p; Raw8<TW> w0p, w1p;
  a0p.load(&Az[(size_t)(row0+sr0)*K + c8]);
  a1p.load(&Az[(size_t)(row0+sr1)*K + c8]);
  w0p.load(&Wz[(size_t)(col0+sr0)*K + c8]);
  w1p.load(&Wz[(size_t)(col0+sr1)*K + c8]);
  a0p.store(&Al[0][sr0*72 + c8]); a1p.store(&Al[0][sr1*72 + c8]);
  w0p.store(&Wl[0][sr0*72 + c8]); w1p.store(&Wl[0][sr1*72 + c8]);
  __syncthreads();

  for (int k0 = 0; k0 < K; k0 += 64) {
    int cur = (k0 >> 6) & 1;
    bool pre = (k0 + 64 < K);
    if (pre) {
      a0p.load(&Az[(size_t)(row0+sr0)*K + k0+64 + c8]);
      a1p.load(&Az[(size_t)(row0+sr1)*K + k0+64 + c8]);
      w0p.load(&Wz[(size_t)(col0+sr0)*K + k0+64 + c8]);
      w1p.load(&Wz[(size_t)(col0+sr1)*K + k0+64 + c8]);
    }
    fp16x8 a0[2], a1[2], b0[2], b1[2];
#pragma unroll
    for (int mb = 0; mb < 2; ++mb) {
      a0[mb] = *(fp16x8*)&Al[cur][(wr + mb*16 + lm)*72 + lq*8];
      a1[mb] = *(fp16x8*)&Al[cur][(wr + mb*16 + lm)*72 + 32 + lq*8];
    }
#pragma unroll
    for (int nb = 0; nb < 2; ++nb) {
      b0[nb] = *(fp16x8*)&Wl[cur][(wc + nb*16 + lm)*72 + lq*8];
      b1[nb] = *(fp16x8*)&Wl[cur][(wc + nb*16 + lm)*72 + 32 + lq*8];
    }
    __builtin_amdgcn_s_setprio(1);
#pragma unroll
    for (int mb = 0; mb < 2; ++mb)
#pragma unroll
      for (int nb = 0; nb < 2; ++nb) {
        acc[mb][nb] = MFMA16H(a0[mb], b0[nb], acc[mb][nb]);
        acc[mb][nb] = MFMA16H(a1[mb], b1[nb], acc[mb][nb]);
      }
    __builtin_amdgcn_s_setprio(0);
    if (pre) {
      a0p.store(&Al[cur^1][sr0*72 + c8]); a1p.store(&Al[cur^1][sr1*72 + c8]);
      w0p.store(&Wl[cur^1][sr0*72 + c8]); w1p.store(&Wl[cur^1][sr1*72 + c8]);
    }
    __syncthreads();
  }
  float lamv = 1.f;
  if (lam_ptr) lamv = softplusf(lam_ptr[0]) + 1e-6f;
#pragma unroll
  for (int mb = 0; mb < 2; ++mb) {
#pragma unroll
    for (int nb = 0; nb < 2; ++nb) {
#pragma unroll
      for (int r = 0; r < 4; ++r) {
        int grow = row0 + wr + mb*16 + lq*4 + r;
        int gcol = col0 + wc + nb*16 + lm;
        float v = acc[mb][nb][r];
        if (rowdiv) v /= rowdiv[(size_t)z*KM + grow];
        if (Rz) v += lamv * Rz[(size_t)grow*O + gcol];
        Cz[(size_t)grow*O + gcol] = (TO)v;
      }
    }
  }
}

// ---------------- fp32 tile GEMM (head only, O=64) ----------------
__global__ __launch_bounds__(256) void gemm_f32_kernel(
    const float* __restrict__ A, int K,
    const float* __restrict__ W, const float* __restrict__ bias,
    float* __restrict__ C, int O)
{
  __shared__ float As[32][68];
  __shared__ float Ws[32][68];
  int t = threadIdx.x;
  int row0 = blockIdx.x * 64;
  int col0 = blockIdx.y * 64;
  int ti = t & 15, tj = t >> 4;
  float acc[4][4] = {};
  for (int k0 = 0; k0 < K; k0 += 32) {
#pragma unroll
    for (int p = 0; p < 2; ++p) {
      int idx = p*256 + t;
      int ar = idx >> 3, af = (idx & 7)*4;
      float4 av = *(const float4*)&A[(size_t)(row0+ar)*K + k0 + af];
      As[af+0][ar] = av.x; As[af+1][ar] = av.y;
      As[af+2][ar] = av.z; As[af+3][ar] = av.w;
      float4 wv = *(const float4*)&W[(size_t)(col0+ar)*K + k0 + af];
      Ws[af+0][ar] = wv.x; Ws[af+1][ar] = wv.y;
      Ws[af+2][ar] = wv.z; Ws[af+3][ar] = wv.w;
    }
    __syncthreads();
#pragma unroll
    for (int kk = 0; kk < 32; ++kk) {
      float4 a4 = *(float4*)&As[kk][ti*4];
      float4 b4 = *(float4*)&Ws[kk][tj*4];
      float a[4] = {a4.x, a4.y, a4.z, a4.w};
      float b[4] = {b4.x, b4.y, b4.z, b4.w};
#pragma unroll
      for (int x = 0; x < 4; ++x)
#pragma unroll
        for (int y = 0; y < 4; ++y) acc[x][y] += a[x]*b[y];
    }
    __syncthreads();
  }
#pragma unroll
  for (int x = 0; x < 4; ++x) {
    int r = row0 + ti*4 + x;
#pragma unroll
    for (int y = 0; y < 4; ++y) {
      int c = col0 + tj*4 + y;
      float v = fmaxf(acc[x][y] + bias[c], 0.f);
      C[(size_t)r*O + c] = v;
    }
  }
}

// ---------------- transpose-init: PT=RT=F^T, XT=0 (no atomics) --------------
__global__ __launch_bounds__(256) void tinit_kernel(
    const float* __restrict__ F, float* __restrict__ PT, float* __restrict__ RT,
    float* __restrict__ XT)
{
  __shared__ float Ls[64][68];
  int t = threadIdx.x;
  int k0 = blockIdx.x*64, n0 = blockIdx.y*64, z = blockIdx.z;
#pragma unroll
  for (int p = 0; p < 4; ++p) {
    int idx = p*256 + t;
    int kr = idx >> 4, c4 = (idx & 15)*4;
    *(float4*)&Ls[kr][c4] = *(const float4*)&F[((size_t)z*KM + k0+kr)*DD + n0 + c4];
  }
  __syncthreads();
#pragma unroll
  for (int p = 0; p < 4; ++p) {
    int idx = p*256 + t;
    int nl = idx >> 4, k4 = (idx & 15)*4;
    float4 v = { Ls[k4+0][nl], Ls[k4+1][nl], Ls[k4+2][nl], Ls[k4+3][nl] };
    size_t o = ((size_t)z*DD + n0+nl)*KM + k0 + k4;
    *(float4*)&PT[o] = v;
    *(float4*)&RT[o] = v;
    float4 zr = {0.f,0.f,0.f,0.f};
    *(float4*)&XT[o] = zr;
  }
}

// ---------------- merged CG update (self-contained, deterministic) ----------
__global__ __launch_bounds__(256) void cg_update_kernel(
    float* __restrict__ XT, float* __restrict__ RT,
    float* __restrict__ PT, const float* __restrict__ APT)
{
  __shared__ float redw[12];
  int row = blockIdx.x;
  int t = threadIdx.x;
  int lane = t & 63, w = t >> 6;
  size_t base = (size_t)row*KM + (size_t)t*4;
  float4 p4 = *(float4*)&PT[base];
  float4 a4 = *(const float4*)&APT[base];
  float4 r4 = *(float4*)&RT[base];
  float4 x4 = *(float4*)&XT[base];
  float prr  = (r4.x*r4.x + r4.y*r4.y) + (r4.z*r4.z + r4.w*r4.w);
  float ppap = (p4.x*a4.x + p4.y*a4.y) + (p4.z*a4.z + p4.w*a4.w);
  prr = wred(prr); ppap = wred(ppap);
  if (lane == 0) { redw[w] = prr; redw[4+w] = ppap; }
  __syncthreads();
  float rr  = (redw[0]+redw[1]) + (redw[2]+redw[3]);
  float pap = (redw[4]+redw[5]) + (redw[6]+redw[7]);
  float alpha = (pap > 1e-30f) ? rr/pap : 0.f;
  x4.x += alpha*p4.x; x4.y += alpha*p4.y; x4.z += alpha*p4.z; x4.w += alpha*p4.w;
  r4.x -= alpha*a4.x; r4.y -= alpha*a4.y; r4.z -= alpha*a4.z; r4.w -= alpha*a4.w;
  *(float4*)&XT[base] = x4;
  *(float4*)&RT[base] = r4;
  float s = (r4.x*r4.x + r4.y*r4.y) + (r4.z*r4.z + r4.w*r4.w);
  s = wred(s);
  if (lane == 0) redw[8+w] = s;
  __syncthreads();
  float rrnew = (redw[8]+redw[9]) + (redw[10]+redw[11]);
  float beta = (rr > 1e-30f) ? rrnew/rr : 0.f;
  p4.x = r4.x + beta*p4.x; p4.y = r4.y + beta*p4.y;
  p4.z = r4.z + beta*p4.z; p4.w = r4.w + beta*p4.w;
  *(float4*)&PT[base] = p4;
}

// ---------------- RoPE (coalesced, de-interleaved QKV) ----------------
__global__ __launch_bounds__(256) void rope_split_kernel(
    const bf16* __restrict__ qkv, const float* __restrict__ enc0,
    const float* __restrict__ enc1, bf16* __restrict__ Qo,
    bf16* __restrict__ Ko)
{
  int t = threadIdx.x;
  int r = blockIdx.x*2 + (t >> 7);
  int c = (t & 127)*2;                    // even col
  int ts = r >> 10, i = r & 1023;
  int d = c & 63;
  const float* enc = (ts < BB) ? enc0 : enc1;
  int s = (ts < BB) ? ts : ts - BB;
  const float* eb = enc + (((size_t)s*2)*KM + i)*HD;
  float2 cs = *(const float2*)&eb[d];
  float2 sn = *(const float2*)&eb[(size_t)KM*HD + d];
  size_t base = (size_t)r*768;
  bf16x2 qv = *(const bf16x2*)&qkv[base + c];
  bf16x2 kv = *(const bf16x2*)&qkv[base + 256 + c];
  float q0 = (float)qv[0], q1 = (float)qv[1];
  float k0 = (float)kv[0], k1 = (float)kv[1];
  float oq0 = q0*cs.x - q1*sn.x, oq1 = q1*cs.y + q0*sn.y;
  float ok0 = k0*cs.x - k1*sn.x, ok1 = k1*cs.y + k0*sn.y;
  size_t o = (size_t)r*DD + c;
  bf16x2 qo = {(bf16)(0.1803368801f*oq0), (bf16)(0.1803368801f*oq1)};
  bf16x2 ko = {(bf16)ok0, (bf16)ok1};
  *(bf16x2*)&Qo[o] = qo;
  *(bf16x2*)&Ko[o] = ko;
}

// ---------------- V -> V^T transpose (per (stream,head)), strided src -------
__global__ __launch_bounds__(256) void vt_kernel(
    const bf16* __restrict__ Vin, int vstride, bf16* __restrict__ VT)
{
  __shared__ __align__(16) bf16 Ls[64*72];
  int tid = threadIdx.x;
  int zh = blockIdx.x;
  int ts = zh >> 2, h = zh & 3;
  int k0 = blockIdx.y * 64;
#pragma unroll
  for (int p = 0; p < 2; ++p) {
    int idx = p*256 + tid;
    int kr = idx >> 3, c8 = (idx & 7)*8;
    *(uint4*)&Ls[kr*72 + c8] =
      *(const uint4*)&Vin[((size_t)ts*KM + k0 + kr)*vstride + h*HD + c8];
  }
  __syncthreads();
#pragma unroll
  for (int p = 0; p < 2; ++p) {
    int idx = p*256 + tid;
    int dr = idx >> 3, k8 = (idx & 7)*8;
    bf16 tmp[8] __attribute__((aligned(16)));
#pragma unroll
    for (int j = 0; j < 8; ++j) tmp[j] = Ls[(k8+j)*72 + dr];
    *(uint4*)&VT[((size_t)zh*HD + dr)*KM + k0 + k8] = *(uint4*)tmp;
  }
}

// ---------------- MFMA flash attention body (S^T scheme, V^T input) ----------
__device__ __forceinline__ void mha_body(
    const bf16* __restrict__ Qg, const bf16* __restrict__ Kg,
    const bf16* __restrict__ VTg, bf16* __restrict__ Og,
    size_t qkbase, size_t obase, size_t vbase, int qkstride,
    int q0, int tid, bf16* Qs, bf16* Ks, bf16* Vt)
{
  int lane = tid & 63, w = tid >> 6;
  int lm = lane & 15, lq = lane >> 4;
  int r0 = tid >> 3, c8 = (tid & 7)*8;
  int r1 = r0 + 32;
  *(uint4*)&Qs[SWZ(r0,c8)] = *(const uint4*)&Qg[qkbase + (size_t)(q0+r0)*qkstride + c8];
  *(uint4*)&Qs[SWZ(r1,c8)] = *(const uint4*)&Qg[qkbase + (size_t)(q0+r1)*qkstride + c8];
  __syncthreads();
  bf16x8 qa0 = *(bf16x8*)&Qs[SWZ(w*16 + lm, lq*8)];
  bf16x8 qa1 = *(bf16x8*)&Qs[SWZ(w*16 + lm, 32 + lq*8)];
  short4v ones4;
  { bf16x4 o1 = {(bf16)1.f,(bf16)1.f,(bf16)1.f,(bf16)1.f};
    __builtin_memcpy(&ones4, &o1, 8); }
  float m_ = 0.f;
  floatx4 lacc = (floatx4){0.f,0.f,0.f,0.f};
  floatx4 oacc[4];
#pragma unroll
  for (int db = 0; db < 4; ++db) oacc[db] = (floatx4){0.f,0.f,0.f,0.f};

  for (int kt = 0; kt < KM; kt += 64) {
    __syncthreads();
    *(uint4*)&Ks[SWZ(r0,c8)] = *(const uint4*)&Kg[qkbase + (size_t)(kt+r0)*qkstride + c8];
    *(uint4*)&Ks[SWZ(r1,c8)] = *(const uint4*)&Kg[qkbase + (size_t)(kt+r1)*qkstride + c8];
    *(uint4*)&Vt[SWZ(r0,c8)] = *(const uint4*)&VTg[vbase + (size_t)r0*KM + kt + c8];
    *(uint4*)&Vt[SWZ(r1,c8)] = *(const uint4*)&VTg[vbase + (size_t)r1*KM + kt + c8];
    __syncthreads();
    floatx4 st[4];
    float negm = -m_;
    __builtin_amdgcn_s_setprio(1);
#pragma unroll
    for (int kb = 0; kb < 4; ++kb) {
      bf16x8 a0 = *(bf16x8*)&Ks[SWZ(kb*16 + lm, lq*8)];
      bf16x8 a1 = *(bf16x8*)&Ks[SWZ(kb*16 + lm, 32 + lq*8)];
      floatx4 acc = (floatx4){negm, negm, negm, negm};
      acc = MFMA16(a0, qa0, acc);
      acc = MFMA16(a1, qa1, acc);
      st[kb] = acc;
    }
    __builtin_amdgcn_s_setprio(0);
    // local max, max3-shaped (16 -> 8 ops)
    float ma = fmaxf(fmaxf(st[0][0], st[0][1]), st[0][2]);
    float mb = fmaxf(fmaxf(st[0][3], st[1][0]), st[1][1]);
    float mc = fmaxf(fmaxf(st[1][2], st[1][3]), st[2][0]);
    float md = fmaxf(fmaxf(st[2][1], st[2][2]), st[2][3]);
    float me = fmaxf(fmaxf(st[3][0], st[3][1]), st[3][2]);
    float mf = fmaxf(fmaxf(ma, mb), st[3][3]);
    float mg = fmaxf(fmaxf(mc, md), me);
    float mx = fmaxf(mf, mg);
    // defer-max: wave-uniform test; shfls + subs only when a rescale is needed
    if (!__all(mx <= 8.f)) {
      float wmx = fmaxf(mx, __shfl_xor(mx, 16));
      wmx = fmaxf(wmx, __shfl_xor(wmx, 32));
      float delta = fmaxf(wmx, 0.f);
      float al = exp2f(-delta);
      m_ += delta;
      lacc[0] *= al; lacc[1] *= al; lacc[2] *= al; lacc[3] *= al;
#pragma unroll
      for (int db = 0; db < 4; ++db) {
        oacc[db][0] *= al; oacc[db][1] *= al;
        oacc[db][2] *= al; oacc[db][3] *= al;
      }
#pragma unroll
      for (int kb = 0; kb < 4; ++kb) {
        st[kb][0] -= delta; st[kb][1] -= delta;
        st[kb][2] -= delta; st[kb][3] -= delta;
      }
    }
    __builtin_amdgcn_s_setprio(1);
#pragma unroll
    for (int kb = 0; kb < 4; ++kb) {
      float p0 = exp2f(st[kb][0]);
      float p1 = exp2f(st[kb][1]);
      float p2 = exp2f(st[kb][2]);
      float p3 = exp2f(st[kb][3]);
      short4v pb = pack4(p0, p1, p2, p3);
      lacc = MFMA1K(ones4, pb, lacc);
#pragma unroll
      for (int db = 0; db < 4; ++db) {
        short4v va = *(const short4v*)&Vt[SWZ(db*16 + lm, kb*16 + lq*4)];
        oacc[db] = MFMA1K(va, pb, oacc[db]);
      }
    }
    __builtin_amdgcn_s_setprio(0);
  }
  float inv = 1.f / lacc[0];
  int q = q0 + w*16 + lm;
#pragma unroll
  for (int db = 0; db < 4; ++db) {
    bf16x4 o4 = { (bf16)(oacc[db][0]*inv), (bf16)(oacc[db][1]*inv),
                  (bf16)(oacc[db][2]*inv), (bf16)(oacc[db][3]*inv) };
    *(bf16x4*)&Og[obase + (size_t)q*DD + db*16 + lq*4] = o4;
  }
}

// self attention: grid (zh=64, qtile=16); Q/K row stride 256
__global__ __launch_bounds__(256) void mha_kernel(
    const bf16* __restrict__ Qg, const bf16* __restrict__ Kg,
    const bf16* __restrict__ VTg, bf16* __restrict__ Og)
{
  __shared__ __align__(16) bf16 Qs[64*64];
  __shared__ __align__(16) bf16 Ks[64*64];
  __shared__ __align__(16) bf16 Vt[64*64];
  int zh = blockIdx.x;
  int z = zh >> 2, h = zh & 3;
  size_t base = ((size_t)z*KM)*DD + (size_t)h*HD;
  size_t vbase = (size_t)zh*HD*KM;
  mha_body(Qg, Kg, VTg, Og, base, base, vbase, DD,
           blockIdx.y*64, threadIdx.x, Qs, Ks, Vt);
}

// cross attention, both directions: grid (zh=32, qtile=16, dir=2)
__global__ __launch_bounds__(256) void mha_cross_kernel(
    const bf16* __restrict__ QKV2, const bf16* __restrict__ VT2,
    bf16* __restrict__ ATTO2)
{
  __shared__ __align__(16) bf16 Qs[64*64];
  __shared__ __align__(16) bf16 Ks[64*64];
  __shared__ __align__(16) bf16 Vt[64*64];
  int dir = blockIdx.z;
  const bf16* Qg  = QKV2 + (dir ? (size_t)BN*512 : 0);
  const bf16* Kg  = QKV2 + (dir ? 0 : (size_t)BN*512);
  const bf16* VTg = VT2  + (dir ? 0 : (size_t)32*HD*KM);
  bf16*       Og  = ATTO2 + (dir ? (size_t)BN*DD : 0);
  int zh = blockIdx.x;
  int z = zh >> 2, h = zh & 3;
  size_t qkbase = ((size_t)z*KM)*512 + (size_t)h*HD;
  size_t obase  = ((size_t)z*KM)*DD  + (size_t)h*HD;
  size_t vbase  = (size_t)zh*HD*KM;
  mha_body(Qg, Kg, VTg, Og, qkbase, obase, vbase, 512,
           blockIdx.y*64, threadIdx.x, Qs, Ks, Vt);
}

// ---------------- in-place LayerNorm + exact GELU (bf16, width 512) --------
__global__ __launch_bounds__(256) void ln_gelu_kernel(
    bf16* __restrict__ Hb, const float* __restrict__ g,
    const float* __restrict__ be)
{
  int t = threadIdx.x;
  int lane = t & 63, w = t >> 6;
  size_t r = (size_t)blockIdx.x*4 + w;
  bf16* rowp = Hb + r*512 + lane*8;
  bf16x8 hv = *(bf16x8*)rowp;
  float x[8];
#pragma unroll
  for (int j = 0; j < 8; ++j) x[j] = (float)hv[j];
  float s = ((x[0]+x[1]) + (x[2]+x[3])) + ((x[4]+x[5]) + (x[6]+x[7]));
  s = wred(s);
  float mu = s * (1.f/512.f);
  float v = 0.f;
#pragma unroll
  for (int j = 0; j < 8; ++j) { float d = x[j] - mu; v += d*d; }
  v = wred(v);
  float rstd = rsqrtf(v*(1.f/512.f) + 1e-5f);
  float4 g0 = *(const float4*)&g[lane*8];
  float4 g1 = *(const float4*)&g[lane*8 + 4];
  float4 b0 = *(const float4*)&be[lane*8];
  float4 b1 = *(const float4*)&be[lane*8 + 4];
  float gv[8] = {g0.x,g0.y,g0.z,g0.w,g1.x,g1.y,g1.z,g1.w};
  float bv[8] = {b0.x,b0.y,b0.z,b0.w,b1.x,b1.y,b1.z,b1.w};
  bf16x8 ov;
#pragma unroll
  for (int j = 0; j < 8; ++j) {
    float h = (x[j] - mu)*rstd*gv[j] + bv[j];
    h = 0.5f*h*(1.f + erff(h*0.70710678118f));
    ov[j] = (bf16)h;
  }
  *(bf16x8*)rowp = ov;
}

// ---------------- final head 2 ----------------
__global__ __launch_bounds__(256) void head2_kernel(
    const float* __restrict__ Hb, const float* __restrict__ w,
    const float* __restrict__ b, float* __restrict__ out)
{
  int r = blockIdx.x*256 + threadIdx.x;
  float acc = b[0];
#pragma unroll
  for (int k = 0; k < 64; ++k) acc += Hb[(size_t)r*64 + k]*w[k];
  out[r] = 1.f/(1.f + expf(-acc));
}

extern "C" void kernel_launch(void* const* d_in, const int* in_sizes, int n_in,
                              void* d_out, int out_size, void* d_ws, size_t ws_size,
                              hipStream_t stream)
{
  (void)in_sizes; (void)n_in; (void)out_size; (void)ws_size;
  const float* fa      = (const float*)d_in[0];
  const float* fb      = (const float*)d_in[1];
  const int*   matches = (const int*)d_in[2];
  const float* ka      = (const float*)d_in[3];
  const float* kb      = (const float*)d_in[4];
  const float* lam     = (const float*)d_in[5];
  const float* beta    = (const float*)d_in[6];
  const float* Wr      = (const float*)d_in[7];
  const float* pW1     = (const float*)d_in[8];
  const float* pb1     = (const float*)d_in[9];
  const float* pW2     = (const float*)d_in[10];
  const float* pb2     = (const float*)d_in[11];
  const float* sWqkv   = (const float*)d_in[12];
  const float* sbqkv   = (const float*)d_in[13];
  const float* sWo     = (const float*)d_in[14];
  const float* sbo     = (const float*)d_in[15];
  const float* sW1     = (const float*)d_in[16];
  const float* sb1     = (const float*)d_in[17];
  const float* sg      = (const float*)d_in[18];
  const float* sbe     = (const float*)d_in[19];
  const float* sW2     = (const float*)d_in[20];
  const float* sb2     = (const float*)d_in[21];
  const float* cWqk    = (const float*)d_in[22];
  const float* cbqk    = (const float*)d_in[23];
  const float* cWv     = (const float*)d_in[24];
  const float* cbv     = (const float*)d_in[25];
  const float* cWo     = (const float*)d_in[26];
  const float* cbo     = (const float*)d_in[27];
  const float* cW1     = (const float*)d_in[28];
  const float* cb1     = (const float*)d_in[29];
  const float* cgw     = (const float*)d_in[30];
  const float* cbe     = (const float*)d_in[31];
  const float* cW2     = (const float*)d_in[32];
  const float* cb2     = (const float*)d_in[33];

  char* wsb = (char*)d_ws;
  float* DCAT = (float*)wsb;                      // 16,777,216 B
  float* ENC0 = (float*)(wsb + 16777216);
  float* ENC1 = (float*)(wsb + 20971520);
  float* XY0  = (float*)(wsb + 25165824);
  float* XY1  = (float*)(wsb + 25231360);
  float* ROWS = (float*)(wsb + 25296896);
  char*  POOL = wsb + 25354240;
  const size_t SLOT = 8388608;
  // CG phase
  fp16*  KMATH = (fp16*)POOL;                    // slots 0-1
  float* FBUF  = (float*)(POOL + 2*SLOT);
  float* PT    = (float*)(POOL + 3*SLOT);
  float* RT    = (float*)(POOL + 4*SLOT);
  float* XT    = (float*)(POOL + 5*SLOT);
  float* APT   = (float*)(POOL + 6*SLOT);
  // transformer phase
  bf16*  QKV   = (bf16*)POOL;                    // slots 0-2 (q|k|v cols)
  bf16*  QR    = (bf16*)(POOL + 3*SLOT);
  bf16*  KR    = (bf16*)(POOL + 4*SLOT);
  bf16*  VTG   = (bf16*)(POOL + 8*SLOT);         // slot 8 (V^T, self)
  bf16*  ATTO  = (bf16*)POOL;                    // slot 0
  bf16*  MSG   = (bf16*)(POOL + 1*SLOT);
  bf16*  H1    = (bf16*)(POOL + 6*SLOT);         // slots 6-7
  bf16*  QKV2  = (bf16*)POOL;                    // slots 0-1 (cross q|v cols)
  bf16*  ATTO2 = (bf16*)(POOL + 2*SLOT);
  bf16*  MSG2  = (bf16*)(POOL + 3*SLOT);
  bf16*  VT2   = (bf16*)(POOL + 4*SLOT);         // slot 4 (V^T, cross)
  bf16*  H1C   = H1;
  float* HBUF  = (float*)POOL;

  const float scq = 0.42466090f;   // 64^-0.25 * sqrt(log2 e)

  // ---- gather / posenc / Kmat ----
  gather_kernel<<<BN, 256, 0, stream>>>(fa, fb, matches, ka, kb, FBUF, DCAT, XY0, XY1);
  posenc_kernel<<<BN/4, 256, 0, stream>>>(XY0, Wr, ENC0);
  posenc_kernel<<<BN/4, 256, 0, stream>>>(XY1, Wr, ENC1);
  kmat_kernel<<<BN, 256, 0, stream>>>(XY0, beta, KMATH, ROWS);

  // ---- CG (transposed state, deterministic: no fp atomics anywhere) ----
  tinit_kernel<<<dim3(16,4,BB), 256, 0, stream>>>(FBUF, PT, RT, XT);
  for (int it = 0; it < CG_ITERS; ++it) {
    mv64_kernel<float,fp16,float><<<dim3(4,16,BB), 256, 0, stream>>>(
        PT, 1024, KMATH, APT, 1024, PT, lam, (const float*)0,
        262144, 1048576, 262144, 262144);
    cg_update_kernel<<<2048, 256, 0, stream>>>(XT, RT, PT, APT);
  }

  // ---- d1 = rownorm(Kmat) @ C  (d0 = f_i already written by gather) ----
  mv64_kernel<fp16,float,float><<<dim3(16,4,BB), 256, 0, stream>>>(
      KMATH, 1024, XT, DCAT + (size_t)BN*DD, 256,
      (const float*)0, (const float*)0, ROWS,
      1048576, 262144, 262144, 0);

  // ---- transformer layers ----
  for (int l = 0; l < NLAYER; ++l) {
    // self block: QKV projection (WPERM de-interleave); 16384 rows -> 256 blocks
    mm64g_kernel<1,0,float,bf16,bf16><<<dim3(256,12,1), 256, 0, stream>>>(
        DCAT, (const bf16*)0, 256, 256, sWqkv + (size_t)l*768*256, sbqkv + l*768,
        (const float*)0, (const float*)0, QKV, 768, 1.f, 1.f, (const float*)0);
    rope_split_kernel<<<8192, 256, 0, stream>>>(QKV, ENC0, ENC1, QR, KR);
    vt_kernel<<<dim3(64,16), 256, 0, stream>>>(QKV + 512, 768, VTG);
    mha_kernel<<<dim3(64,16), 256, 0, stream>>>(QR, KR, VTG, ATTO);
    mm64d_kernel<bf16><<<dim3(256,4,1), 256, 0, stream>>>(
        ATTO, 256, sWo + (size_t)l*256*256, sbo + l*256, MSG, 256,
        (const float*)0);
    mm64g_kernel<0,0,float,bf16,bf16><<<dim3(256,8,1), 256, 0, stream>>>(
        DCAT, MSG, 256, 512, sW1 + (size_t)l*512*512, sb1 + l*512,
        (const float*)0, (const float*)0, H1, 512, 1.f, 1.f, (const float*)0);
    ln_gelu_kernel<<<N2/4, 256, 0, stream>>>(H1, sg + l*512, sbe + l*512);
    mm64d_kernel<float><<<dim3(256,4,1), 256, 0, stream>>>(
        H1, 512, sW2 + (size_t)l*256*512, sb2 + l*256, DCAT, 256, DCAT);
    // cross block: fused qk|v projection into QKV2; 16384 rows -> 256 blocks
    mm64g_kernel<0,1,float,bf16,bf16><<<dim3(256,8,1), 256, 0, stream>>>(
        DCAT, (const bf16*)0, 256, 256, cWqk + (size_t)l*256*256, cbqk + l*256,
        cWv + (size_t)l*256*256, cbv + l*256, QKV2, 512, scq, 1.f,
        (const float*)0);
    vt_kernel<<<dim3(64,16), 256, 0, stream>>>(QKV2 + 256, 512, VT2);
    mha_cross_kernel<<<dim3(32,16,2), 256, 0, stream>>>(QKV2, VT2, ATTO2);
    mm64d_kernel<bf16><<<dim3(256,4,1), 256, 0, stream>>>(
        ATTO2, 256, cWo + (size_t)l*256*256, cbo + l*256, MSG2, 256,
        (const float*)0);
    mm64g_kernel<0,0,float,bf16,bf16><<<dim3(256,8,1), 256, 0, stream>>>(
        DCAT, MSG2, 256, 512, cW1 + (size_t)l*512*512, cb1 + l*512,
        (const float*)0, (const float*)0, H1C, 512, 1.f, 1.f, (const float*)0);
    ln_gelu_kernel<<<N2/4, 256, 0, stream>>>(H1C, cgw + l*512, cbe + l*512);
    mm64d_kernel<float><<<dim3(256,4,1), 256, 0, stream>>>(
        H1C, 512, cW2 + (size_t)l*256*512, cb2 + l*256, DCAT, 256, DCAT);
  }

  // ---- head ----
  gemm_f32_kernel<<<dim3(128,1), 256, 0, stream>>>(DCAT, 256, pW1, pb1, HBUF, 64);
  head2_kernel<<<32, 256, 0, stream>>>(HBUF, pW2, pb2, (float*)d_out);
}

// Round 18
// 889.995 us; speedup vs baseline: 1.2983x; 1.0124x over previous
//
#include <hip/hip_runtime.h>
#include <math.h>

// Problem constants
#define BB 8
#define MM 2048
#define KM 1024
#define DD 256
#define HH 4
#define HD 64
#define NLAYER 2
#define BN (BB*KM)        // 8192 rows per "decoder half"
#define N2 (2*BN)         // 16384 rows d0||d1
#define CG_ITERS 5

// XOR-swizzled LDS addressing for the attention tiles: stride 64 (no pad),
// 16-byte blocks permuted by row. Conflict-free for uint4 stores, bf16x8
// reads, and short4v reads — and keeps every access 16B/8B aligned.
#define SWZ(r,c) (((r)<<6) + ((((c)>>3) ^ ((r)&7))<<3) + ((c)&7))

typedef __bf16 bf16;
typedef __bf16 bf16x8 __attribute__((ext_vector_type(8)));
typedef __bf16 bf16x4 __attribute__((ext_vector_type(4)));
typedef __bf16 bf16x2 __attribute__((ext_vector_type(2)));
typedef _Float16 fp16;
typedef _Float16 fp16x8 __attribute__((ext_vector_type(8)));
typedef short  short4v __attribute__((ext_vector_type(4)));
typedef float  floatx4 __attribute__((ext_vector_type(4)));
#define MFMA16(a,b,c)  __builtin_amdgcn_mfma_f32_16x16x32_bf16(a,b,c,0,0,0)
#define MFMA16H(a,b,c) __builtin_amdgcn_mfma_f32_16x16x32_f16(a,b,c,0,0,0)

// K=16 bf16 MFMA (PV stage: S^T C-frag == its B-operand layout).
#if defined(__HIP_DEVICE_COMPILE__)
  #if __has_builtin(__builtin_amdgcn_mfma_f32_16x16x16bf16_1k)
    #define MFMA1K(a,b,c) __builtin_amdgcn_mfma_f32_16x16x16bf16_1k(a,b,c,0,0,0)
  #else
    #error "device pass lacks mfma_f32_16x16x16bf16_1k"
  #endif
#else
  #define MFMA1K(a,b,c) (c)   /* host stub, never executed */
#endif

__device__ __forceinline__ float softplusf(float x) {
  return fmaxf(x, 0.f) + log1pf(expf(-fabsf(x)));
}

__device__ __forceinline__ float wred(float x) {
  x += __shfl_xor(x, 1);  x += __shfl_xor(x, 2);  x += __shfl_xor(x, 4);
  x += __shfl_xor(x, 8);  x += __shfl_xor(x, 16); x += __shfl_xor(x, 32);
  return x;
}

__device__ __forceinline__ short4v pack4(float a, float b, float c, float d) {
  bf16x4 v = {(bf16)a,(bf16)b,(bf16)c,(bf16)d};
  short4v s;
  __builtin_memcpy(&s, &v, 8);
  return s;
}

// raw staging (load early / convert+store late)
template<typename T> struct Raw8;
template<> struct Raw8<float> {
  float4 a, b;
  __device__ __forceinline__ void load(const float* s) {
    a = *(const float4*)s; b = *(const float4*)(s + 4);
  }
  __device__ __forceinline__ void store(fp16* d) const {
    fp16x8 v = { (fp16)a.x,(fp16)a.y,(fp16)a.z,(fp16)a.w,
                 (fp16)b.x,(fp16)b.y,(fp16)b.z,(fp16)b.w };
    *(fp16x8*)d = v;
  }
  __device__ __forceinline__ void storeb(bf16* d) const {
    bf16x8 v = { (bf16)a.x,(bf16)a.y,(bf16)a.z,(bf16)a.w,
                 (bf16)b.x,(bf16)b.y,(bf16)b.z,(bf16)b.w };
    *(bf16x8*)d = v;
  }
};
template<> struct Raw8<fp16> {
  uint4 u;
  __device__ __forceinline__ void load(const fp16* s) { u = *(const uint4*)s; }
  __device__ __forceinline__ void store(fp16* d) const { *(uint4*)d = u; }
};
template<> struct Raw8<bf16> {
  uint4 u;
  __device__ __forceinline__ void load(const bf16* s) { u = *(const uint4*)s; }
  __device__ __forceinline__ void storeb(bf16* d) const { *(uint4*)d = u; }
};

// ---------------- gather (writes F to both FBUF and DCAT; no copy pass) -----
__global__ __launch_bounds__(256) void gather_kernel(
    const float* __restrict__ fa, const float* __restrict__ fb,
    const int* __restrict__ matches, const float* __restrict__ ka,
    const float* __restrict__ kb, float* __restrict__ F,
    float* __restrict__ Fd,
    float* __restrict__ xy0, float* __restrict__ xy1)
{
  int si = blockIdx.x;
  int s  = si >> 10;
  int t  = threadIdx.x;
  int ia = matches[(size_t)si*2+0];
  int ib = matches[(size_t)si*2+1];
  float v = fb[((size_t)s*MM + ib)*DD + t] - fa[((size_t)s*MM + ia)*DD + t];
  F[(size_t)si*DD + t]  = v;
  Fd[(size_t)si*DD + t] = v;
  if (t == 0) {
    xy0[(size_t)si*2+0] = ka[((size_t)s*MM + ia)*2+0];
    xy0[(size_t)si*2+1] = ka[((size_t)s*MM + ia)*2+1];
    xy1[(size_t)si*2+0] = kb[((size_t)s*MM + ib)*2+0];
    xy1[(size_t)si*2+1] = kb[((size_t)s*MM + ib)*2+1];
  }
}

// ---------------- positional encoding (4 rows per 256-thread block) ---------
__global__ __launch_bounds__(256) void posenc_kernel(
    const float* __restrict__ xy, const float* __restrict__ Wr,
    float* __restrict__ enc)
{
  int t = threadIdx.x;
  int si = blockIdx.x*4 + (t >> 6);
  int s = si >> 10, i = si & 1023;
  int d = t & 63; int p = d >> 1;
  float x = xy[(size_t)si*2], y = xy[(size_t)si*2+1];
  float pr = Wr[p*2]*x + Wr[p*2+1]*y;
  enc[(((size_t)s*2+0)*KM + i)*HD + d] = cosf(pr);
  enc[(((size_t)s*2+1)*KM + i)*HD + d] = sinf(pr);
}

// ---------------- Kmat (fp16) + rowsum (wave butterflies) -------------------
__global__ __launch_bounds__(256) void kmat_kernel(
    const float* __restrict__ xy0, const float* __restrict__ beta_ptr,
    fp16* __restrict__ Km, float* __restrict__ rowsum)
{
  __shared__ float redw[4];
  int si = blockIdx.x; int s = si >> 10;
  int t = threadIdx.x;
  int lane = t & 63, w = t >> 6;
  float beta_l2 = softplusf(beta_ptr[0]) * 1.442695040888963f;
  float xi = xy0[(size_t)si*2], yi = xy0[(size_t)si*2+1];
  const float* xys = xy0 + (size_t)s*KM*2;
  float sum = 0.f;
  for (int jj = 0; jj < 4; ++jj) {
    int j = jj*256 + t;
    float dx = xi - xys[j*2], dy = yi - xys[j*2+1];
    float v = exp2f(-beta_l2*(dx*dx + dy*dy));
    Km[(size_t)si*KM + j] = (fp16)v;
    sum += v;
  }
  sum = wred(sum);
  if (lane == 0) redw[w] = sum;
  __syncthreads();
  if (t == 0)
    rowsum[si] = ((redw[0]+redw[1]) + (redw[2]+redw[3])) + 1e-6f;
}

// ---------------- mm64g: 64x64 tile GEMM, mv64/mm64d-proven schedule --------
template<int WPERM, int DUALW, typename TA1, typename TA2, typename TO>
__global__ __launch_bounds__(256) void mm64g_kernel(
    const TA1* __restrict__ A1, const TA2* __restrict__ A2, int K1, int K,
    const float* __restrict__ W, const float* __restrict__ bias,
    const float* __restrict__ Wb, const float* __restrict__ biasb,
    TO* __restrict__ C, int O, float scale, float scaleb,
    const float* __restrict__ resid)
{
  __shared__ __align__(16) bf16 Al[2][64*72];
  __shared__ __align__(16) bf16 Wl[2][64*72];
  int tid = threadIdx.x;
  int row0 = blockIdx.x*64, col0 = blockIdx.y*64;
  int lane = tid & 63, w = tid >> 6;
  int wr = (w>>1)*32, wc = (w&1)*32;
  int lm = lane & 15, lq = lane >> 4;
  int sr0 = tid >> 3, c8 = (tid & 7)*8;
  int sr1 = sr0 + 32;
  int K2 = K - K1;

  const TA1* a1p0 = A1 + (size_t)(row0+sr0)*K1 + c8;
  const TA1* a1p1 = A1 + (size_t)(row0+sr1)*K1 + c8;
  const TA2* a2p0 = A2 + (size_t)(row0+sr0)*K2 + c8;
  const TA2* a2p1 = A2 + (size_t)(row0+sr1)*K2 + c8;
  const float* wp0; const float* wp1;
  {
    int wg0 = col0 + sr0, wg1 = col0 + sr1;
    const float* ws0; int wrow0;
    if (DUALW && wg0 >= 256) { ws0 = Wb; wrow0 = wg0 - 256; }
    else { ws0 = W; wrow0 = WPERM ? ((wg0 & 255)*3 + (wg0 >> 8)) : wg0; }
    const float* ws1; int wrow1;
    if (DUALW && wg1 >= 256) { ws1 = Wb; wrow1 = wg1 - 256; }
    else { ws1 = W; wrow1 = WPERM ? ((wg1 & 255)*3 + (wg1 >> 8)) : wg1; }
    wp0 = ws0 + (size_t)wrow0*K + c8;
    wp1 = ws1 + (size_t)wrow1*K + c8;
  }

  floatx4 acc[2][2];
#pragma unroll
  for (int mb = 0; mb < 2; ++mb)
#pragma unroll
    for (int nb = 0; nb < 2; ++nb) acc[mb][nb] = (floatx4){0.f,0.f,0.f,0.f};

  Raw8<TA1> ra1_0, ra1_1; Raw8<TA2> ra2_0, ra2_1;
  Raw8<float> rw_0, rw_1;
  {
    bool u0 = (0 < K1);
    if (u0) { ra1_0.load(a1p0); ra1_1.load(a1p1); }
    else    { ra2_0.load(a2p0); ra2_1.load(a2p1); }
    rw_0.load(wp0); rw_1.load(wp1);
    if (u0) { ra1_0.storeb(&Al[0][sr0*72 + c8]); ra1_1.storeb(&Al[0][sr1*72 + c8]); }
    else    { ra2_0.storeb(&Al[0][sr0*72 + c8]); ra2_1.storeb(&Al[0][sr1*72 + c8]); }
    rw_0.storeb(&Wl[0][sr0*72 + c8]);
    rw_1.storeb(&Wl[0][sr1*72 + c8]);
    __syncthreads();
  }

  int nst = K >> 6;
  for (int j = 0; j < nst; ++j) {
    int cur = j & 1;
    bool pre = (j + 1 < nst);
    bool nUse1 = (((j+1) << 6) < K1);
    if (pre) {
      int k1n = (j+1) << 6;
      if (nUse1) { ra1_0.load(a1p0 + k1n); ra1_1.load(a1p1 + k1n); }
      else       { ra2_0.load(a2p0 + (k1n - K1)); ra2_1.load(a2p1 + (k1n - K1)); }
      rw_0.load(wp0 + k1n); rw_1.load(wp1 + k1n);
    }
    bf16x8 af0[2], af1[2], b0[2], b1[2];
#pragma unroll
    for (int mb = 0; mb < 2; ++mb) {
      af0[mb] = *(bf16x8*)&Al[cur][(wr + mb*16 + lm)*72 + lq*8];
      af1[mb] = *(bf16x8*)&Al[cur][(wr + mb*16 + lm)*72 + 32 + lq*8];
    }
#pragma unroll
    for (int nb = 0; nb < 2; ++nb) {
      b0[nb] = *(bf16x8*)&Wl[cur][(wc + nb*16 + lm)*72 + lq*8];
      b1[nb] = *(bf16x8*)&Wl[cur][(wc + nb*16 + lm)*72 + 32 + lq*8];
    }
    __builtin_amdgcn_s_setprio(1);
#pragma unroll
    for (int mb = 0; mb < 2; ++mb)
#pragma unroll
      for (int nb = 0; nb < 2; ++nb) {
        acc[mb][nb] = MFMA16(af0[mb], b0[nb], acc[mb][nb]);
        acc[mb][nb] = MFMA16(af1[mb], b1[nb], acc[mb][nb]);
      }
    __builtin_amdgcn_s_setprio(0);
    if (pre) {
      if (nUse1) {
        ra1_0.storeb(&Al[cur^1][sr0*72 + c8]);
        ra1_1.storeb(&Al[cur^1][sr1*72 + c8]);
      } else {
        ra2_0.storeb(&Al[cur^1][sr0*72 + c8]);
        ra2_1.storeb(&Al[cur^1][sr1*72 + c8]);
      }
      rw_0.storeb(&Wl[cur^1][sr0*72 + c8]);
      rw_1.storeb(&Wl[cur^1][sr1*72 + c8]);
    }
    __syncthreads();
  }
#pragma unroll
  for (int mb = 0; mb < 2; ++mb) {
#pragma unroll
    for (int nb = 0; nb < 2; ++nb) {
#pragma unroll
      for (int r = 0; r < 4; ++r) {
        int grow = row0 + wr + mb*16 + lq*4 + r;
        int gcol = col0 + wc + nb*16 + lm;
        float v = acc[mb][nb][r];
        float bv = 0.f, scl = scale;
        if (DUALW && gcol >= 256) {
          if (biasb) bv = biasb[gcol - 256];
          scl = scaleb;
        } else if (bias) {
          bv = bias[WPERM ? ((gcol & 255)*3 + (gcol >> 8)) : gcol];
        }
        v = (v + bv) * scl;
        if (resid) v += resid[(size_t)grow*O + gcol];
        C[(size_t)grow*O + gcol] = (TO)v;
      }
    }
  }
}

// ---------------- mm64d: 64x64 tile GEMM, exact mv64 schedule ----------------
template<typename TO>
__global__ __launch_bounds__(256) void mm64d_kernel(
    const bf16* __restrict__ A, int K, const float* __restrict__ W,
    const float* __restrict__ bias, TO* __restrict__ C, int O,
    const float* __restrict__ resid)
{
  __shared__ __align__(16) bf16 Al[2][64*72];
  __shared__ __align__(16) bf16 Wl[2][64*72];
  int tid = threadIdx.x;
  int row0 = blockIdx.x*64, col0 = blockIdx.y*64;
  int lane = tid & 63, w = tid >> 6;
  int wr = (w>>1)*32, wc = (w&1)*32;
  int lm = lane & 15, lq = lane >> 4;
  int sr0 = tid >> 3, c8 = (tid & 7)*8;
  int sr1 = sr0 + 32;
  const bf16*  a0ptr = A + (size_t)(row0+sr0)*K + c8;
  const bf16*  a1ptr = A + (size_t)(row0+sr1)*K + c8;
  const float* w0ptr = W + (size_t)(col0+sr0)*K + c8;
  const float* w1ptr = W + (size_t)(col0+sr1)*K + c8;

  floatx4 acc[2][2];
#pragma unroll
  for (int mb = 0; mb < 2; ++mb)
#pragma unroll
    for (int nb = 0; nb < 2; ++nb) acc[mb][nb] = (floatx4){0.f,0.f,0.f,0.f};

  uint4 ra0 = *(const uint4*)a0ptr;
  uint4 ra1 = *(const uint4*)a1ptr;
  Raw8<float> rw0, rw1;
  rw0.load(w0ptr); rw1.load(w1ptr);
  *(uint4*)&Al[0][sr0*72 + c8] = ra0;
  *(uint4*)&Al[0][sr1*72 + c8] = ra1;
  rw0.storeb(&Wl[0][sr0*72 + c8]);
  rw1.storeb(&Wl[0][sr1*72 + c8]);
  __syncthreads();

  for (int k0 = 0; k0 < K; k0 += 64) {
    int cur = (k0 >> 6) & 1;
    bool pre = (k0 + 64 < K);
    if (pre) {
      ra0 = *(const uint4*)(a0ptr + k0 + 64);
      ra1 = *(const uint4*)(a1ptr + k0 + 64);
      rw0.load(w0ptr + k0 + 64);
      rw1.load(w1ptr + k0 + 64);
    }
    bf16x8 af0[2], af1[2], b0[2], b1[2];
#pragma unroll
    for (int mb = 0; mb < 2; ++mb) {
      af0[mb] = *(bf16x8*)&Al[cur][(wr + mb*16 + lm)*72 + lq*8];
      af1[mb] = *(bf16x8*)&Al[cur][(wr + mb*16 + lm)*72 + 32 + lq*8];
    }
#pragma unroll
    for (int nb = 0; nb < 2; ++nb) {
      b0[nb] = *(bf16x8*)&Wl[cur][(wc + nb*16 + lm)*72 + lq*8];
      b1[nb] = *(bf16x8*)&Wl[cur][(wc + nb*16 + lm)*72 + 32 + lq*8];
    }
    __builtin_amdgcn_s_setprio(1);
#pragma unroll
    for (int mb = 0; mb < 2; ++mb)
#pragma unroll
      for (int nb = 0; nb < 2; ++nb) {
        acc[mb][nb] = MFMA16(af0[mb], b0[nb], acc[mb][nb]);
        acc[mb][nb] = MFMA16(af1[mb], b1[nb], acc[mb][nb]);
      }
    __builtin_amdgcn_s_setprio(0);
    if (pre) {
      *(uint4*)&Al[cur^1][sr0*72 + c8] = ra0;
      *(uint4*)&Al[cur^1][sr1*72 + c8] = ra1;
      rw0.storeb(&Wl[cur^1][sr0*72 + c8]);
      rw1.storeb(&Wl[cur^1][sr1*72 + c8]);
    }
    __syncthreads();
  }
#pragma unroll
  for (int mb = 0; mb < 2; ++mb) {
#pragma unroll
    for (int nb = 0; nb < 2; ++nb) {
#pragma unroll
      for (int r = 0; r < 4; ++r) {
        int grow = row0 + wr + mb*16 + lq*4 + r;
        int gcol = col0 + wc + nb*16 + lm;
        float v = acc[mb][nb][r] + bias[gcol];
        if (resid) v += resid[(size_t)grow*O + gcol];
        C[(size_t)grow*O + gcol] = (TO)v;
      }
    }
  }
}

// ---------------- MFMA matvec-GEMM, 64x64 tile, BK=64, batched over z --------
template<typename TA, typename TW, typename TO>
__global__ __launch_bounds__(256) void mv64_kernel(
    const TA* __restrict__ A, int K, const TW* __restrict__ W,
    TO* __restrict__ C, int O,
    const float* __restrict__ resid, const float* __restrict__ lam_ptr,
    const float* __restrict__ rowdiv,
    long zsA, long zsW, long zsC, long zsR)
{
  __shared__ __align__(16) fp16 Al[2][64*72];
  __shared__ __align__(16) fp16 Wl[2][64*72];
  int tid = threadIdx.x;
  int z = blockIdx.z;
  const TA* Az = A + (size_t)z*zsA;
  const TW* Wz = W + (size_t)z*zsW;
  TO* Cz = C + (size_t)z*zsC;
  const float* Rz = resid ? (resid + (size_t)z*zsR) : (const float*)0;
  int row0 = blockIdx.x*64, col0 = blockIdx.y*64;
  int lane = tid & 63, w = tid >> 6;
  int wr = (w>>1)*32, wc = (w&1)*32;
  int lm = lane & 15, lq = lane >> 4;
  int sr0 = tid >> 3, c8 = (tid & 7)*8;
  int sr1 = sr0 + 32;
  floatx4 acc[2][2];
#pragma unroll
  for (int mb = 0; mb < 2; ++mb)
#pragma unroll
    for (int nb = 0; nb < 2; ++nb) acc[mb][nb] = (floatx4){0.f,0.f,0.f,0.f};

  Raw8<TA> a0p, a1p; Raw8<TW> w0p, w1p;
  a0p.load(&Az[(size_t)(row0+sr0)*K + c8]);
  a1p.load(&Az[(size_t)(row0+sr1)*K + c8]);
  w0p.load(&Wz[(size_t)(col0+sr0)*K + c8]);
  w1p.load(&Wz[(size_t)(col0+sr1)*K + c8]);
  a0p.store(&Al[0][sr0*72 + c8]); a1p.store(&Al[0][sr1*72 + c8]);
  w0p.store(&Wl[0][sr0*72 + c8]); w1p.store(&Wl[0][sr1*72 + c8]);
  __syncthreads();

  for (int k0 = 0; k0 < K; k0 += 64) {
    int cur = (k0 >> 6) & 1;
    bool pre = (k0 + 64 < K);
    if (pre) {
      a0p.load(&Az[(size_t)(row0+sr0)*K + k0+64 + c8]);
      a1p.load(&Az[(size_t)(row0+sr1)*K + k0+64 + c8]);
      w0p.load(&Wz[(size_t)(col0+sr0)*K + k0+64 + c8]);
      w1p.load(&Wz[(size_t)(col0+sr1)*K + k0+64 + c8]);
    }
    fp16x8 a0[2], a1[2], b0[2], b1[2];
#pragma unroll
    for (int mb = 0; mb < 2; ++mb) {
      a0[mb] = *(fp16x8*)&Al[cur][(wr + mb*16 + lm)*72 + lq*8];
      a1[mb] = *(fp16x8*)&Al[cur][(wr + mb*16 + lm)*72 + 32 + lq*8];
    }
#pragma unroll
    for (int nb = 0; nb < 2; ++nb) {
      b0[nb] = *(fp16x8*)&Wl[cur][(wc + nb*16 + lm)*72 + lq*8];
      b1[nb] = *(fp16x8*)&Wl[cur][(wc + nb*16 + lm)*72 + 32 + lq*8];
    }
    __builtin_amdgcn_s_setprio(1);
#pragma unroll
    for (int mb = 0; mb < 2; ++mb)
#pragma unroll
      for (int nb = 0; nb < 2; ++nb) {
        acc[mb][nb] = MFMA16H(a0[mb], b0[nb], acc[mb][nb]);
        acc[mb][nb] = MFMA16H(a1[mb], b1[nb], acc[mb][nb]);
      }
    __builtin_amdgcn_s_setprio(0);
    if (pre) {
      a0p.store(&Al[cur^1][sr0*72 + c8]); a1p.store(&Al[cur^1][sr1*72 + c8]);
      w0p.store(&Wl[cur^1][sr0*72 + c8]); w1p.store(&Wl[cur^1][sr1*72 + c8]);
    }
    __syncthreads();
  }
  float lamv = 1.f;
  if (lam_ptr) lamv = softplusf(lam_ptr[0]) + 1e-6f;
#pragma unroll
  for (int mb = 0; mb < 2; ++mb) {
#pragma unroll
    for (int nb = 0; nb < 2; ++nb) {
#pragma unroll
      for (int r = 0; r < 4; ++r) {
        int grow = row0 + wr + mb*16 + lq*4 + r;
        int gcol = col0 + wc + nb*16 + lm;
        float v = acc[mb][nb][r];
        if (rowdiv) v /= rowdiv[(size_t)z*KM + grow];
        if (Rz) v += lamv * Rz[(size_t)grow*O + gcol];
        Cz[(size_t)grow*O + gcol] = (TO)v;
      }
    }
  }
}

// ---------------- fp32 tile GEMM (head only, O=64) ----------------
__global__ __launch_bounds__(256) void gemm_f32_kernel(
    const float* __restrict__ A, int K,
    const float* __restrict__ W, const float* __restrict__ bias,
    float* __restrict__ C, int O)
{
  __shared__ float As[32][68];
  __shared__ float Ws[32][68];
  int t = threadIdx.x;
  int row0 = blockIdx.x * 64;
  int col0 = blockIdx.y * 64;
  int ti = t & 15, tj = t >> 4;
  float acc[4][4] = {};
  for (int k0 = 0; k0 < K; k0 += 32) {
#pragma unroll
    for (int p = 0; p < 2; ++p) {
      int idx = p*256 + t;
      int ar = idx >> 3, af = (idx & 7)*4;
      float4 av = *(const float4*)&A[(size_t)(row0+ar)*K + k0 + af];
      As[af+0][ar] = av.x; As[af+1][ar] = av.y;
      As[af+2][ar] = av.z; As[af+3][ar] = av.w;
      float4 wv = *(const float4*)&W[(size_t)(col0+ar)*K + k0 + af];
      Ws[af+0][ar] = wv.x; Ws[af+1][ar] = wv.y;
      Ws[af+2][ar] = wv.z; Ws[af+3][ar] = wv.w;
    }
    __syncthreads();
#pragma unroll
    for (int kk = 0; kk < 32; ++kk) {
      float4 a4 = *(float4*)&As[kk][ti*4];
      float4 b4 = *(float4*)&Ws[kk][tj*4];
      float a[4] = {a4.x, a4.y, a4.z, a4.w};
      float b[4] = {b4.x, b4.y, b4.z, b4.w};
#pragma unroll
      for (int x = 0; x < 4; ++x)
#pragma unroll
        for (int y = 0; y < 4; ++y) acc[x][y] += a[x]*b[y];
    }
    __syncthreads();
  }
#pragma unroll
  for (int x = 0; x < 4; ++x) {
    int r = row0 + ti*4 + x;
#pragma unroll
    for (int y = 0; y < 4; ++y) {
      int c = col0 + tj*4 + y;
      float v = fmaxf(acc[x][y] + bias[c], 0.f);
      C[(size_t)r*O + c] = v;
    }
  }
}

// ---------------- transpose-init: PT=RT=F^T, XT=0 (no atomics) --------------
__global__ __launch_bounds__(256) void tinit_kernel(
    const float* __restrict__ F, float* __restrict__ PT, float* __restrict__ RT,
    float* __restrict__ XT)
{
  __shared__ float Ls[64][68];
  int t = threadIdx.x;
  int k0 = blockIdx.x*64, n0 = blockIdx.y*64, z = blockIdx.z;
#pragma unroll
  for (int p = 0; p < 4; ++p) {
    int idx = p*256 + t;
    int kr = idx >> 4, c4 = (idx & 15)*4;
    *(float4*)&Ls[kr][c4] = *(const float4*)&F[((size_t)z*KM + k0+kr)*DD + n0 + c4];
  }
  __syncthreads();
#pragma unroll
  for (int p = 0; p < 4; ++p) {
    int idx = p*256 + t;
    int nl = idx >> 4, k4 = (idx & 15)*4;
    float4 v = { Ls[k4+0][nl], Ls[k4+1][nl], Ls[k4+2][nl], Ls[k4+3][nl] };
    size_t o = ((size_t)z*DD + n0+nl)*KM + k0 + k4;
    *(float4*)&PT[o] = v;
    *(float4*)&RT[o] = v;
    float4 zr = {0.f,0.f,0.f,0.f};
    *(float4*)&XT[o] = zr;
  }
}

// ---------------- merged CG update (self-contained, deterministic) ----------
__global__ __launch_bounds__(256) void cg_update_kernel(
    float* __restrict__ XT, float* __restrict__ RT,
    float* __restrict__ PT, const float* __restrict__ APT)
{
  __shared__ float redw[12];
  int row = blockIdx.x;
  int t = threadIdx.x;
  int lane = t & 63, w = t >> 6;
  size_t base = (size_t)row*KM + (size_t)t*4;
  float4 p4 = *(float4*)&PT[base];
  float4 a4 = *(const float4*)&APT[base];
  float4 r4 = *(float4*)&RT[base];
  float4 x4 = *(float4*)&XT[base];
  float prr  = (r4.x*r4.x + r4.y*r4.y) + (r4.z*r4.z + r4.w*r4.w);
  float ppap = (p4.x*a4.x + p4.y*a4.y) + (p4.z*a4.z + p4.w*a4.w);
  prr = wred(prr); ppap = wred(ppap);
  if (lane == 0) { redw[w] = prr; redw[4+w] = ppap; }
  __syncthreads();
  float rr  = (redw[0]+redw[1]) + (redw[2]+redw[3]);
  float pap = (redw[4]+redw[5]) + (redw[6]+redw[7]);
  float alpha = (pap > 1e-30f) ? rr/pap : 0.f;
  x4.x += alpha*p4.x; x4.y += alpha*p4.y; x4.z += alpha*p4.z; x4.w += alpha*p4.w;
  r4.x -= alpha*a4.x; r4.y -= alpha*a4.y; r4.z -= alpha*a4.z; r4.w -= alpha*a4.w;
  *(float4*)&XT[base] = x4;
  *(float4*)&RT[base] = r4;
  float s = (r4.x*r4.x + r4.y*r4.y) + (r4.z*r4.z + r4.w*r4.w);
  s = wred(s);
  if (lane == 0) redw[8+w] = s;
  __syncthreads();
  float rrnew = (redw[8]+redw[9]) + (redw[10]+redw[11]);
  float beta = (rr > 1e-30f) ? rrnew/rr : 0.f;
  p4.x = r4.x + beta*p4.x; p4.y = r4.y + beta*p4.y;
  p4.z = r4.z + beta*p4.z; p4.w = r4.w + beta*p4.w;
  *(float4*)&PT[base] = p4;
}

// ---------------- RoPE (coalesced, de-interleaved QKV) ----------------
__global__ __launch_bounds__(256) void rope_split_kernel(
    const bf16* __restrict__ qkv, const float* __restrict__ enc0,
    const float* __restrict__ enc1, bf16* __restrict__ Qo,
    bf16* __restrict__ Ko)
{
  int t = threadIdx.x;
  int r = blockIdx.x*2 + (t >> 7);
  int c = (t & 127)*2;                    // even col
  int ts = r >> 10, i = r & 1023;
  int d = c & 63;
  const float* enc = (ts < BB) ? enc0 : enc1;
  int s = (ts < BB) ? ts : ts - BB;
  const float* eb = enc + (((size_t)s*2)*KM + i)*HD;
  float2 cs = *(const float2*)&eb[d];
  float2 sn = *(const float2*)&eb[(size_t)KM*HD + d];
  size_t base = (size_t)r*768;
  bf16x2 qv = *(const bf16x2*)&qkv[base + c];
  bf16x2 kv = *(const bf16x2*)&qkv[base + 256 + c];
  float q0 = (float)qv[0], q1 = (float)qv[1];
  float k0 = (float)kv[0], k1 = (float)kv[1];
  float oq0 = q0*cs.x - q1*sn.x, oq1 = q1*cs.y + q0*sn.y;
  float ok0 = k0*cs.x - k1*sn.x, ok1 = k1*cs.y + k0*sn.y;
  size_t o = (size_t)r*DD + c;
  bf16x2 qo = {(bf16)(0.1803368801f*oq0), (bf16)(0.1803368801f*oq1)};
  bf16x2 ko = {(bf16)ok0, (bf16)ok1};
  *(bf16x2*)&Qo[o] = qo;
  *(bf16x2*)&Ko[o] = ko;
}

// ---------------- V -> V^T transpose (per (stream,head)), strided src -------
__global__ __launch_bounds__(256) void vt_kernel(
    const bf16* __restrict__ Vin, int vstride, bf16* __restrict__ VT)
{
  __shared__ __align__(16) bf16 Ls[64*72];
  int tid = threadIdx.x;
  int zh = blockIdx.x;
  int ts = zh >> 2, h = zh & 3;
  int k0 = blockIdx.y * 64;
#pragma unroll
  for (int p = 0; p < 2; ++p) {
    int idx = p*256 + tid;
    int kr = idx >> 3, c8 = (idx & 7)*8;
    *(uint4*)&Ls[kr*72 + c8] =
      *(const uint4*)&Vin[((size_t)ts*KM + k0 + kr)*vstride + h*HD + c8];
  }
  __syncthreads();
#pragma unroll
  for (int p = 0; p < 2; ++p) {
    int idx = p*256 + tid;
    int dr = idx >> 3, k8 = (idx & 7)*8;
    bf16 tmp[8] __attribute__((aligned(16)));
#pragma unroll
    for (int j = 0; j < 8; ++j) tmp[j] = Ls[(k8+j)*72 + dr];
    *(uint4*)&VT[((size_t)zh*HD + dr)*KM + k0 + k8] = *(uint4*)tmp;
  }
}

// ---------------- MFMA flash attention (KVBLK=128, S^T scheme, V^T input) ---
// Round-8-proven per-tile logic, restructured to stage TWO 64-k sub-tiles
// per barrier pair: barriers per KV pass halved (32 -> 16), 8 staged 16B
// loads in flight per region. LDS = Q + K0 + K1 + V0 + V1 = 40 KB -> still
// 4 blocks/CU. Per-tile op sequence identical -> bit-identical numerics.
__device__ __forceinline__ void mha_subtile(
    const bf16* Kc, const bf16* Vc, bf16x8 qa0, bf16x8 qa1,
    short4v ones4, float& m_, floatx4& lacc, floatx4* oacc,
    int lm, int lq)
{
  floatx4 st[4];
  float negm = -m_;
  __builtin_amdgcn_s_setprio(1);
#pragma unroll
  for (int kb = 0; kb < 4; ++kb) {
    bf16x8 a0 = *(bf16x8*)&Kc[SWZ(kb*16 + lm, lq*8)];
    bf16x8 a1 = *(bf16x8*)&Kc[SWZ(kb*16 + lm, 32 + lq*8)];
    floatx4 acc = (floatx4){negm, negm, negm, negm};
    acc = MFMA16(a0, qa0, acc);
    acc = MFMA16(a1, qa1, acc);
    st[kb] = acc;
  }
  __builtin_amdgcn_s_setprio(0);
  // local max, max3-shaped (16 -> 8 ops)
  float ma = fmaxf(fmaxf(st[0][0], st[0][1]), st[0][2]);
  float mb = fmaxf(fmaxf(st[0][3], st[1][0]), st[1][1]);
  float mc = fmaxf(fmaxf(st[1][2], st[1][3]), st[2][0]);
  float md = fmaxf(fmaxf(st[2][1], st[2][2]), st[2][3]);
  float me = fmaxf(fmaxf(st[3][0], st[3][1]), st[3][2]);
  float mf = fmaxf(fmaxf(ma, mb), st[3][3]);
  float mg = fmaxf(fmaxf(mc, md), me);
  float mx = fmaxf(mf, mg);
  // defer-max: wave-uniform test; shfls + subs only when a rescale is needed
  if (!__all(mx <= 8.f)) {
    float wmx = fmaxf(mx, __shfl_xor(mx, 16));
    wmx = fmaxf(wmx, __shfl_xor(wmx, 32));
    float delta = fmaxf(wmx, 0.f);
    float al = exp2f(-delta);
    m_ += delta;
    lacc[0] *= al; lacc[1] *= al; lacc[2] *= al; lacc[3] *= al;
#pragma unroll
    for (int db = 0; db < 4; ++db) {
      oacc[db][0] *= al; oacc[db][1] *= al;
      oacc[db][2] *= al; oacc[db][3] *= al;
    }
#pragma unroll
    for (int kb = 0; kb < 4; ++kb) {
      st[kb][0] -= delta; st[kb][1] -= delta;
      st[kb][2] -= delta; st[kb][3] -= delta;
    }
  }
  __builtin_amdgcn_s_setprio(1);
#pragma unroll
  for (int kb = 0; kb < 4; ++kb) {
    float p0 = exp2f(st[kb][0]);
    float p1 = exp2f(st[kb][1]);
    float p2 = exp2f(st[kb][2]);
    float p3 = exp2f(st[kb][3]);
    short4v pb = pack4(p0, p1, p2, p3);
    lacc = MFMA1K(ones4, pb, lacc);
#pragma unroll
    for (int db = 0; db < 4; ++db) {
      short4v va = *(const short4v*)&Vc[SWZ(db*16 + lm, kb*16 + lq*4)];
      oacc[db] = MFMA1K(va, pb, oacc[db]);
    }
  }
  __builtin_amdgcn_s_setprio(0);
}

__device__ __forceinline__ void mha_body(
    const bf16* __restrict__ Qg, const bf16* __restrict__ Kg,
    const bf16* __restrict__ VTg, bf16* __restrict__ Og,
    size_t qkbase, size_t obase, size_t vbase, int qkstride,
    int q0, int tid, bf16* Qs, bf16* K0, bf16* K1, bf16* V0, bf16* V1)
{
  int lane = tid & 63, w = tid >> 6;
  int lm = lane & 15, lq = lane >> 4;
  int r0 = tid >> 3, c8 = (tid & 7)*8;
  int r1 = r0 + 32;
  *(uint4*)&Qs[SWZ(r0,c8)] = *(const uint4*)&Qg[qkbase + (size_t)(q0+r0)*qkstride + c8];
  *(uint4*)&Qs[SWZ(r1,c8)] = *(const uint4*)&Qg[qkbase + (size_t)(q0+r1)*qkstride + c8];
  __syncthreads();
  bf16x8 qa0 = *(bf16x8*)&Qs[SWZ(w*16 + lm, lq*8)];
  bf16x8 qa1 = *(bf16x8*)&Qs[SWZ(w*16 + lm, 32 + lq*8)];
  short4v ones4;
  { bf16x4 o1 = {(bf16)1.f,(bf16)1.f,(bf16)1.f,(bf16)1.f};
    __builtin_memcpy(&ones4, &o1, 8); }
  float m_ = 0.f;
  floatx4 lacc = (floatx4){0.f,0.f,0.f,0.f};
  floatx4 oacc[4];
#pragma unroll
  for (int db = 0; db < 4; ++db) oacc[db] = (floatx4){0.f,0.f,0.f,0.f};

  for (int kt = 0; kt < KM; kt += 128) {
    __syncthreads();
    *(uint4*)&K0[SWZ(r0,c8)] = *(const uint4*)&Kg[qkbase + (size_t)(kt+r0)*qkstride + c8];
    *(uint4*)&K0[SWZ(r1,c8)] = *(const uint4*)&Kg[qkbase + (size_t)(kt+r1)*qkstride + c8];
    *(uint4*)&K1[SWZ(r0,c8)] = *(const uint4*)&Kg[qkbase + (size_t)(kt+64+r0)*qkstride + c8];
    *(uint4*)&K1[SWZ(r1,c8)] = *(const uint4*)&Kg[qkbase + (size_t)(kt+64+r1)*qkstride + c8];
    *(uint4*)&V0[SWZ(r0,c8)] = *(const uint4*)&VTg[vbase + (size_t)r0*KM + kt + c8];
    *(uint4*)&V0[SWZ(r1,c8)] = *(const uint4*)&VTg[vbase + (size_t)r1*KM + kt + c8];
    *(uint4*)&V1[SWZ(r0,c8)] = *(const uint4*)&VTg[vbase + (size_t)r0*KM + kt+64 + c8];
    *(uint4*)&V1[SWZ(r1,c8)] = *(const uint4*)&VTg[vbase + (size_t)r1*KM + kt+64 + c8];
    __syncthreads();
    mha_subtile(K0, V0, qa0, qa1, ones4, m_, lacc, oacc, lm, lq);
    mha_subtile(K1, V1, qa0, qa1, ones4, m_, lacc, oacc, lm, lq);
  }
  float inv = 1.f / lacc[0];
  int q = q0 + w*16 + lm;
#pragma unroll
  for (int db = 0; db < 4; ++db) {
    bf16x4 o4 = { (bf16)(oacc[db][0]*inv), (bf16)(oacc[db][1]*inv),
                  (bf16)(oacc[db][2]*inv), (bf16)(oacc[db][3]*inv) };
    *(bf16x4*)&Og[obase + (size_t)q*DD + db*16 + lq*4] = o4;
  }
}

// self attention: grid (zh=64, qtile=16); Q/K row stride 256
__global__ __launch_bounds__(256) void mha_kernel(
    const bf16* __restrict__ Qg, const bf16* __restrict__ Kg,
    const bf16* __restrict__ VTg, bf16* __restrict__ Og)
{
  __shared__ __align__(16) bf16 SM[5*4096];
  int zh = blockIdx.x;
  int z = zh >> 2, h = zh & 3;
  size_t base = ((size_t)z*KM)*DD + (size_t)h*HD;
  size_t vbase = (size_t)zh*HD*KM;
  mha_body(Qg, Kg, VTg, Og, base, base, vbase, DD,
           blockIdx.y*64, threadIdx.x,
           SM, SM + 4096, SM + 2*4096, SM + 3*4096, SM + 4*4096);
}

// cross attention, both directions: grid (zh=32, qtile=16, dir=2)
__global__ __launch_bounds__(256) void mha_cross_kernel(
    const bf16* __restrict__ QKV2, const bf16* __restrict__ VT2,
    bf16* __restrict__ ATTO2)
{
  __shared__ __align__(16) bf16 SM[5*4096];
  int dir = blockIdx.z;
  const bf16* Qg  = QKV2 + (dir ? (size_t)BN*512 : 0);
  const bf16* Kg  = QKV2 + (dir ? 0 : (size_t)BN*512);
  const bf16* VTg = VT2  + (dir ? 0 : (size_t)32*HD*KM);
  bf16*       Og  = ATTO2 + (dir ? (size_t)BN*DD : 0);
  int zh = blockIdx.x;
  int z = zh >> 2, h = zh & 3;
  size_t qkbase = ((size_t)z*KM)*512 + (size_t)h*HD;
  size_t obase  = ((size_t)z*KM)*DD  + (size_t)h*HD;
  size_t vbase  = (size_t)zh*HD*KM;
  mha_body(Qg, Kg, VTg, Og, qkbase, obase, vbase, 512,
           blockIdx.y*64, threadIdx.x,
           SM, SM + 4096, SM + 2*4096, SM + 3*4096, SM + 4*4096);
}

// ---------------- in-place LayerNorm + exact GELU (bf16, width 512) --------
__global__ __launch_bounds__(256) void ln_gelu_kernel(
    bf16* __restrict__ Hb, const float* __restrict__ g,
    const float* __restrict__ be)
{
  int t = threadIdx.x;
  int lane = t & 63, w = t >> 6;
  size_t r = (size_t)blockIdx.x*4 + w;
  bf16* rowp = Hb + r*512 + lane*8;
  bf16x8 hv = *(bf16x8*)rowp;
  float x[8];
#pragma unroll
  for (int j = 0; j < 8; ++j) x[j] = (float)hv[j];
  float s = ((x[0]+x[1]) + (x[2]+x[3])) + ((x[4]+x[5]) + (x[6]+x[7]));
  s = wred(s);
  float mu = s * (1.f/512.f);
  float v = 0.f;
#pragma unroll
  for (int j = 0; j < 8; ++j) { float d = x[j] - mu; v += d*d; }
  v = wred(v);
  float rstd = rsqrtf(v*(1.f/512.f) + 1e-5f);
  float4 g0 = *(const float4*)&g[lane*8];
  float4 g1 = *(const float4*)&g[lane*8 + 4];
  float4 b0 = *(const float4*)&be[lane*8];
  float4 b1 = *(const float4*)&be[lane*8 + 4];
  float gv[8] = {g0.x,g0.y,g0.z,g0.w,g1.x,g1.y,g1.z,g1.w};
  float bv[8] = {b0.x,b0.y,b0.z,b0.w,b1.x,b1.y,b1.z,b1.w};
  bf16x8 ov;
#pragma unroll
  for (int j = 0; j < 8; ++j) {
    float h = (x[j] - mu)*rstd*gv[j] + bv[j];
    h = 0.5f*h*(1.f + erff(h*0.70710678118f));
    ov[j] = (bf16)h;
  }
  *(bf16x8*)rowp = ov;
}

// ---------------- final head 2 ----------------
__global__ __launch_bounds__(256) void head2_kernel(
    const float* __restrict__ Hb, const float* __restrict__ w,
    const float* __restrict__ b, float* __restrict__ out)
{
  int r = blockIdx.x*256 + threadIdx.x;
  float acc = b[0];
#pragma unroll
  for (int k = 0; k < 64; ++k) acc += Hb[(size_t)r*64 + k]*w[k];
  out[r] = 1.f/(1.f + expf(-acc));
}

extern "C" void kernel_launch(void* const* d_in, const int* in_sizes, int n_in,
                              void* d_out, int out_size, void* d_ws, size_t ws_size,
                              hipStream_t stream)
{
  (void)in_sizes; (void)n_in; (void)out_size; (void)ws_size;
  const float* fa      = (const float*)d_in[0];
  const float* fb      = (const float*)d_in[1];
  const int*   matches = (const int*)d_in[2];
  const float* ka      = (const float*)d_in[3];
  const float* kb      = (const float*)d_in[4];
  const float* lam     = (const float*)d_in[5];
  const float* beta    = (const float*)d_in[6];
  const float* Wr      = (const float*)d_in[7];
  const float* pW1     = (const float*)d_in[8];
  const float* pb1     = (const float*)d_in[9];
  const float* pW2     = (const float*)d_in[10];
  const float* pb2     = (const float*)d_in[11];
  const float* sWqkv   = (const float*)d_in[12];
  const float* sbqkv   = (const float*)d_in[13];
  const float* sWo     = (const float*)d_in[14];
  const float* sbo     = (const float*)d_in[15];
  const float* sW1     = (const float*)d_in[16];
  const float* sb1     = (const float*)d_in[17];
  const float* sg      = (const float*)d_in[18];
  const float* sbe     = (const float*)d_in[19];
  const float* sW2     = (const float*)d_in[20];
  const float* sb2     = (const float*)d_in[21];
  const float* cWqk    = (const float*)d_in[22];
  const float* cbqk    = (const float*)d_in[23];
  const float* cWv     = (const float*)d_in[24];
  const float* cbv     = (const float*)d_in[25];
  const float* cWo     = (const float*)d_in[26];
  const float* cbo     = (const float*)d_in[27];
  const float* cW1     = (const float*)d_in[28];
  const float* cb1     = (const float*)d_in[29];
  const float* cgw     = (const float*)d_in[30];
  const float* cbe     = (const float*)d_in[31];
  const float* cW2     = (const float*)d_in[32];
  const float* cb2     = (const float*)d_in[33];

  char* wsb = (char*)d_ws;
  float* DCAT = (float*)wsb;                      // 16,777,216 B
  float* ENC0 = (float*)(wsb + 16777216);
  float* ENC1 = (float*)(wsb + 20971520);
  float* XY0  = (float*)(wsb + 25165824);
  float* XY1  = (float*)(wsb + 25231360);
  float* ROWS = (float*)(wsb + 25296896);
  char*  POOL = wsb + 25354240;
  const size_t SLOT = 8388608;
  // CG phase
  fp16*  KMATH = (fp16*)POOL;                    // slots 0-1
  float* FBUF  = (float*)(POOL + 2*SLOT);
  float* PT    = (float*)(POOL + 3*SLOT);
  float* RT    = (float*)(POOL + 4*SLOT);
  float* XT    = (float*)(POOL + 5*SLOT);
  float* APT   = (float*)(POOL + 6*SLOT);
  // transformer phase
  bf16*  QKV   = (bf16*)POOL;                    // slots 0-2 (q|k|v cols)
  bf16*  QR    = (bf16*)(POOL + 3*SLOT);
  bf16*  KR    = (bf16*)(POOL + 4*SLOT);
  bf16*  VTG   = (bf16*)(POOL + 8*SLOT);         // slot 8 (V^T, self)
  bf16*  ATTO  = (bf16*)POOL;                    // slot 0
  bf16*  MSG   = (bf16*)(POOL + 1*SLOT);
  bf16*  H1    = (bf16*)(POOL + 6*SLOT);         // slots 6-7
  bf16*  QKV2  = (bf16*)POOL;                    // slots 0-1 (cross q|v cols)
  bf16*  ATTO2 = (bf16*)(POOL + 2*SLOT);
  bf16*  MSG2  = (bf16*)(POOL + 3*SLOT);
  bf16*  VT2   = (bf16*)(POOL + 4*SLOT);         // slot 4 (V^T, cross)
  bf16*  H1C   = H1;
  float* HBUF  = (float*)POOL;

  const float scq = 0.42466090f;   // 64^-0.25 * sqrt(log2 e)

  // ---- gather / posenc / Kmat ----
  gather_kernel<<<BN, 256, 0, stream>>>(fa, fb, matches, ka, kb, FBUF, DCAT, XY0, XY1);
  posenc_kernel<<<BN/4, 256, 0, stream>>>(XY0, Wr, ENC0);
  posenc_kernel<<<BN/4, 256, 0, stream>>>(XY1, Wr, ENC1);
  kmat_kernel<<<BN, 256, 0, stream>>>(XY0, beta, KMATH, ROWS);

  // ---- CG (transposed state, deterministic: no fp atomics anywhere) ----
  tinit_kernel<<<dim3(16,4,BB), 256, 0, stream>>>(FBUF, PT, RT, XT);
  for (int it = 0; it < CG_ITERS; ++it) {
    mv64_kernel<float,fp16,float><<<dim3(4,16,BB), 256, 0, stream>>>(
        PT, 1024, KMATH, APT, 1024, PT, lam, (const float*)0,
        262144, 1048576, 262144, 262144);
    cg_update_kernel<<<2048, 256, 0, stream>>>(XT, RT, PT, APT);
  }

  // ---- d1 = rownorm(Kmat) @ C  (d0 = f_i already written by gather) ----
  mv64_kernel<fp16,float,float><<<dim3(16,4,BB), 256, 0, stream>>>(
      KMATH, 1024, XT, DCAT + (size_t)BN*DD, 256,
      (const float*)0, (const float*)0, ROWS,
      1048576, 262144, 262144, 0);

  // ---- transformer layers ----
  for (int l = 0; l < NLAYER; ++l) {
    // self block: QKV projection (WPERM de-interleave); 16384 rows -> 256 blocks
    mm64g_kernel<1,0,float,bf16,bf16><<<dim3(256,12,1), 256, 0, stream>>>(
        DCAT, (const bf16*)0, 256, 256, sWqkv + (size_t)l*768*256, sbqkv + l*768,
        (const float*)0, (const float*)0, QKV, 768, 1.f, 1.f, (const float*)0);
    rope_split_kernel<<<8192, 256, 0, stream>>>(QKV, ENC0, ENC1, QR, KR);
    vt_kernel<<<dim3(64,16), 256, 0, stream>>>(QKV + 512, 768, VTG);
    mha_kernel<<<dim3(64,16), 256, 0, stream>>>(QR, KR, VTG, ATTO);
    mm64d_kernel<bf16><<<dim3(256,4,1), 256, 0, stream>>>(
        ATTO, 256, sWo + (size_t)l*256*256, sbo + l*256, MSG, 256,
        (const float*)0);
    mm64g_kernel<0,0,float,bf16,bf16><<<dim3(256,8,1), 256, 0, stream>>>(
        DCAT, MSG, 256, 512, sW1 + (size_t)l*512*512, sb1 + l*512,
        (const float*)0, (const float*)0, H1, 512, 1.f, 1.f, (const float*)0);
    ln_gelu_kernel<<<N2/4, 256, 0, stream>>>(H1, sg + l*512, sbe + l*512);
    mm64d_kernel<float><<<dim3(256,4,1), 256, 0, stream>>>(
        H1, 512, sW2 + (size_t)l*256*512, sb2 + l*256, DCAT, 256, DCAT);
    // cross block: fused qk|v projection into QKV2; 16384 rows -> 256 blocks
    mm64g_kernel<0,1,float,bf16,bf16><<<dim3(256,8,1), 256, 0, stream>>>(
        DCAT, (const bf16*)0, 256, 256, cWqk + (size_t)l*256*256, cbqk + l*256,
        cWv + (size_t)l*256*256, cbv + l*256, QKV2, 512, scq, 1.f,
        (const float*)0);
    vt_kernel<<<dim3(64,16), 256, 0, stream>>>(QKV2 + 256, 512, VT2);
    mha_cross_kernel<<<dim3(32,16,2), 256, 0, stream>>>(QKV2, VT2, ATTO2);
    mm64d_kernel<bf16><<<dim3(256,4,1), 256, 0, stream>>>(
        ATTO2, 256, cWo + (size_t)l*256*256, cbo + l*256, MSG2, 256,
        (const float*)0);
    mm64g_kernel<0,0,float,bf16,bf16><<<dim3(256,8,1), 256, 0, stream>>>(
        DCAT, MSG2, 256, 512, cW1 + (size_t)l*512*512, cb1 + l*512,
        (const float*)0, (const float*)0, H1C, 512, 1.f, 1.f, (const float*)0);
    ln_gelu_kernel<<<N2/4, 256, 0, stream>>>(H1C, cgw + l*512, cbe + l*512);
    mm64d_kernel<float><<<dim3(256,4,1), 256, 0, stream>>>(
        H1C, 512, cW2 + (size_t)l*256*512, cb2 + l*256, DCAT, 256, DCAT);
  }

  // ---- head ----
  gemm_f32_kernel<<<dim3(128,1), 256, 0, stream>>>(DCAT, 256, pW1, pb1, HBUF, 64);
  head2_kernel<<<32, 256, 0, stream>>>(HBUF, pW2, pb2, (float*)d_out);
}